// Round 1
// baseline (1205.178 us; speedup 1.0000x reference)
//
#include <hip/hip_runtime.h>
#include <math.h>

#define N2 2048
#define RS 144            // padded LDS row stride (floats) for 128-wide tiles
#define LRELU_S 0.2f
#define BN4_RS 0.9999950000374997f   // rsqrt(1+1e-5)

__device__ __forceinline__ int pof(int x) { return x + ((x >> 5) << 2); } // 4-float bump per 32

// ---------------------------------------------------------------------------
// Generic 128x128-tile fp32 GEMM: out[bz][o][n] = sum_k A[k][o] * B[k][n]
// ASRC: 0 = weight [O][Ktot] row-major (aw)
//       1 = normalized x rows: aw=[B][Ktot][2048] * invnA  (simi)
// BSRC: 0 = plain [B][Ktot][2048] (b0)
//       1 = normalized [B][Ktot][2048] (b0 * invnB)        (simi)
//       2 = cat4: x1(64) x2(64) x3(128) x4(256)
//       3 = cat2: x3(128) G(128)
// EPI:  0 raw; 1 = bn4-scale+bias+lrelu (epg,epb); 2 = +bias (epb)
// ---------------------------------------------------------------------------
template<int ASRC, int BSRC, int EPI>
__global__ __launch_bounds__(256) void gemmK(
    const float* __restrict__ aw,  const float* __restrict__ invnA,
    const float* __restrict__ b0,  const float* __restrict__ invnB,
    const float* __restrict__ bx1, const float* __restrict__ bx2,
    const float* __restrict__ bx3, const float* __restrict__ bx4,
    const float* __restrict__ epg, const float* __restrict__ epb,
    float* __restrict__ out, long sOut, int Ktot, int bbase)
{
    __shared__ float a_sm[32 * RS];
    __shared__ float b_sm[32 * RS];
    const int t  = threadIdx.x;
    const int n0 = blockIdx.x * 128;
    const int o0 = blockIdx.y * 128;
    const int bz = blockIdx.z;
    const int bsrc = bbase + bz;

    float acc[8][8];
    #pragma unroll
    for (int i = 0; i < 8; ++i) {
        #pragma unroll
        for (int j = 0; j < 8; ++j) acc[i][j] = 0.f;
    }

    const int o8 = (t & 15) * 8;
    const int n8 = (t >> 4) * 8;

    for (int kc = 0; kc < Ktot; kc += 32) {
        __syncthreads();
        // ---- load A tile [32k][128o] ----
        if (ASRC == 0) {
            const int k4 = (t & 7) * 4;
            const int ob = t >> 3;                // 0..31
            #pragma unroll
            for (int i = 0; i < 4; ++i) {
                const int o = ob + 32 * i;
                float4 v = *(const float4*)(aw + (long)(o0 + o) * Ktot + kc + k4);
                a_sm[(k4 + 0) * RS + pof(o)] = v.x;
                a_sm[(k4 + 1) * RS + pof(o)] = v.y;
                a_sm[(k4 + 2) * RS + pof(o)] = v.z;
                a_sm[(k4 + 3) * RS + pof(o)] = v.w;
            }
        } else {
            const int r4 = (t & 31) * 4;
            const int kb = t >> 5;                // 0..7
            #pragma unroll
            for (int i = 0; i < 4; ++i) {
                const int k = kb + 8 * i;
                float4 v = *(const float4*)(aw + ((long)bsrc * Ktot + kc + k) * N2 + o0 + r4);
                float4 s = *(const float4*)(invnA + (long)bsrc * N2 + o0 + r4);
                v.x *= s.x; v.y *= s.y; v.z *= s.z; v.w *= s.w;
                *(float4*)(a_sm + k * RS + pof(r4)) = v;
            }
        }
        // ---- load B tile [32k][128n] ----
        {
            const int c4 = (t & 31) * 4;
            const int kb = t >> 5;
            #pragma unroll
            for (int i = 0; i < 4; ++i) {
                const int k = kb + 8 * i;
                const int kg = kc + k;
                float4 v;
                if (BSRC == 0) {
                    v = *(const float4*)(b0 + ((long)bsrc * Ktot + kg) * N2 + n0 + c4);
                } else if (BSRC == 1) {
                    v = *(const float4*)(b0 + ((long)bsrc * Ktot + kg) * N2 + n0 + c4);
                    float4 s = *(const float4*)(invnB + (long)bsrc * N2 + n0 + c4);
                    v.x *= s.x; v.y *= s.y; v.z *= s.z; v.w *= s.w;
                } else if (BSRC == 2) {
                    if (kg < 64)        v = *(const float4*)(bx1 + ((long)bsrc *  64 +  kg       ) * N2 + n0 + c4);
                    else if (kg < 128)  v = *(const float4*)(bx2 + ((long)bsrc *  64 + (kg -  64)) * N2 + n0 + c4);
                    else if (kg < 256)  v = *(const float4*)(bx3 + ((long)bsrc * 128 + (kg - 128)) * N2 + n0 + c4);
                    else                v = *(const float4*)(bx4 + ((long)bsrc * 256 + (kg - 256)) * N2 + n0 + c4);
                } else { // 3: cat2(x3, G)
                    if (kg < 128)       v = *(const float4*)(bx3 + ((long)bsrc * 128 +  kg       ) * N2 + n0 + c4);
                    else                v = *(const float4*)(bx4 + ((long)bsrc * 128 + (kg - 128)) * N2 + n0 + c4);
                }
                *(float4*)(b_sm + k * RS + pof(c4)) = v;
            }
        }
        __syncthreads();
        // ---- outer-product accumulate ----
        #pragma unroll 4
        for (int k = 0; k < 32; ++k) {
            float ar[8], br[8];
            *(float4*)&ar[0] = *(const float4*)(a_sm + k * RS + pof(o8));
            *(float4*)&ar[4] = *(const float4*)(a_sm + k * RS + pof(o8) + 4);
            *(float4*)&br[0] = *(const float4*)(b_sm + k * RS + pof(n8));
            *(float4*)&br[4] = *(const float4*)(b_sm + k * RS + pof(n8) + 4);
            #pragma unroll
            for (int i = 0; i < 8; ++i) {
                #pragma unroll
                for (int j = 0; j < 8; ++j)
                    acc[i][j] = fmaf(ar[i], br[j], acc[i][j]);
            }
        }
    }
    // ---- epilogue ----
    #pragma unroll
    for (int i = 0; i < 8; ++i) {
        const int o = o0 + o8 + i;
        float sc = 1.f, sh = 0.f;
        if (EPI == 1) { sc = epg[o] * BN4_RS; sh = epb[o]; }
        else if (EPI == 2) { sh = epb[o]; }
        float r[8];
        #pragma unroll
        for (int j = 0; j < 8; ++j) {
            float v = acc[i][j];
            if (EPI == 1) { v = v * sc + sh; v = (v >= 0.f) ? v : LRELU_S * v; }
            else if (EPI == 2) { v = v + sh; }
            r[j] = v;
        }
        float* dst = out + (long)bz * sOut + (long)o * N2 + n0 + n8;
        *(float4*)(dst)     = *(float4*)&r[0];
        *(float4*)(dst + 4) = *(float4*)&r[4];
    }
}

// ---------------------------------------------------------------------------
// inverse norms over C=128 channels for x3 (z=0) and y3 (z=1)
__global__ void normK(const float* __restrict__ x3, const float* __restrict__ y3,
                      float* __restrict__ invnx, float* __restrict__ invny)
{
    const int n = blockIdx.x * 256 + threadIdx.x;
    const int b = blockIdx.y;
    const float* src = blockIdx.z ? y3 : x3;
    float ss = 0.f;
    for (int c = 0; c < 128; ++c) {
        float v = src[((long)b * 128 + c) * N2 + n];
        ss = fmaf(v, v, ss);
    }
    (blockIdx.z ? invny : invnx)[b * N2 + n] = rsqrtf(ss);
}

// transpose y3 [B][128][2048] -> yT [B][2048][128]
__global__ __launch_bounds__(256) void transK(const float* __restrict__ y3, float* __restrict__ yT)
{
    __shared__ float lt[64 * 133];
    const int t = threadIdx.x;
    const int m0 = blockIdx.x * 64;
    const int b  = blockIdx.y;
    {
        const int mi = t & 63;
        const int cb = t >> 6;               // 0..3
        for (int i = 0; i < 32; ++i) {
            const int cc = cb + 4 * i;
            lt[mi * 133 + cc] = y3[((long)b * 128 + cc) * N2 + m0 + mi];
        }
    }
    __syncthreads();
    {
        const int cc = t & 127;
        const int mb = t >> 7;               // 0..1
        for (int i = 0; i < 32; ++i) {
            const int m = mb + 2 * i;
            yT[((long)b * N2 + m0 + m) * 128 + cc] = lt[m * 133 + cc];
        }
    }
}

// W4' = [W4a - W4b | W4b]  (folds the "- x3 * sum(w)" term of agg into conv4)
__global__ void w4pK(const float* __restrict__ w4, float* __restrict__ w4p)
{
    const int idx = blockIdx.x * 256 + threadIdx.x;      // 256*256
    const int k = idx & 255;
    float v = w4[idx];
    if (k < 128) v -= w4[idx + 128];
    w4p[idx] = v;
}

// top-20 of a 2048 simi row + softmax weights
__global__ __launch_bounds__(256) void topkK(const float* __restrict__ simi,
    float* __restrict__ topw, int* __restrict__ topi, int bbase)
{
    __shared__ float s[2048];
    __shared__ float bwv[4]; __shared__ int bwi[4];
    __shared__ float selv[20]; __shared__ int seli[20];
    const int t = threadIdx.x;
    const int n = blockIdx.x;
    const int bl = blockIdx.y;
    const float* row = simi + ((long)bl * N2 + n) * N2;
    #pragma unroll
    for (int i = 0; i < 8; ++i) s[t + 256 * i] = row[t + 256 * i];
    __syncthreads();
    for (int it = 0; it < 20; ++it) {
        float bv = -1e30f; int bi = 0x7fffffff;
        #pragma unroll
        for (int i = 0; i < 8; ++i) {
            const int idx = t + 256 * i;
            const float v = s[idx];
            if (v > bv || (v == bv && idx < bi)) { bv = v; bi = idx; }
        }
        #pragma unroll
        for (int m = 1; m < 64; m <<= 1) {
            const float ov = __shfl_xor(bv, m);
            const int   oi = __shfl_xor(bi, m);
            if (ov > bv || (ov == bv && oi < bi)) { bv = ov; bi = oi; }
        }
        if ((t & 63) == 0) { bwv[t >> 6] = bv; bwi[t >> 6] = bi; }
        __syncthreads();
        if (t == 0) {
            float vv = bwv[0]; int ii = bwi[0];
            for (int w = 1; w < 4; ++w)
                if (bwv[w] > vv || (bwv[w] == vv && bwi[w] < ii)) { vv = bwv[w]; ii = bwi[w]; }
            selv[it] = vv; seli[it] = ii; s[ii] = -1e30f;
        }
        __syncthreads();
    }
    if (t == 0) {
        const float m = selv[0];
        float sum = 0.f;
        for (int k = 0; k < 20; ++k) { selv[k] = expf(selv[k] - m); sum += selv[k]; }
        const float inv = 1.f / sum;
        for (int k = 0; k < 20; ++k) selv[k] *= inv;
    }
    __syncthreads();
    if (t < 20) {
        const long base = (((long)(bbase + bl)) * N2 + n) * 20;
        topw[base + t] = selv[t];
        topi[base + t] = seli[t];
    }
}

// G[b][c][n] = sum_k w_k * yT[b][idx_k][c]
__global__ __launch_bounds__(256) void aggK(const float* __restrict__ yT,
    const float* __restrict__ topw, const int* __restrict__ topi,
    float* __restrict__ G)
{
    __shared__ float tile[128][33];
    const int t = threadIdx.x;
    const int c = t & 127;
    const int h = t >> 7;                    // 0/1
    const int n0 = blockIdx.x * 32;
    const int b  = blockIdx.y;
    for (int j = 0; j < 16; ++j) {
        const int n = n0 + 2 * j + h;
        const long tb = ((long)b * N2 + n) * 20;
        float a = 0.f;
        for (int k = 0; k < 20; ++k) {
            const float w = topw[tb + k];
            const int idx = topi[tb + k];
            a = fmaf(w, yT[((long)b * N2 + idx) * 128 + c], a);
        }
        tile[c][2 * j + h] = a;
    }
    __syncthreads();
    const int nl = t & 31;
    const int cb = t >> 5;                   // 0..7
    #pragma unroll
    for (int i = 0; i < 16; ++i) {
        const int cc = cb + 8 * i;
        G[((long)b * 128 + cc) * N2 + n0 + nl] = tile[cc][nl];
    }
}

// GroupNorm stats: per (b, g) mean & rsqrt(var+eps) over (C/32)*2048 elems
__global__ __launch_bounds__(256) void gnstatK(const float* __restrict__ pre,
    float* __restrict__ stats, int C)
{
    const int g = blockIdx.x, b = blockIdx.y;
    const int cpg = C >> 5;
    const long base = ((long)b * C + (long)g * cpg) * N2;
    const int sz = cpg * N2;
    const int t = threadIdx.x;
    float s1 = 0.f, s2 = 0.f;
    for (int i = t; i < sz; i += 256) {
        const float v = pre[base + i];
        s1 += v; s2 = fmaf(v, v, s2);
    }
    #pragma unroll
    for (int m = 1; m < 64; m <<= 1) { s1 += __shfl_xor(s1, m); s2 += __shfl_xor(s2, m); }
    __shared__ float r1[4], r2[4];
    if ((t & 63) == 0) { r1[t >> 6] = s1; r2[t >> 6] = s2; }
    __syncthreads();
    if (t == 0) {
        s1 = r1[0] + r1[1] + r1[2] + r1[3];
        s2 = r2[0] + r2[1] + r2[2] + r2[3];
        const float mu = s1 / sz;
        const float var = s2 / sz - mu * mu;
        stats[(b * 32 + g) * 2]     = mu;
        stats[(b * 32 + g) * 2 + 1] = rsqrtf(var + 1e-5f);
    }
}

// GN apply + activation. ACT: 0 = lrelu, 1 = relu
template<int ACT>
__global__ void gnapplyK(const float* __restrict__ pre, const float* __restrict__ stats,
    const float* __restrict__ gamma, const float* __restrict__ beta,
    float* __restrict__ out, int C)
{
    const long idx = ((long)blockIdx.x * 256 + threadIdx.x) * 4;
    const int cpg = C >> 5;
    const long cn = (long)C * N2;
    const int b = (int)(idx / cn);
    const long rem = idx - (long)b * cn;
    const int c = (int)(rem / N2);
    const int g = c / cpg;
    const float mu = stats[(b * 32 + g) * 2];
    const float rs = stats[(b * 32 + g) * 2 + 1];
    const float sc = rs * gamma[c];
    const float sh = beta[c] - mu * sc;
    float4 v = *(const float4*)(pre + idx);
    float r[4] = {v.x, v.y, v.z, v.w};
    #pragma unroll
    for (int j = 0; j < 4; ++j) {
        float x = r[j] * sc + sh;
        if (ACT == 0) x = (x >= 0.f) ? x : LRELU_S * x;
        else          x = (x >= 0.f) ? x : 0.f;
        r[j] = x;
    }
    float4 o; o.x = r[0]; o.y = r[1]; o.z = r[2]; o.w = r[3];
    *(float4*)(out + idx) = o;
}

// global max + mean pooling over n for local_concat [B][512][2048]
__global__ void poolK(const float* __restrict__ lc, float* __restrict__ outgv)
{
    const int t = threadIdx.x;
    const int lane = t & 63;
    const int sub = t >> 6;
    const int c = blockIdx.x * 4 + sub;
    const int b = blockIdx.y;
    const float* base = lc + ((long)b * 512 + c) * N2;
    float mx = -1e30f, sm = 0.f;
    for (int i = 0; i < 32; ++i) {
        const float v = base[lane + 64 * i];
        mx = fmaxf(mx, v); sm += v;
    }
    #pragma unroll
    for (int m = 1; m < 64; m <<= 1) {
        mx = fmaxf(mx, __shfl_xor(mx, m));
        sm += __shfl_xor(sm, m);
    }
    if (lane == 0) {
        outgv[b * 1024 + c]       = mx;
        outgv[b * 1024 + 512 + c] = sm * (1.f / 2048.f);
    }
}

// ---------------------------------------------------------------------------
extern "C" void kernel_launch(void* const* d_in, const int* in_sizes, int n_in,
                              void* d_out, int out_size, void* d_ws, size_t ws_size,
                              hipStream_t stream)
{
    const float* x1    = (const float*)d_in[0];
    const float* x2    = (const float*)d_in[1];
    const float* x3    = (const float*)d_in[2];
    const float* y3    = (const float*)d_in[3];
    const float* w4    = (const float*)d_in[4];
    const float* bn4g  = (const float*)d_in[5];
    const float* bn4b  = (const float*)d_in[6];
    const float* w5    = (const float*)d_in[7];
    const float* gn5g  = (const float*)d_in[8];
    const float* gn5b  = (const float*)d_in[9];
    const float* wm1   = (const float*)d_in[10];
    const float* bm1   = (const float*)d_in[11];
    const float* gn6g  = (const float*)d_in[12];
    const float* gn6b  = (const float*)d_in[13];
    const float* wm2   = (const float*)d_in[14];
    const float* bm2   = (const float*)d_in[15];
    const float* gn7g  = (const float*)d_in[16];
    const float* gn7b  = (const float*)d_in[17];
    const float* wm3   = (const float*)d_in[18];
    const float* bm3   = (const float*)d_in[19];
    const float* gn8g  = (const float*)d_in[20];
    const float* gn8b  = (const float*)d_in[21];
    float* out = (float*)d_out;

    // ---- workspace arena (~137 MB) ----
    char* ws = (char*)d_ws;
    size_t off = 0;
    auto alloc = [&](size_t bytes) { size_t o = off; off += (bytes + 255) & ~(size_t)255; return o; };
    float* bufA  = (float*)(ws + alloc((size_t)2 * 2048 * 2048 * 4)); // simi chunks / c5pre / h1pre / embpre
    float* bufB  = (float*)(ws + alloc((size_t)8 * 512 * 2048 * 4)); // lc / h2pre
    float* bufC  = (float*)(ws + alloc((size_t)8 * 512 * 2048 * 4)); // h1 / h2
    float* x4b   = (float*)(ws + alloc((size_t)8 * 256 * 2048 * 4));
    float* Gb    = (float*)(ws + alloc((size_t)8 * 128 * 2048 * 4));
    float* yT    = (float*)(ws + alloc((size_t)8 * 2048 * 128 * 4));
    float* invnx = (float*)(ws + alloc((size_t)8 * 2048 * 4));
    float* invny = (float*)(ws + alloc((size_t)8 * 2048 * 4));
    float* topw  = (float*)(ws + alloc((size_t)8 * 2048 * 20 * 4));
    int*   topi  = (int*)  (ws + alloc((size_t)8 * 2048 * 20 * 4));
    float* w4p   = (float*)(ws + alloc((size_t)256 * 256 * 4));
    float* stats = (float*)(ws + alloc((size_t)8 * 32 * 2 * 4));
    (void)ws_size; (void)in_sizes; (void)n_in; (void)out_size;

    const dim3 B256(256);

    // 1. norms, transpose, folded W4'
    normK<<<dim3(8, 8, 2), B256, 0, stream>>>(x3, y3, invnx, invny);
    transK<<<dim3(32, 8), B256, 0, stream>>>(y3, yT);
    w4pK<<<dim3(256), B256, 0, stream>>>(w4, w4p);

    // 2. simi + topk, 2 batches per chunk (bufA reused)
    for (int ch = 0; ch < 4; ++ch) {
        gemmK<1, 1, 0><<<dim3(16, 16, 2), B256, 0, stream>>>(
            x3, invnx, y3, invny, nullptr, nullptr, nullptr, nullptr,
            nullptr, nullptr, bufA, (long)2048 * 2048, 128, ch * 2);
        topkK<<<dim3(2048, 2), B256, 0, stream>>>(bufA, topw, topi, ch * 2);
    }

    // 3. gather-aggregate G = sum_k w*yT[idx]
    aggK<<<dim3(64, 8), B256, 0, stream>>>(yT, topw, topi, Gb);

    // 4. conv4 (+BN eval + lrelu) over virtual concat [x3 | G] with folded W4'
    gemmK<0, 3, 1><<<dim3(16, 2, 8), B256, 0, stream>>>(
        w4p, nullptr, nullptr, nullptr, nullptr, nullptr, x3, Gb,
        bn4g, bn4b, x4b, (long)256 * 2048, 256, 0);

    // 5. conv5 over virtual concat [x1|x2|x3|x4] -> c5pre (bufA)
    gemmK<0, 2, 0><<<dim3(16, 4, 8), B256, 0, stream>>>(
        w5, nullptr, nullptr, nullptr, x1, x2, x3, x4b,
        nullptr, nullptr, bufA, (long)512 * 2048, 512, 0);
    gnstatK<<<dim3(32, 8), B256, 0, stream>>>(bufA, stats, 512);
    gnapplyK<0><<<dim3(8192), B256, 0, stream>>>(bufA, stats, gn5g, gn5b, bufB, 512); // lc

    // 6. global pooling -> gv section of output
    poolK<<<dim3(128, 8), B256, 0, stream>>>(bufB, out + (long)8 * 128 * 2048);

    // 7. mlp1: wm1 + bm1 -> h1pre (bufA), GN6 + relu -> h1 (bufC)
    gemmK<0, 0, 2><<<dim3(16, 4, 8), B256, 0, stream>>>(
        wm1, nullptr, bufB, nullptr, nullptr, nullptr, nullptr, nullptr,
        nullptr, bm1, bufA, (long)512 * 2048, 512, 0);
    gnstatK<<<dim3(32, 8), B256, 0, stream>>>(bufA, stats, 512);
    gnapplyK<1><<<dim3(8192), B256, 0, stream>>>(bufA, stats, gn6g, gn6b, bufC, 512);

    // 8. mlp2: wm2 + bm2 -> h2pre (bufB), GN7 + relu -> h2 (bufC)
    gemmK<0, 0, 2><<<dim3(16, 2, 8), B256, 0, stream>>>(
        wm2, nullptr, bufC, nullptr, nullptr, nullptr, nullptr, nullptr,
        nullptr, bm2, bufB, (long)256 * 2048, 512, 0);
    gnstatK<<<dim3(32, 8), B256, 0, stream>>>(bufB, stats, 256);
    gnapplyK<1><<<dim3(4096), B256, 0, stream>>>(bufB, stats, gn7g, gn7b, bufC, 256);

    // 9. mlp3: wm3 + bm3 -> embpre (bufA), GN8 + relu -> emb (d_out)
    gemmK<0, 0, 2><<<dim3(16, 1, 8), B256, 0, stream>>>(
        wm3, nullptr, bufC, nullptr, nullptr, nullptr, nullptr, nullptr,
        nullptr, bm3, bufA, (long)128 * 2048, 256, 0);
    gnstatK<<<dim3(32, 8), B256, 0, stream>>>(bufA, stats, 128);
    gnapplyK<1><<<dim3(2048), B256, 0, stream>>>(bufA, stats, gn8g, gn8b, out, 128);
}

// Round 3
// 1063.936 us; speedup vs baseline: 1.1328x; 1.1328x over previous
//
#include <hip/hip_runtime.h>
#include <math.h>

#define N2 2048
#define LRELU_S 0.2f
#define BN4_RS 0.9999950000374997f   // rsqrt(1+1e-5)

typedef short bf16x8 __attribute__((ext_vector_type(8)));
typedef float f32x16 __attribute__((ext_vector_type(16)));

__device__ __forceinline__ unsigned short bhi(float v) { return (unsigned short)(__float_as_uint(v) >> 16); }
__device__ __forceinline__ float bhif(float v) { return __uint_as_float(__float_as_uint(v) & 0xFFFF0000u); }
__device__ __forceinline__ float bf2f(unsigned short u) { return __uint_as_float(((unsigned int)u) << 16); }

__device__ __forceinline__ void gl16(const void* g, void* l) {
    __builtin_amdgcn_global_load_lds((const __attribute__((address_space(1))) unsigned int*)g,
                                     (__attribute__((address_space(3))) unsigned int*)l, 16, 0, 0);
}

__device__ __forceinline__ f32x16 z16() {
    f32x16 v;
    #pragma unroll
    for (int i = 0; i < 16; ++i) v[i] = 0.f;
    return v;
}

#define MFMA32 __builtin_amdgcn_mfma_f32_32x32x16_bf16

// ---------------------------------------------------------------------------
// Split-bf16 3-pass MFMA GEMM.  out[bz][n][o] = sum_k A[b][n][k] * B[o][k]
// A sources are [B*2048][CA] hi/lo bf16 (activation layout, k contiguous).
// B is [O][Ktot] hi/lo bf16 (weight layout, k contiguous; bBs = batch stride for yn).
// ASRC: 0 single (a1, stride CA); 1 cat2 (x3t 128 | G 128); 2 cat4 (x1 64|x2 64|x3 128|x4 256)
// EPI:  0 fp32 store; 1 bn4-scale+bias+lrelu -> split hi/lo store; 2 +bias fp32 store + colsum atomics
// Tile: 128(M=n) x 128(N=o) x BK=32, 4 waves as 2x2 of 64x64, 32x32x16 MFMA.
// ---------------------------------------------------------------------------
template<int ASRC, int EPI>
__global__ __launch_bounds__(256) void mgemm(
    const unsigned short* __restrict__ a1H, const unsigned short* __restrict__ a1L, int CA,
    const unsigned short* __restrict__ a2H, const unsigned short* __restrict__ a2L,
    const unsigned short* __restrict__ a3H, const unsigned short* __restrict__ a3L,
    const unsigned short* __restrict__ a4H, const unsigned short* __restrict__ a4L,
    const unsigned short* __restrict__ bH,  const unsigned short* __restrict__ bL, long bBs,
    int Ktot, int OC, int bbase,
    float* __restrict__ outF,
    unsigned short* __restrict__ oH, unsigned short* __restrict__ oL,
    const float* __restrict__ epg, const float* __restrict__ epb,
    float* __restrict__ cs1, float* __restrict__ cs2)
{
    __shared__ alignas(16) unsigned short lAh[4096], lAl[4096], lBh[4096], lBl[4096];
    const int t  = threadIdx.x;
    const int n0 = blockIdx.x * 128;
    const int o0 = blockIdx.y * 128;
    const int bz = blockIdx.z;
    const int b  = bbase + bz;

    const int lane = t & 63;
    const int h    = lane >> 5;
    const int l31  = lane & 31;
    const int wid  = t >> 6;
    const int wm   = wid >> 1;
    const int wn   = wid & 1;
    const int sw   = (l31 >> 1) & 3;            // LDS chunk swizzle for frag reads

    f32x16 acc00 = z16(), acc01 = z16(), acc10 = z16(), acc11 = z16();

    // staging chunk ids (16B each); wave-consecutive lanes -> consecutive LDS chunks
    const int q0 = t, q1 = t + 256;
    const int r0 = q0 >> 2, p0 = q0 & 3, c0s = p0 ^ ((r0 >> 1) & 3);
    const int r1 = q1 >> 2, p1 = q1 & 3, c1s = p1 ^ ((r1 >> 1) & 3);

    // frag read row bases (ushort index)
    const int rA0 = (wm * 64 + l31) * 32, rA1 = rA0 + 1024;
    const int rB0 = (wn * 64 + l31) * 32, rB1 = rB0 + 1024;

    for (int kc = 0; kc < Ktot; kc += 32) {
        const unsigned short *sAH, *sAL; int koff, Cs;
        if (ASRC == 0)      { sAH = a1H; sAL = a1L; koff = kc;       Cs = CA; }
        else if (ASRC == 1) {
            if (kc < 128)   { sAH = a1H; sAL = a1L; koff = kc;       Cs = 128; }
            else            { sAH = a2H; sAL = a2L; koff = kc - 128; Cs = 128; }
        } else {
            if (kc < 64)        { sAH = a1H; sAL = a1L; koff = kc;       Cs = 64;  }
            else if (kc < 128)  { sAH = a2H; sAL = a2L; koff = kc - 64;  Cs = 64;  }
            else if (kc < 256)  { sAH = a3H; sAL = a3L; koff = kc - 128; Cs = 128; }
            else                { sAH = a4H; sAL = a4L; koff = kc - 256; Cs = 256; }
        }
        __syncthreads();
        {
            long ga = ((long)b * N2 + n0 + r0) * Cs + koff + c0s * 8;
            gl16(sAH + ga, lAh + q0 * 8);
            gl16(sAL + ga, lAl + q0 * 8);
            long gb = (long)b * bBs + (long)(o0 + r0) * Ktot + kc + c0s * 8;
            gl16(bH + gb, lBh + q0 * 8);
            gl16(bL + gb, lBl + q0 * 8);
            ga = ((long)b * N2 + n0 + r1) * Cs + koff + c1s * 8;
            gl16(sAH + ga, lAh + q1 * 8);
            gl16(sAL + ga, lAl + q1 * 8);
            gb = (long)b * bBs + (long)(o0 + r1) * Ktot + kc + c1s * 8;
            gl16(bH + gb, lBh + q1 * 8);
            gl16(bL + gb, lBl + q1 * 8);
        }
        __syncthreads();
        #pragma unroll
        for (int s = 0; s < 2; ++s) {
            const int off = ((s * 2 + h) ^ sw) * 8;
            bf16x8 a0h = *(const bf16x8*)(lAh + rA0 + off);
            bf16x8 a0l = *(const bf16x8*)(lAl + rA0 + off);
            bf16x8 a1h_ = *(const bf16x8*)(lAh + rA1 + off);
            bf16x8 a1l_ = *(const bf16x8*)(lAl + rA1 + off);
            bf16x8 b0h = *(const bf16x8*)(lBh + rB0 + off);
            bf16x8 b0l = *(const bf16x8*)(lBl + rB0 + off);
            bf16x8 b1h = *(const bf16x8*)(lBh + rB1 + off);
            bf16x8 b1l = *(const bf16x8*)(lBl + rB1 + off);
            acc00 = MFMA32(a0h, b0h, acc00, 0, 0, 0);
            acc01 = MFMA32(a0h, b1h, acc01, 0, 0, 0);
            acc10 = MFMA32(a1h_, b0h, acc10, 0, 0, 0);
            acc11 = MFMA32(a1h_, b1h, acc11, 0, 0, 0);
            acc00 = MFMA32(a0h, b0l, acc00, 0, 0, 0);
            acc00 = MFMA32(a0l, b0h, acc00, 0, 0, 0);
            acc01 = MFMA32(a0h, b1l, acc01, 0, 0, 0);
            acc01 = MFMA32(a0l, b1h, acc01, 0, 0, 0);
            acc10 = MFMA32(a1h_, b0l, acc10, 0, 0, 0);
            acc10 = MFMA32(a1l_, b0h, acc10, 0, 0, 0);
            acc11 = MFMA32(a1h_, b1l, acc11, 0, 0, 0);
            acc11 = MFMA32(a1l_, b1h, acc11, 0, 0, 0);
        }
    }

    // epilogue: D col = lane&31 (o), row = (r&3) + 8*(r>>2) + 4*h (+ mi*32 + wm*64)
    #pragma unroll
    for (int ni = 0; ni < 2; ++ni) {
        const int o = o0 + wn * 64 + ni * 32 + l31;
        float sc = 0.f, sh = 0.f, bias = 0.f;
        if (EPI == 1) { sc = epg[o] * BN4_RS; sh = epb[o]; }
        if (EPI == 2) { bias = epb ? epb[o] : 0.f; }
        float s1 = 0.f, s2 = 0.f;
        #pragma unroll
        for (int mi = 0; mi < 2; ++mi) {
            #pragma unroll
            for (int r = 0; r < 16; ++r) {
                const int n = n0 + wm * 64 + mi * 32 + (r & 3) + 8 * (r >> 2) + 4 * h;
                float v = (ni == 0) ? (mi == 0 ? acc00[r] : acc10[r])
                                    : (mi == 0 ? acc01[r] : acc11[r]);
                const long oi = ((long)bz * N2 + n) * (long)OC + o;
                if (EPI == 0) {
                    outF[oi] = v;
                } else if (EPI == 1) {
                    v = fmaf(v, sc, sh);
                    v = v >= 0.f ? v : LRELU_S * v;
                    oH[oi] = bhi(v); oL[oi] = bhi(v - bhif(v));
                } else {
                    v += bias;
                    outF[oi] = v;
                    s1 += v; s2 = fmaf(v, v, s2);
                }
            }
        }
        if (EPI == 2) {
            s1 += __shfl_xor(s1, 32);
            s2 += __shfl_xor(s2, 32);
            if (h == 0) {
                atomicAdd(cs1 + bz * OC + o, s1);
                atomicAdd(cs2 + bz * OC + o, s2);
            }
        }
    }
}

// ---------------------------------------------------------------------------
// inverse norms over C=128 channels for x3 (z=0) and y3 (z=1)
__global__ void normK(const float* __restrict__ x3, const float* __restrict__ y3,
                      float* __restrict__ invnx, float* __restrict__ invny)
{
    const int n = blockIdx.x * 256 + threadIdx.x;
    const int b = blockIdx.y;
    const float* src = blockIdx.z ? y3 : x3;
    float ss = 0.f;
    for (int c = 0; c < 128; ++c) {
        float v = src[((long)b * 128 + c) * N2 + n];
        ss = fmaf(v, v, ss);
    }
    (blockIdx.z ? invny : invnx)[b * N2 + n] = rsqrtf(ss);
}

// ---------------------------------------------------------------------------
// transpose [C][2048] -> [2048][C] with bf16 split.  MODE bits:
//  1 = write unscaled hi/lo; 2 = write invn-scaled hi/lo; 4 = write fp32 transposed
template<int MODE>
__global__ __launch_bounds__(256) void tsplitK(
    const float* __restrict__ in, int C,
    unsigned short* __restrict__ tHi, unsigned short* __restrict__ tLo,
    const float* __restrict__ invn,
    unsigned short* __restrict__ sHi, unsigned short* __restrict__ sLo,
    float* __restrict__ tF)
{
    __shared__ float lt[64 * 65];
    const int t = threadIdx.x;
    const int n0 = blockIdx.x * 64, c0 = blockIdx.y * 64, b = blockIdx.z;
    {
        const int nl = t & 63;
        const int cb = t >> 6;
        #pragma unroll
        for (int i = 0; i < 16; ++i) {
            const int cl = cb + 4 * i;
            lt[nl * 65 + cl] = in[((long)b * C + c0 + cl) * N2 + n0 + nl];
        }
    }
    __syncthreads();
    const int cl = t & 63;
    const int nb = t >> 6;
    #pragma unroll
    for (int i = 0; i < 16; ++i) {
        const int nl = nb + 4 * i;
        const float v = lt[nl * 65 + cl];
        const long oi = ((long)b * N2 + n0 + nl) * C + c0 + cl;
        if (MODE & 1) { tHi[oi] = bhi(v); tLo[oi] = bhi(v - bhif(v)); }
        if (MODE & 2) {
            const float svv = v * invn[b * N2 + n0 + nl];
            sHi[oi] = bhi(svv); sLo[oi] = bhi(svv - bhif(svv));
        }
        if (MODE & 4) tF[oi] = v;
    }
}

// ---------------------------------------------------------------------------
// weight fold (w4) + bf16 split for all 5 weight tensors; blockIdx.y selects
__global__ void wsplitK(const float* __restrict__ w4, const float* __restrict__ w5,
    const float* __restrict__ wm1, const float* __restrict__ wm2, const float* __restrict__ wm3,
    unsigned short* __restrict__ w4h, unsigned short* __restrict__ w4l,
    unsigned short* __restrict__ w5h, unsigned short* __restrict__ w5l,
    unsigned short* __restrict__ m1h, unsigned short* __restrict__ m1l,
    unsigned short* __restrict__ m2h, unsigned short* __restrict__ m2l,
    unsigned short* __restrict__ m3h, unsigned short* __restrict__ m3l)
{
    const int y = blockIdx.y;
    const int idx = blockIdx.x * 256 + threadIdx.x;
    float v; unsigned short *dh, *dl;
    if (y == 0) {
        if (idx >= 256 * 256) return;
        const int k = idx & 255;
        v = w4[idx];
        if (k < 128) v -= w4[idx + 128];
        dh = w4h; dl = w4l;
    } else if (y == 1) {
        if (idx >= 512 * 512) return;
        v = w5[idx]; dh = w5h; dl = w5l;
    } else if (y == 2) {
        if (idx >= 512 * 512) return;
        v = wm1[idx]; dh = m1h; dl = m1l;
    } else if (y == 3) {
        if (idx >= 256 * 512) return;
        v = wm2[idx]; dh = m2h; dl = m2l;
    } else {
        if (idx >= 128 * 256) return;
        v = wm3[idx]; dh = m3h; dl = m3l;
    }
    dh[idx] = bhi(v); dl[idx] = bhi(v - bhif(v));
}

// ---------------------------------------------------------------------------
// top-20 of a 2048 simi row + softmax weights (simi layout [bl][n][m])
__global__ __launch_bounds__(256) void topkK(const float* __restrict__ simi,
    float* __restrict__ topw, int* __restrict__ topi, int bbase)
{
    __shared__ float s[2048];
    __shared__ float bwv[4]; __shared__ int bwi[4];
    __shared__ float selv[20]; __shared__ int seli[20];
    const int t = threadIdx.x;
    const int n = blockIdx.x;
    const int bl = blockIdx.y;
    const float* row = simi + ((long)bl * N2 + n) * N2;
    #pragma unroll
    for (int i = 0; i < 8; ++i) s[t + 256 * i] = row[t + 256 * i];
    __syncthreads();
    for (int it = 0; it < 20; ++it) {
        float bv = -1e30f; int bi = 0x7fffffff;
        #pragma unroll
        for (int i = 0; i < 8; ++i) {
            const int idx = t + 256 * i;
            const float v = s[idx];
            if (v > bv || (v == bv && idx < bi)) { bv = v; bi = idx; }
        }
        #pragma unroll
        for (int m = 1; m < 64; m <<= 1) {
            const float ov = __shfl_xor(bv, m);
            const int   oi = __shfl_xor(bi, m);
            if (ov > bv || (ov == bv && oi < bi)) { bv = ov; bi = oi; }
        }
        if ((t & 63) == 0) { bwv[t >> 6] = bv; bwi[t >> 6] = bi; }
        __syncthreads();
        if (t == 0) {
            float vv = bwv[0]; int ii = bwi[0];
            for (int w = 1; w < 4; ++w)
                if (bwv[w] > vv || (bwv[w] == vv && bwi[w] < ii)) { vv = bwv[w]; ii = bwi[w]; }
            selv[it] = vv; seli[it] = ii; s[ii] = -1e30f;
        }
        __syncthreads();
    }
    if (t == 0) {
        const float m = selv[0];
        float sum = 0.f;
        for (int k = 0; k < 20; ++k) { selv[k] = expf(selv[k] - m); sum += selv[k]; }
        const float inv = 1.f / sum;
        for (int k = 0; k < 20; ++k) selv[k] *= inv;
    }
    __syncthreads();
    if (t < 20) {
        const long base = (((long)(bbase + bl)) * N2 + n) * 20;
        topw[base + t] = selv[t];
        topi[base + t] = seli[t];
    }
}

// ---------------------------------------------------------------------------
// G[n][c] = sum_k w_k * yT[idx_k][c], written as split bf16
__global__ __launch_bounds__(256) void aggK(const float* __restrict__ yT,
    const float* __restrict__ topw, const int* __restrict__ topi,
    unsigned short* __restrict__ Gh, unsigned short* __restrict__ Gl)
{
    const int t = threadIdx.x;
    const int c = t & 127, nh = t >> 7;
    const int n0 = blockIdx.x * 32;
    const int b  = blockIdx.y;
    for (int j = 0; j < 16; ++j) {
        const int n = n0 + 2 * j + nh;
        const long tb = ((long)b * N2 + n) * 20;
        float a = 0.f;
        for (int k = 0; k < 20; ++k)
            a = fmaf(topw[tb + k], yT[((long)b * N2 + topi[tb + k]) * 128 + c], a);
        const long oi = ((long)b * N2 + n) * 128 + c;
        Gh[oi] = bhi(a); Gl[oi] = bhi(a - bhif(a));
    }
}

// ---------------------------------------------------------------------------
// reduce per-column sums to per-(b,group) GN stats;  one block of 256 = 8b x 32g
__global__ void statsK(const float* __restrict__ cs1, const float* __restrict__ cs2,
    float* __restrict__ stats, int C)
{
    const int t = threadIdx.x;
    const int b = t >> 5, g = t & 31;
    const int cpg = C >> 5;
    float s1 = 0.f, s2 = 0.f;
    for (int j = 0; j < cpg; ++j) {
        s1 += cs1[b * C + g * cpg + j];
        s2 += cs2[b * C + g * cpg + j];
    }
    const float cnt = (float)(cpg * N2);
    const float mu = s1 / cnt;
    const float var = s2 / cnt - mu * mu;
    stats[t * 2] = mu;
    stats[t * 2 + 1] = rsqrtf(var + 1e-5f);
}

// ---------------------------------------------------------------------------
// GN apply + activation, fp32 [n][C] -> split bf16 [n][C].  ACT 0=lrelu 1=relu
template<int ACT, int LC>
__global__ void gnapplyK(const float* __restrict__ pre, const float* __restrict__ stats,
    const float* __restrict__ gamma, const float* __restrict__ beta,
    unsigned short* __restrict__ oH, unsigned short* __restrict__ oL)
{
    const long i4 = ((long)blockIdx.x * 256 + threadIdx.x) * 4;
    const int C = 1 << LC;
    const int c = (int)(i4 & (C - 1));
    const int bn = (int)(i4 >> LC);
    const int b = bn >> 11;
    const int g = c >> (LC - 5);
    const float mu = stats[(b * 32 + g) * 2];
    const float rs = stats[(b * 32 + g) * 2 + 1];
    const float4 gm = *(const float4*)(gamma + c);
    const float4 bt = *(const float4*)(beta + c);
    const float4 v = *(const float4*)(pre + i4);
    const float vals[4] = {v.x, v.y, v.z, v.w};
    const float gms[4] = {gm.x, gm.y, gm.z, gm.w};
    const float bts[4] = {bt.x, bt.y, bt.z, bt.w};
    unsigned short hs[4], ls[4];
    #pragma unroll
    for (int j = 0; j < 4; ++j) {
        float x = (vals[j] - mu) * (rs * gms[j]) + bts[j];
        x = (ACT == 0) ? (x >= 0.f ? x : LRELU_S * x) : (x >= 0.f ? x : 0.f);
        hs[j] = bhi(x); ls[j] = bhi(x - bhif(x));
    }
    ushort4 hh; hh.x = hs[0]; hh.y = hs[1]; hh.z = hs[2]; hh.w = hs[3];
    ushort4 ll; ll.x = ls[0]; ll.y = ls[1]; ll.z = ls[2]; ll.w = ls[3];
    *(ushort4*)(oH + i4) = hh;
    *(ushort4*)(oL + i4) = ll;
}

// ---------------------------------------------------------------------------
// final GN8 + relu + transpose to out[b][128][2048]
__global__ __launch_bounds__(256) void gnfinalK(const float* __restrict__ pre,
    const float* __restrict__ stats, const float* __restrict__ gamma,
    const float* __restrict__ beta, float* __restrict__ out)
{
    __shared__ float lt[64 * 65];
    const int t = threadIdx.x;
    const int n0 = blockIdx.x * 64, c0 = blockIdx.y * 64, b = blockIdx.z;
    {
        const int cl = t & 63;
        const int nb = t >> 6;
        const int c = c0 + cl;
        const int g = c >> 2;
        const float mu = stats[(b * 32 + g) * 2];
        const float rs = stats[(b * 32 + g) * 2 + 1];
        const float sc = rs * gamma[c], sh = beta[c] - mu * sc;
        #pragma unroll
        for (int i = 0; i < 16; ++i) {
            const int nl = nb + 4 * i;
            float v = pre[((long)b * N2 + n0 + nl) * 128 + c];
            v = v * sc + sh;
            lt[cl * 65 + nl] = v > 0.f ? v : 0.f;
        }
    }
    __syncthreads();
    const int nl = t & 63;
    const int cb = t >> 6;
    #pragma unroll
    for (int i = 0; i < 16; ++i) {
        const int cl = cb + 4 * i;
        out[((long)b * 128 + c0 + cl) * N2 + n0 + nl] = lt[cl * 65 + nl];
    }
}

// ---------------------------------------------------------------------------
// global max+mean pooling over n from split-bf16 lc [n][512]
__global__ __launch_bounds__(256) void poolK(const unsigned short* __restrict__ lcH,
    const unsigned short* __restrict__ lcL, float* __restrict__ gv)
{
    __shared__ float lmx[128], lsm[128];
    const int t = threadIdx.x;
    const int cl = t & 127;
    const int c = blockIdx.x * 128 + cl;
    const int half = t >> 7;
    const int b = blockIdx.y;
    float mx = -1e30f, sm = 0.f;
    for (int n = half; n < N2; n += 2) {
        const long i = ((long)b * N2 + n) * 512 + c;
        const float v = bf2f(lcH[i]) + bf2f(lcL[i]);
        mx = fmaxf(mx, v); sm += v;
    }
    if (half) { lmx[cl] = mx; lsm[cl] = sm; }
    __syncthreads();
    if (!half) {
        mx = fmaxf(mx, lmx[cl]); sm += lsm[cl];
        gv[b * 1024 + c] = mx;
        gv[b * 1024 + 512 + c] = sm * (1.f / 2048.f);
    }
}

// ---------------------------------------------------------------------------
extern "C" void kernel_launch(void* const* d_in, const int* in_sizes, int n_in,
                              void* d_out, int out_size, void* d_ws, size_t ws_size,
                              hipStream_t stream)
{
    const float* x1    = (const float*)d_in[0];
    const float* x2    = (const float*)d_in[1];
    const float* x3    = (const float*)d_in[2];
    const float* y3    = (const float*)d_in[3];
    const float* w4    = (const float*)d_in[4];
    const float* bn4g  = (const float*)d_in[5];
    const float* bn4b  = (const float*)d_in[6];
    const float* w5    = (const float*)d_in[7];
    const float* gn5g  = (const float*)d_in[8];
    const float* gn5b  = (const float*)d_in[9];
    const float* wm1   = (const float*)d_in[10];
    const float* bm1   = (const float*)d_in[11];
    const float* gn6g  = (const float*)d_in[12];
    const float* gn6b  = (const float*)d_in[13];
    const float* wm2   = (const float*)d_in[14];
    const float* bm2   = (const float*)d_in[15];
    const float* gn7g  = (const float*)d_in[16];
    const float* gn7b  = (const float*)d_in[17];
    const float* wm3   = (const float*)d_in[18];
    const float* bm3   = (const float*)d_in[19];
    const float* gn8g  = (const float*)d_in[20];
    const float* gn8b  = (const float*)d_in[21];
    float* out = (float*)d_out;
    (void)in_sizes; (void)n_in; (void)out_size; (void)ws_size;

    char* ws = (char*)d_ws;
    // ---- arena (aliased regions; ~124 MB total) ----
    float*          bufPS = (float*)(ws + 0);                         // 33.55 MB: simi chunks, then GEMM pre
    unsigned short* lcH   = (unsigned short*)(ws + 33554432);         // 16.78 MB
    unsigned short* lcL   = (unsigned short*)(ws + 50331648);         // 16.78 MB
    const size_t R3 = 67108864;                                       // 33.55 MB region
    float*          yT    = (float*)(ws + R3);                        //  8.39 MB
    unsigned short* x3tH  = (unsigned short*)(ws + R3 + 8388608);
    unsigned short* x3tL  = (unsigned short*)(ws + R3 + 12582912);
    unsigned short* x1tH  = (unsigned short*)(ws + R3 + 16777216);
    unsigned short* x1tL  = (unsigned short*)(ws + R3 + 18874368);
    unsigned short* x2tH  = (unsigned short*)(ws + R3 + 20971520);
    unsigned short* x2tL  = (unsigned short*)(ws + R3 + 23068672);
    unsigned short* GH    = (unsigned short*)(ws + R3 + 25165824);
    unsigned short* GL    = (unsigned short*)(ws + R3 + 29360128);
    unsigned short* h1H   = (unsigned short*)(ws + R3);               // alias (after conv5/agg/conv4 done)
    unsigned short* h1L   = (unsigned short*)(ws + R3 + 16777216);
    const size_t R4 = 100663296;                                      // 16.78 MB region
    unsigned short* xnH   = (unsigned short*)(ws + R4);
    unsigned short* xnL   = (unsigned short*)(ws + R4 + 4194304);
    unsigned short* ynH   = (unsigned short*)(ws + R4 + 8388608);
    unsigned short* ynL   = (unsigned short*)(ws + R4 + 12582912);
    unsigned short* x4H   = (unsigned short*)(ws + R4);               // alias (after simi done)
    unsigned short* x4L   = (unsigned short*)(ws + R4 + 8388608);
    unsigned short* h2H   = (unsigned short*)(ws + R4);               // alias (after conv5 done)
    unsigned short* h2L   = (unsigned short*)(ws + R4 + 8388608);
    const size_t W = 117440512;
    unsigned short* w4pH = (unsigned short*)(ws + W);
    unsigned short* w4pL = (unsigned short*)(ws + W + 131072);
    unsigned short* w5H  = (unsigned short*)(ws + W + 262144);
    unsigned short* w5L  = (unsigned short*)(ws + W + 786432);
    unsigned short* m1H  = (unsigned short*)(ws + W + 1310720);
    unsigned short* m1L  = (unsigned short*)(ws + W + 1835008);
    unsigned short* m2H  = (unsigned short*)(ws + W + 2359296);
    unsigned short* m2L  = (unsigned short*)(ws + W + 2621440);
    unsigned short* m3H  = (unsigned short*)(ws + W + 2883584);
    unsigned short* m3L  = (unsigned short*)(ws + W + 2949120);
    const size_t M = W + 3145728;
    float* invnx = (float*)(ws + M);
    float* invny = (float*)(ws + M + 65536);
    float* topw  = (float*)(ws + M + 131072);
    int*   topi  = (int*)  (ws + M + 131072 + 1310720);
    float* csb   = (float*)(ws + M + 131072 + 2621440);               // 8 x 16384 B
    float* cs1_5 = csb,          *cs2_5 = csb + 4096;
    float* cs1_6 = csb + 8192,   *cs2_6 = csb + 12288;
    float* cs1_7 = csb + 16384,  *cs2_7 = csb + 20480;
    float* cs1_8 = csb + 24576,  *cs2_8 = csb + 28672;
    float* stats5 = (float*)(ws + M + 131072 + 2621440 + 131072);
    float* stats6 = stats5 + 512;
    float* stats7 = stats5 + 1024;
    float* stats8 = stats5 + 1536;

    const dim3 B256(256);
    const unsigned short* nu = nullptr;

    // 0. zero colsum accumulators (ws is poisoned each launch)
    hipMemsetAsync(csb, 0, 131072, stream);

    // 1. norms, transposes + bf16 splits, weight folds/splits
    normK<<<dim3(8, 8, 2), B256, 0, stream>>>(x3, y3, invnx, invny);
    tsplitK<6><<<dim3(32, 2, 8), B256, 0, stream>>>(y3, 128, nullptr, nullptr, invny, ynH, ynL, yT);
    tsplitK<3><<<dim3(32, 2, 8), B256, 0, stream>>>(x3, 128, x3tH, x3tL, invnx, xnH, xnL, nullptr);
    tsplitK<1><<<dim3(32, 1, 8), B256, 0, stream>>>(x1, 64, x1tH, x1tL, nullptr, nullptr, nullptr, nullptr);
    tsplitK<1><<<dim3(32, 1, 8), B256, 0, stream>>>(x2, 64, x2tH, x2tL, nullptr, nullptr, nullptr, nullptr);
    wsplitK<<<dim3(1024, 5), B256, 0, stream>>>(w4, w5, wm1, wm2, wm3,
        w4pH, w4pL, w5H, w5L, m1H, m1L, m2H, m2L, m3H, m3L);

    // 2. simi (split-bf16 MFMA) + topk, 2 batches per chunk
    for (int ch = 0; ch < 4; ++ch) {
        mgemm<0, 0><<<dim3(16, 16, 2), B256, 0, stream>>>(
            xnH, xnL, 128, nu, nu, nu, nu, nu, nu,
            ynH, ynL, (long)N2 * 128, 128, 2048, ch * 2,
            bufPS, nullptr, nullptr, nullptr, nullptr, nullptr, nullptr);
        topkK<<<dim3(2048, 2), B256, 0, stream>>>(bufPS, topw, topi, ch * 2);
    }

    // 3. gather-aggregate G (split bf16)
    aggK<<<dim3(64, 8), B256, 0, stream>>>(yT, topw, topi, GH, GL);

    // 4. conv4 (+BN eval + lrelu) over [x3 | G] with folded W4' -> x4 hi/lo
    mgemm<1, 1><<<dim3(16, 2, 8), B256, 0, stream>>>(
        x3tH, x3tL, 128, GH, GL, nu, nu, nu, nu,
        w4pH, w4pL, 0, 256, 256, 0,
        nullptr, x4H, x4L, bn4g, bn4b, nullptr, nullptr);

    // 5. conv5 over [x1|x2|x3|x4] -> pre (bufPS) + colsums; GN5 + lrelu -> lc
    mgemm<2, 2><<<dim3(16, 4, 8), B256, 0, stream>>>(
        x1tH, x1tL, 64, x2tH, x2tL, x3tH, x3tL, x4H, x4L,
        w5H, w5L, 0, 512, 512, 0,
        bufPS, nullptr, nullptr, nullptr, nullptr, cs1_5, cs2_5);
    statsK<<<1, B256, 0, stream>>>(cs1_5, cs2_5, stats5, 512);
    gnapplyK<0, 9><<<8192, B256, 0, stream>>>(bufPS, stats5, gn5g, gn5b, lcH, lcL);

    // 6. global pooling -> gv section of output
    poolK<<<dim3(4, 8), B256, 0, stream>>>(lcH, lcL, out + (long)8 * 128 * 2048);

    // 7. mlp1 -> pre + colsums; GN6 + relu -> h1
    mgemm<0, 2><<<dim3(16, 4, 8), B256, 0, stream>>>(
        lcH, lcL, 512, nu, nu, nu, nu, nu, nu,
        m1H, m1L, 0, 512, 512, 0,
        bufPS, nullptr, nullptr, nullptr, bm1, cs1_6, cs2_6);
    statsK<<<1, B256, 0, stream>>>(cs1_6, cs2_6, stats6, 512);
    gnapplyK<1, 9><<<8192, B256, 0, stream>>>(bufPS, stats6, gn6g, gn6b, h1H, h1L);

    // 8. mlp2 -> pre + colsums; GN7 + relu -> h2
    mgemm<0, 2><<<dim3(16, 2, 8), B256, 0, stream>>>(
        h1H, h1L, 512, nu, nu, nu, nu, nu, nu,
        m2H, m2L, 0, 512, 256, 0,
        bufPS, nullptr, nullptr, nullptr, bm2, cs1_7, cs2_7);
    statsK<<<1, B256, 0, stream>>>(cs1_7, cs2_7, stats7, 256);
    gnapplyK<1, 8><<<4096, B256, 0, stream>>>(bufPS, stats7, gn7g, gn7b, h2H, h2L);

    // 9. mlp3 -> pre + colsums; GN8 + relu + transpose -> emb (d_out)
    mgemm<0, 2><<<dim3(16, 1, 8), B256, 0, stream>>>(
        h2H, h2L, 256, nu, nu, nu, nu, nu, nu,
        m3H, m3L, 0, 256, 128, 0,
        bufPS, nullptr, nullptr, nullptr, bm3, cs1_8, cs2_8);
    statsK<<<1, B256, 0, stream>>>(cs1_8, cs2_8, stats8, 128);
    gnfinalK<<<dim3(32, 2, 8), B256, 0, stream>>>(bufPS, stats8, gn8g, gn8b, out);
}

// Round 4
// 810.200 us; speedup vs baseline: 1.4875x; 1.3132x over previous
//
#include <hip/hip_runtime.h>
#include <math.h>

#define N2 2048
#define LRELU_S 0.2f
#define BN4_RS 0.9999950000374997f   // rsqrt(1+1e-5)

typedef short bf16x8 __attribute__((ext_vector_type(8)));
typedef float f32x16 __attribute__((ext_vector_type(16)));

__device__ __forceinline__ unsigned short bhi(float v) { return (unsigned short)(__float_as_uint(v) >> 16); }
__device__ __forceinline__ float bhif(float v) { return __uint_as_float(__float_as_uint(v) & 0xFFFF0000u); }
__device__ __forceinline__ float bf2f(unsigned short u) { return __uint_as_float(((unsigned int)u) << 16); }

__device__ __forceinline__ void gl16(const void* g, void* l) {
    __builtin_amdgcn_global_load_lds((const __attribute__((address_space(1))) unsigned int*)g,
                                     (__attribute__((address_space(3))) unsigned int*)l, 16, 0, 0);
}

__device__ __forceinline__ f32x16 z16() {
    f32x16 v;
    #pragma unroll
    for (int i = 0; i < 16; ++i) v[i] = 0.f;
    return v;
}

#define MFMA32 __builtin_amdgcn_mfma_f32_32x32x16_bf16

// ---------------------------------------------------------------------------
// Split-bf16 3-pass MFMA GEMM.  out[bz][n][o] = sum_k A[b][n][k] * B[o][k]
// A sources are [B*2048][CA] hi/lo bf16 (activation layout, k contiguous).
// B is [O][Ktot] hi/lo bf16 (weight layout, k contiguous; bBs = batch stride for yn).
// ASRC: 0 single (a1, stride CA); 1 cat2 (x3t 128 | G 128); 2 cat4 (x1 64|x2 64|x3 128|x4 256)
// EPI:  0 fp32 store; 1 bn4-scale+bias+lrelu -> split hi/lo store; 2 +bias fp32 store + colsum atomics
// Tile: 128(M=n) x 128(N=o) x BK=32, 4 waves as 2x2 of 64x64, 32x32x16 MFMA.
// ---------------------------------------------------------------------------
template<int ASRC, int EPI>
__global__ __launch_bounds__(256) void mgemm(
    const unsigned short* __restrict__ a1H, const unsigned short* __restrict__ a1L, int CA,
    const unsigned short* __restrict__ a2H, const unsigned short* __restrict__ a2L,
    const unsigned short* __restrict__ a3H, const unsigned short* __restrict__ a3L,
    const unsigned short* __restrict__ a4H, const unsigned short* __restrict__ a4L,
    const unsigned short* __restrict__ bH,  const unsigned short* __restrict__ bL, long bBs,
    int Ktot, int OC, int bbase,
    float* __restrict__ outF,
    unsigned short* __restrict__ oH, unsigned short* __restrict__ oL,
    const float* __restrict__ epg, const float* __restrict__ epb,
    float* __restrict__ cs1, float* __restrict__ cs2)
{
    __shared__ alignas(16) unsigned short lAh[4096], lAl[4096], lBh[4096], lBl[4096];
    const int t  = threadIdx.x;
    const int n0 = blockIdx.x * 128;
    const int o0 = blockIdx.y * 128;
    const int bz = blockIdx.z;
    const int b  = bbase + bz;

    const int lane = t & 63;
    const int h    = lane >> 5;
    const int l31  = lane & 31;
    const int wid  = t >> 6;
    const int wm   = wid >> 1;
    const int wn   = wid & 1;
    const int sw   = (l31 >> 1) & 3;            // LDS chunk swizzle for frag reads

    f32x16 acc00 = z16(), acc01 = z16(), acc10 = z16(), acc11 = z16();

    // staging chunk ids (16B each); wave-consecutive lanes -> consecutive LDS chunks
    const int q0 = t, q1 = t + 256;
    const int r0 = q0 >> 2, p0 = q0 & 3, c0s = p0 ^ ((r0 >> 1) & 3);
    const int r1 = q1 >> 2, p1 = q1 & 3, c1s = p1 ^ ((r1 >> 1) & 3);

    // frag read row bases (ushort index)
    const int rA0 = (wm * 64 + l31) * 32, rA1 = rA0 + 1024;
    const int rB0 = (wn * 64 + l31) * 32, rB1 = rB0 + 1024;

    for (int kc = 0; kc < Ktot; kc += 32) {
        const unsigned short *sAH, *sAL; int koff, Cs;
        if (ASRC == 0)      { sAH = a1H; sAL = a1L; koff = kc;       Cs = CA; }
        else if (ASRC == 1) {
            if (kc < 128)   { sAH = a1H; sAL = a1L; koff = kc;       Cs = 128; }
            else            { sAH = a2H; sAL = a2L; koff = kc - 128; Cs = 128; }
        } else {
            if (kc < 64)        { sAH = a1H; sAL = a1L; koff = kc;       Cs = 64;  }
            else if (kc < 128)  { sAH = a2H; sAL = a2L; koff = kc - 64;  Cs = 64;  }
            else if (kc < 256)  { sAH = a3H; sAL = a3L; koff = kc - 128; Cs = 128; }
            else                { sAH = a4H; sAL = a4L; koff = kc - 256; Cs = 256; }
        }
        __syncthreads();
        {
            long ga = ((long)b * N2 + n0 + r0) * Cs + koff + c0s * 8;
            gl16(sAH + ga, lAh + q0 * 8);
            gl16(sAL + ga, lAl + q0 * 8);
            long gb = (long)b * bBs + (long)(o0 + r0) * Ktot + kc + c0s * 8;
            gl16(bH + gb, lBh + q0 * 8);
            gl16(bL + gb, lBl + q0 * 8);
            ga = ((long)b * N2 + n0 + r1) * Cs + koff + c1s * 8;
            gl16(sAH + ga, lAh + q1 * 8);
            gl16(sAL + ga, lAl + q1 * 8);
            gb = (long)b * bBs + (long)(o0 + r1) * Ktot + kc + c1s * 8;
            gl16(bH + gb, lBh + q1 * 8);
            gl16(bL + gb, lBl + q1 * 8);
        }
        __syncthreads();
        #pragma unroll
        for (int s = 0; s < 2; ++s) {
            const int off = ((s * 2 + h) ^ sw) * 8;
            bf16x8 a0h = *(const bf16x8*)(lAh + rA0 + off);
            bf16x8 a0l = *(const bf16x8*)(lAl + rA0 + off);
            bf16x8 a1h_ = *(const bf16x8*)(lAh + rA1 + off);
            bf16x8 a1l_ = *(const bf16x8*)(lAl + rA1 + off);
            bf16x8 b0h = *(const bf16x8*)(lBh + rB0 + off);
            bf16x8 b0l = *(const bf16x8*)(lBl + rB0 + off);
            bf16x8 b1h = *(const bf16x8*)(lBh + rB1 + off);
            bf16x8 b1l = *(const bf16x8*)(lBl + rB1 + off);
            acc00 = MFMA32(a0h, b0h, acc00, 0, 0, 0);
            acc01 = MFMA32(a0h, b1h, acc01, 0, 0, 0);
            acc10 = MFMA32(a1h_, b0h, acc10, 0, 0, 0);
            acc11 = MFMA32(a1h_, b1h, acc11, 0, 0, 0);
            acc00 = MFMA32(a0h, b0l, acc00, 0, 0, 0);
            acc00 = MFMA32(a0l, b0h, acc00, 0, 0, 0);
            acc01 = MFMA32(a0h, b1l, acc01, 0, 0, 0);
            acc01 = MFMA32(a0l, b1h, acc01, 0, 0, 0);
            acc10 = MFMA32(a1h_, b0l, acc10, 0, 0, 0);
            acc10 = MFMA32(a1l_, b0h, acc10, 0, 0, 0);
            acc11 = MFMA32(a1h_, b1l, acc11, 0, 0, 0);
            acc11 = MFMA32(a1l_, b1h, acc11, 0, 0, 0);
        }
    }

    // epilogue: D col = lane&31 (o), row = (r&3) + 8*(r>>2) + 4*h (+ mi*32 + wm*64)
    #pragma unroll
    for (int ni = 0; ni < 2; ++ni) {
        const int o = o0 + wn * 64 + ni * 32 + l31;
        float sc = 0.f, sh = 0.f, bias = 0.f;
        if (EPI == 1) { sc = epg[o] * BN4_RS; sh = epb[o]; }
        if (EPI == 2) { bias = epb ? epb[o] : 0.f; }
        float s1 = 0.f, s2 = 0.f;
        #pragma unroll
        for (int mi = 0; mi < 2; ++mi) {
            #pragma unroll
            for (int r = 0; r < 16; ++r) {
                const int n = n0 + wm * 64 + mi * 32 + (r & 3) + 8 * (r >> 2) + 4 * h;
                float v = (ni == 0) ? (mi == 0 ? acc00[r] : acc10[r])
                                    : (mi == 0 ? acc01[r] : acc11[r]);
                const long oi = ((long)bz * N2 + n) * (long)OC + o;
                if (EPI == 0) {
                    outF[oi] = v;
                } else if (EPI == 1) {
                    v = fmaf(v, sc, sh);
                    v = v >= 0.f ? v : LRELU_S * v;
                    oH[oi] = bhi(v); oL[oi] = bhi(v - bhif(v));
                } else {
                    v += bias;
                    outF[oi] = v;
                    s1 += v; s2 = fmaf(v, v, s2);
                }
            }
        }
        if (EPI == 2) {
            s1 += __shfl_xor(s1, 32);
            s2 += __shfl_xor(s2, 32);
            if (h == 0) {
                atomicAdd(cs1 + bz * OC + o, s1);
                atomicAdd(cs2 + bz * OC + o, s2);
            }
        }
    }
}

// ---------------------------------------------------------------------------
// inverse norms over C=128 channels for x3 (z=0) and y3 (z=1)
__global__ void normK(const float* __restrict__ x3, const float* __restrict__ y3,
                      float* __restrict__ invnx, float* __restrict__ invny)
{
    const int n = blockIdx.x * 256 + threadIdx.x;
    const int b = blockIdx.y;
    const float* src = blockIdx.z ? y3 : x3;
    float ss = 0.f;
    for (int c = 0; c < 128; ++c) {
        float v = src[((long)b * 128 + c) * N2 + n];
        ss = fmaf(v, v, ss);
    }
    (blockIdx.z ? invny : invnx)[b * N2 + n] = rsqrtf(ss);
}

// ---------------------------------------------------------------------------
// transpose [C][2048] -> [2048][C] with bf16 split.  MODE bits:
//  1 = write unscaled hi/lo; 2 = write invn-scaled hi/lo; 4 = write fp32 transposed
template<int MODE>
__global__ __launch_bounds__(256) void tsplitK(
    const float* __restrict__ in, int C,
    unsigned short* __restrict__ tHi, unsigned short* __restrict__ tLo,
    const float* __restrict__ invn,
    unsigned short* __restrict__ sHi, unsigned short* __restrict__ sLo,
    float* __restrict__ tF)
{
    __shared__ float lt[64 * 65];
    const int t = threadIdx.x;
    const int n0 = blockIdx.x * 64, c0 = blockIdx.y * 64, b = blockIdx.z;
    {
        const int nl = t & 63;
        const int cb = t >> 6;
        #pragma unroll
        for (int i = 0; i < 16; ++i) {
            const int cl = cb + 4 * i;
            lt[nl * 65 + cl] = in[((long)b * C + c0 + cl) * N2 + n0 + nl];
        }
    }
    __syncthreads();
    const int cl = t & 63;
    const int nb = t >> 6;
    #pragma unroll
    for (int i = 0; i < 16; ++i) {
        const int nl = nb + 4 * i;
        const float v = lt[nl * 65 + cl];
        const long oi = ((long)b * N2 + n0 + nl) * C + c0 + cl;
        if (MODE & 1) { tHi[oi] = bhi(v); tLo[oi] = bhi(v - bhif(v)); }
        if (MODE & 2) {
            const float svv = v * invn[b * N2 + n0 + nl];
            sHi[oi] = bhi(svv); sLo[oi] = bhi(svv - bhif(svv));
        }
        if (MODE & 4) tF[oi] = v;
    }
}

// ---------------------------------------------------------------------------
// weight fold (w4) + bf16 split for all 5 weight tensors; blockIdx.y selects
__global__ void wsplitK(const float* __restrict__ w4, const float* __restrict__ w5,
    const float* __restrict__ wm1, const float* __restrict__ wm2, const float* __restrict__ wm3,
    unsigned short* __restrict__ w4h, unsigned short* __restrict__ w4l,
    unsigned short* __restrict__ w5h, unsigned short* __restrict__ w5l,
    unsigned short* __restrict__ m1h, unsigned short* __restrict__ m1l,
    unsigned short* __restrict__ m2h, unsigned short* __restrict__ m2l,
    unsigned short* __restrict__ m3h, unsigned short* __restrict__ m3l)
{
    const int y = blockIdx.y;
    const int idx = blockIdx.x * 256 + threadIdx.x;
    float v; unsigned short *dh, *dl;
    if (y == 0) {
        if (idx >= 256 * 256) return;
        const int k = idx & 255;
        v = w4[idx];
        if (k < 128) v -= w4[idx + 128];
        dh = w4h; dl = w4l;
    } else if (y == 1) {
        if (idx >= 512 * 512) return;
        v = w5[idx]; dh = w5h; dl = w5l;
    } else if (y == 2) {
        if (idx >= 512 * 512) return;
        v = wm1[idx]; dh = m1h; dl = m1l;
    } else if (y == 3) {
        if (idx >= 256 * 512) return;
        v = wm2[idx]; dh = m2h; dl = m2l;
    } else {
        if (idx >= 128 * 256) return;
        v = wm3[idx]; dh = m3h; dl = m3l;
    }
    dh[idx] = bhi(v); dl[idx] = bhi(v - bhif(v));
}

// ---------------------------------------------------------------------------
// top-20 of a 2048 simi row + softmax weights (simi layout [bl][n][m])
__global__ __launch_bounds__(256) void topkK(const float* __restrict__ simi,
    float* __restrict__ topw, int* __restrict__ topi, int bbase)
{
    __shared__ float s[2048];
    __shared__ float bwv[4]; __shared__ int bwi[4];
    __shared__ float selv[20]; __shared__ int seli[20];
    const int t = threadIdx.x;
    const int n = blockIdx.x;
    const int bl = blockIdx.y;
    const float* row = simi + ((long)bl * N2 + n) * N2;
    #pragma unroll
    for (int i = 0; i < 8; ++i) s[t + 256 * i] = row[t + 256 * i];
    __syncthreads();
    for (int it = 0; it < 20; ++it) {
        float bv = -1e30f; int bi = 0x7fffffff;
        #pragma unroll
        for (int i = 0; i < 8; ++i) {
            const int idx = t + 256 * i;
            const float v = s[idx];
            if (v > bv || (v == bv && idx < bi)) { bv = v; bi = idx; }
        }
        #pragma unroll
        for (int m = 1; m < 64; m <<= 1) {
            const float ov = __shfl_xor(bv, m);
            const int   oi = __shfl_xor(bi, m);
            if (ov > bv || (ov == bv && oi < bi)) { bv = ov; bi = oi; }
        }
        if ((t & 63) == 0) { bwv[t >> 6] = bv; bwi[t >> 6] = bi; }
        __syncthreads();
        if (t == 0) {
            float vv = bwv[0]; int ii = bwi[0];
            for (int w = 1; w < 4; ++w)
                if (bwv[w] > vv || (bwv[w] == vv && bwi[w] < ii)) { vv = bwv[w]; ii = bwi[w]; }
            selv[it] = vv; seli[it] = ii; s[ii] = -1e30f;
        }
        __syncthreads();
    }
    if (t == 0) {
        const float m = selv[0];
        float sum = 0.f;
        for (int k = 0; k < 20; ++k) { selv[k] = expf(selv[k] - m); sum += selv[k]; }
        const float inv = 1.f / sum;
        for (int k = 0; k < 20; ++k) selv[k] *= inv;
    }
    __syncthreads();
    if (t < 20) {
        const long base = (((long)(bbase + bl)) * N2 + n) * 20;
        topw[base + t] = selv[t];
        topi[base + t] = seli[t];
    }
}

// ---------------------------------------------------------------------------
// G[n][c] = sum_k w_k * yT[idx_k][c], written as split bf16
__global__ __launch_bounds__(256) void aggK(const float* __restrict__ yT,
    const float* __restrict__ topw, const int* __restrict__ topi,
    unsigned short* __restrict__ Gh, unsigned short* __restrict__ Gl)
{
    const int t = threadIdx.x;
    const int c = t & 127, nh = t >> 7;
    const int n0 = blockIdx.x * 32;
    const int b  = blockIdx.y;
    for (int j = 0; j < 16; ++j) {
        const int n = n0 + 2 * j + nh;
        const long tb = ((long)b * N2 + n) * 20;
        float a = 0.f;
        for (int k = 0; k < 20; ++k)
            a = fmaf(topw[tb + k], yT[((long)b * N2 + topi[tb + k]) * 128 + c], a);
        const long oi = ((long)b * N2 + n) * 128 + c;
        Gh[oi] = bhi(a); Gl[oi] = bhi(a - bhif(a));
    }
}

// ---------------------------------------------------------------------------
// reduce per-column sums to per-(b,group) GN stats;  one block of 256 = 8b x 32g
__global__ void statsK(const float* __restrict__ cs1, const float* __restrict__ cs2,
    float* __restrict__ stats, int C)
{
    const int t = threadIdx.x;
    const int b = t >> 5, g = t & 31;
    const int cpg = C >> 5;
    float s1 = 0.f, s2 = 0.f;
    for (int j = 0; j < cpg; ++j) {
        s1 += cs1[b * C + g * cpg + j];
        s2 += cs2[b * C + g * cpg + j];
    }
    const float cnt = (float)(cpg * N2);
    const float mu = s1 / cnt;
    const float var = s2 / cnt - mu * mu;
    stats[t * 2] = mu;
    stats[t * 2 + 1] = rsqrtf(var + 1e-5f);
}

// ---------------------------------------------------------------------------
// GN apply + activation, fp32 [n][C] -> split bf16 [n][C].  ACT 0=lrelu 1=relu
template<int ACT, int LC>
__global__ void gnapplyK(const float* __restrict__ pre, const float* __restrict__ stats,
    const float* __restrict__ gamma, const float* __restrict__ beta,
    unsigned short* __restrict__ oH, unsigned short* __restrict__ oL)
{
    const long i4 = ((long)blockIdx.x * 256 + threadIdx.x) * 4;
    const int C = 1 << LC;
    const int c = (int)(i4 & (C - 1));
    const int bn = (int)(i4 >> LC);
    const int b = bn >> 11;
    const int g = c >> (LC - 5);
    const float mu = stats[(b * 32 + g) * 2];
    const float rs = stats[(b * 32 + g) * 2 + 1];
    const float4 gm = *(const float4*)(gamma + c);
    const float4 bt = *(const float4*)(beta + c);
    const float4 v = *(const float4*)(pre + i4);
    const float vals[4] = {v.x, v.y, v.z, v.w};
    const float gms[4] = {gm.x, gm.y, gm.z, gm.w};
    const float bts[4] = {bt.x, bt.y, bt.z, bt.w};
    unsigned short hs[4], ls[4];
    #pragma unroll
    for (int j = 0; j < 4; ++j) {
        float x = (vals[j] - mu) * (rs * gms[j]) + bts[j];
        x = (ACT == 0) ? (x >= 0.f ? x : LRELU_S * x) : (x >= 0.f ? x : 0.f);
        hs[j] = bhi(x); ls[j] = bhi(x - bhif(x));
    }
    ushort4 hh; hh.x = hs[0]; hh.y = hs[1]; hh.z = hs[2]; hh.w = hs[3];
    ushort4 ll; ll.x = ls[0]; ll.y = ls[1]; ll.z = ls[2]; ll.w = ls[3];
    *(ushort4*)(oH + i4) = hh;
    *(ushort4*)(oL + i4) = ll;
}

// ---------------------------------------------------------------------------
// final GN8 + relu + transpose to out[b][128][2048]
__global__ __launch_bounds__(256) void gnfinalK(const float* __restrict__ pre,
    const float* __restrict__ stats, const float* __restrict__ gamma,
    const float* __restrict__ beta, float* __restrict__ out)
{
    __shared__ float lt[64 * 65];
    const int t = threadIdx.x;
    const int n0 = blockIdx.x * 64, c0 = blockIdx.y * 64, b = blockIdx.z;
    {
        const int cl = t & 63;
        const int nb = t >> 6;
        const int c = c0 + cl;
        const int g = c >> 2;
        const float mu = stats[(b * 32 + g) * 2];
        const float rs = stats[(b * 32 + g) * 2 + 1];
        const float sc = rs * gamma[c], sh = beta[c] - mu * sc;
        #pragma unroll
        for (int i = 0; i < 16; ++i) {
            const int nl = nb + 4 * i;
            float v = pre[((long)b * N2 + n0 + nl) * 128 + c];
            v = v * sc + sh;
            lt[cl * 65 + nl] = v > 0.f ? v : 0.f;
        }
    }
    __syncthreads();
    const int nl = t & 63;
    const int cb = t >> 6;
    #pragma unroll
    for (int i = 0; i < 16; ++i) {
        const int cl = cb + 4 * i;
        out[((long)b * 128 + c0 + cl) * N2 + n0 + nl] = lt[cl * 65 + nl];
    }
}

// ---------------------------------------------------------------------------
// pooling stage 1: per (b, n-chunk of 64) partial max/sum over all 512 channels
// lc layout [b][n][512] split bf16; 256 threads = 128 c-quads x 2 row-parities
__global__ __launch_bounds__(256) void pool1K(const unsigned short* __restrict__ lcH,
    const unsigned short* __restrict__ lcL, float* __restrict__ pmax, float* __restrict__ psum)
{
    __shared__ float lmx[512], lsm[512];
    const int t  = threadIdx.x;
    const int cq = t & 127;          // channel quad: channels 4*cq..4*cq+3
    const int rp = t >> 7;           // row parity
    const int nch = blockIdx.x;      // 0..31 (64 rows each)
    const int b   = blockIdx.y;
    float mx[4] = {-1e30f, -1e30f, -1e30f, -1e30f};
    float sm[4] = {0.f, 0.f, 0.f, 0.f};
    for (int i = 0; i < 32; ++i) {
        const int n = nch * 64 + 2 * i + rp;
        const long base = ((long)b * N2 + n) * 512 + cq * 4;
        const ushort4 hh = *(const ushort4*)(lcH + base);
        const ushort4 ll = *(const ushort4*)(lcL + base);
        const float v0 = bf2f(hh.x) + bf2f(ll.x);
        const float v1 = bf2f(hh.y) + bf2f(ll.y);
        const float v2 = bf2f(hh.z) + bf2f(ll.z);
        const float v3 = bf2f(hh.w) + bf2f(ll.w);
        mx[0] = fmaxf(mx[0], v0); sm[0] += v0;
        mx[1] = fmaxf(mx[1], v1); sm[1] += v1;
        mx[2] = fmaxf(mx[2], v2); sm[2] += v2;
        mx[3] = fmaxf(mx[3], v3); sm[3] += v3;
    }
    if (rp) {
        #pragma unroll
        for (int j = 0; j < 4; ++j) { lmx[cq * 4 + j] = mx[j]; lsm[cq * 4 + j] = sm[j]; }
    }
    __syncthreads();
    if (!rp) {
        const long pb = ((long)(b * 32 + nch)) * 512 + cq * 4;
        #pragma unroll
        for (int j = 0; j < 4; ++j) {
            pmax[pb + j] = fmaxf(mx[j], lmx[cq * 4 + j]);
            psum[pb + j] = sm[j] + lsm[cq * 4 + j];
        }
    }
}

// pooling stage 2: reduce 32 chunk partials -> gv[b][1024] (max | mean)
__global__ void pool2K(const float* __restrict__ pmax, const float* __restrict__ psum,
                       float* __restrict__ gv)
{
    const int t = threadIdx.x;       // 256: 2 channels each
    const int b = blockIdx.x;
    float mx0 = -1e30f, mx1 = -1e30f, s0 = 0.f, s1 = 0.f;
    for (int nch = 0; nch < 32; ++nch) {
        const long pb = ((long)(b * 32 + nch)) * 512 + 2 * t;
        const float2 pm = *(const float2*)(pmax + pb);
        const float2 ps = *(const float2*)(psum + pb);
        mx0 = fmaxf(mx0, pm.x); mx1 = fmaxf(mx1, pm.y);
        s0 += ps.x; s1 += ps.y;
    }
    gv[b * 1024 + 2 * t]           = mx0;
    gv[b * 1024 + 2 * t + 1]       = mx1;
    gv[b * 1024 + 512 + 2 * t]     = s0 * (1.f / 2048.f);
    gv[b * 1024 + 512 + 2 * t + 1] = s1 * (1.f / 2048.f);
}

// ---------------------------------------------------------------------------
extern "C" void kernel_launch(void* const* d_in, const int* in_sizes, int n_in,
                              void* d_out, int out_size, void* d_ws, size_t ws_size,
                              hipStream_t stream)
{
    const float* x1    = (const float*)d_in[0];
    const float* x2    = (const float*)d_in[1];
    const float* x3    = (const float*)d_in[2];
    const float* y3    = (const float*)d_in[3];
    const float* w4    = (const float*)d_in[4];
    const float* bn4g  = (const float*)d_in[5];
    const float* bn4b  = (const float*)d_in[6];
    const float* w5    = (const float*)d_in[7];
    const float* gn5g  = (const float*)d_in[8];
    const float* gn5b  = (const float*)d_in[9];
    const float* wm1   = (const float*)d_in[10];
    const float* bm1   = (const float*)d_in[11];
    const float* gn6g  = (const float*)d_in[12];
    const float* gn6b  = (const float*)d_in[13];
    const float* wm2   = (const float*)d_in[14];
    const float* bm2   = (const float*)d_in[15];
    const float* gn7g  = (const float*)d_in[16];
    const float* gn7b  = (const float*)d_in[17];
    const float* wm3   = (const float*)d_in[18];
    const float* bm3   = (const float*)d_in[19];
    const float* gn8g  = (const float*)d_in[20];
    const float* gn8b  = (const float*)d_in[21];
    float* out = (float*)d_out;
    (void)in_sizes; (void)n_in; (void)out_size; (void)ws_size;

    char* ws = (char*)d_ws;
    // ---- arena (aliased regions; ~120 MB total) ----
    float*          bufPS = (float*)(ws + 0);                         // 33.55 MB: simi chunks, then GEMM pre
    unsigned short* lcH   = (unsigned short*)(ws + 33554432);         // 16.78 MB
    unsigned short* lcL   = (unsigned short*)(ws + 50331648);         // 16.78 MB
    const size_t R3 = 67108864;                                       // 33.55 MB region
    float*          yT    = (float*)(ws + R3);                        //  8.39 MB
    unsigned short* x3tH  = (unsigned short*)(ws + R3 + 8388608);
    unsigned short* x3tL  = (unsigned short*)(ws + R3 + 12582912);
    unsigned short* x1tH  = (unsigned short*)(ws + R3 + 16777216);
    unsigned short* x1tL  = (unsigned short*)(ws + R3 + 18874368);
    unsigned short* x2tH  = (unsigned short*)(ws + R3 + 20971520);
    unsigned short* x2tL  = (unsigned short*)(ws + R3 + 23068672);
    unsigned short* GH    = (unsigned short*)(ws + R3 + 25165824);
    unsigned short* GL    = (unsigned short*)(ws + R3 + 29360128);
    unsigned short* h1H   = (unsigned short*)(ws + R3);               // alias (after conv5/agg/conv4 done)
    unsigned short* h1L   = (unsigned short*)(ws + R3 + 16777216);
    const size_t R4 = 100663296;                                      // 16.78 MB region
    unsigned short* xnH   = (unsigned short*)(ws + R4);
    unsigned short* xnL   = (unsigned short*)(ws + R4 + 4194304);
    unsigned short* ynH   = (unsigned short*)(ws + R4 + 8388608);
    unsigned short* ynL   = (unsigned short*)(ws + R4 + 12582912);
    unsigned short* x4H   = (unsigned short*)(ws + R4);               // alias (after simi done)
    unsigned short* x4L   = (unsigned short*)(ws + R4 + 8388608);
    unsigned short* h2H   = (unsigned short*)(ws + R4);               // alias (after conv5 done)
    unsigned short* h2L   = (unsigned short*)(ws + R4 + 8388608);
    const size_t W = 117440512;
    unsigned short* w4pH = (unsigned short*)(ws + W);
    unsigned short* w4pL = (unsigned short*)(ws + W + 131072);
    unsigned short* w5H  = (unsigned short*)(ws + W + 262144);
    unsigned short* w5L  = (unsigned short*)(ws + W + 786432);
    unsigned short* m1H  = (unsigned short*)(ws + W + 1310720);
    unsigned short* m1L  = (unsigned short*)(ws + W + 1835008);
    unsigned short* m2H  = (unsigned short*)(ws + W + 2359296);
    unsigned short* m2L  = (unsigned short*)(ws + W + 2621440);
    unsigned short* m3H  = (unsigned short*)(ws + W + 2883584);
    unsigned short* m3L  = (unsigned short*)(ws + W + 2949120);
    const size_t M = W + 3145728;
    float* invnx = (float*)(ws + M);
    float* invny = (float*)(ws + M + 65536);
    float* topw  = (float*)(ws + M + 131072);
    int*   topi  = (int*)  (ws + M + 1441792);
    float* csb   = (float*)(ws + M + 2752512);                        // 128 KB
    float* cs1_5 = csb,          *cs2_5 = csb + 4096;
    float* cs1_6 = csb + 8192,   *cs2_6 = csb + 12288;
    float* cs1_7 = csb + 16384,  *cs2_7 = csb + 20480;
    float* cs1_8 = csb + 24576,  *cs2_8 = csb + 28672;
    float* stats5 = (float*)(ws + M + 2883584);
    float* stats6 = stats5 + 512;
    float* stats7 = stats5 + 1024;
    float* stats8 = stats5 + 1536;
    float* pmax  = (float*)(ws + M + 2891776);                        // 512 KB
    float* psum  = (float*)(ws + M + 3416064);                        // 512 KB

    const dim3 B256(256);
    const unsigned short* nu = nullptr;

    // 0. zero colsum accumulators (ws is poisoned each launch)
    hipMemsetAsync(csb, 0, 131072, stream);

    // 1. norms, transposes + bf16 splits, weight folds/splits
    normK<<<dim3(8, 8, 2), B256, 0, stream>>>(x3, y3, invnx, invny);
    tsplitK<6><<<dim3(32, 2, 8), B256, 0, stream>>>(y3, 128, nullptr, nullptr, invny, ynH, ynL, yT);
    tsplitK<3><<<dim3(32, 2, 8), B256, 0, stream>>>(x3, 128, x3tH, x3tL, invnx, xnH, xnL, nullptr);
    tsplitK<1><<<dim3(32, 1, 8), B256, 0, stream>>>(x1, 64, x1tH, x1tL, nullptr, nullptr, nullptr, nullptr);
    tsplitK<1><<<dim3(32, 1, 8), B256, 0, stream>>>(x2, 64, x2tH, x2tL, nullptr, nullptr, nullptr, nullptr);
    wsplitK<<<dim3(1024, 5), B256, 0, stream>>>(w4, w5, wm1, wm2, wm3,
        w4pH, w4pL, w5H, w5L, m1H, m1L, m2H, m2L, m3H, m3L);

    // 2. simi (split-bf16 MFMA) + topk, 2 batches per chunk
    for (int ch = 0; ch < 4; ++ch) {
        mgemm<0, 0><<<dim3(16, 16, 2), B256, 0, stream>>>(
            xnH, xnL, 128, nu, nu, nu, nu, nu, nu,
            ynH, ynL, (long)N2 * 128, 128, 2048, ch * 2,
            bufPS, nullptr, nullptr, nullptr, nullptr, nullptr, nullptr);
        topkK<<<dim3(2048, 2), B256, 0, stream>>>(bufPS, topw, topi, ch * 2);
    }

    // 3. gather-aggregate G (split bf16)
    aggK<<<dim3(64, 8), B256, 0, stream>>>(yT, topw, topi, GH, GL);

    // 4. conv4 (+BN eval + lrelu) over [x3 | G] with folded W4' -> x4 hi/lo
    mgemm<1, 1><<<dim3(16, 2, 8), B256, 0, stream>>>(
        x3tH, x3tL, 128, GH, GL, nu, nu, nu, nu,
        w4pH, w4pL, 0, 256, 256, 0,
        nullptr, x4H, x4L, bn4g, bn4b, nullptr, nullptr);

    // 5. conv5 over [x1|x2|x3|x4] -> pre (bufPS) + colsums; GN5 + lrelu -> lc
    mgemm<2, 2><<<dim3(16, 4, 8), B256, 0, stream>>>(
        x1tH, x1tL, 64, x2tH, x2tL, x3tH, x3tL, x4H, x4L,
        w5H, w5L, 0, 512, 512, 0,
        bufPS, nullptr, nullptr, nullptr, nullptr, cs1_5, cs2_5);
    statsK<<<1, B256, 0, stream>>>(cs1_5, cs2_5, stats5, 512);
    gnapplyK<0, 9><<<8192, B256, 0, stream>>>(bufPS, stats5, gn5g, gn5b, lcH, lcL);

    // 6. global pooling -> gv section of output (two-stage, 256 blocks)
    pool1K<<<dim3(32, 8), B256, 0, stream>>>(lcH, lcL, pmax, psum);
    pool2K<<<dim3(8), B256, 0, stream>>>(pmax, psum, out + (long)8 * 128 * 2048);

    // 7. mlp1 -> pre + colsums; GN6 + relu -> h1
    mgemm<0, 2><<<dim3(16, 4, 8), B256, 0, stream>>>(
        lcH, lcL, 512, nu, nu, nu, nu, nu, nu,
        m1H, m1L, 0, 512, 512, 0,
        bufPS, nullptr, nullptr, nullptr, bm1, cs1_6, cs2_6);
    statsK<<<1, B256, 0, stream>>>(cs1_6, cs2_6, stats6, 512);
    gnapplyK<1, 9><<<8192, B256, 0, stream>>>(bufPS, stats6, gn6g, gn6b, h1H, h1L);

    // 8. mlp2 -> pre + colsums; GN7 + relu -> h2
    mgemm<0, 2><<<dim3(16, 2, 8), B256, 0, stream>>>(
        h1H, h1L, 512, nu, nu, nu, nu, nu, nu,
        m2H, m2L, 0, 512, 256, 0,
        bufPS, nullptr, nullptr, nullptr, bm2, cs1_7, cs2_7);
    statsK<<<1, B256, 0, stream>>>(cs1_7, cs2_7, stats7, 256);
    gnapplyK<1, 8><<<4096, B256, 0, stream>>>(bufPS, stats7, gn7g, gn7b, h2H, h2L);

    // 9. mlp3 -> pre + colsums; GN8 + relu + transpose -> emb (d_out)
    mgemm<0, 2><<<dim3(16, 1, 8), B256, 0, stream>>>(
        h2H, h2L, 256, nu, nu, nu, nu, nu, nu,
        m3H, m3L, 0, 256, 128, 0,
        bufPS, nullptr, nullptr, nullptr, bm3, cs1_8, cs2_8);
    statsK<<<1, B256, 0, stream>>>(cs1_8, cs2_8, stats8, 128);
    gnfinalK<<<dim3(32, 2, 8), B256, 0, stream>>>(bufPS, stats8, gn8g, gn8b, out);
}

// Round 5
// 559.955 us; speedup vs baseline: 2.1523x; 1.4469x over previous
//
#include <hip/hip_runtime.h>
#include <math.h>

#define N2 2048
#define LRELU_S 0.2f
#define BN4_RS 0.9999950000374997f   // rsqrt(1+1e-5)

typedef short bf16x8 __attribute__((ext_vector_type(8)));
typedef float f32x16 __attribute__((ext_vector_type(16)));

__device__ __forceinline__ unsigned short bhi(float v) { return (unsigned short)(__float_as_uint(v) >> 16); }
__device__ __forceinline__ float bhif(float v) { return __uint_as_float(__float_as_uint(v) & 0xFFFF0000u); }
__device__ __forceinline__ float bf2f(unsigned short u) { return __uint_as_float(((unsigned int)u) << 16); }

__device__ __forceinline__ void gl16(const void* g, void* l) {
    __builtin_amdgcn_global_load_lds((const __attribute__((address_space(1))) unsigned int*)g,
                                     (__attribute__((address_space(3))) unsigned int*)l, 16, 0, 0);
}

__device__ __forceinline__ f32x16 z16() {
    f32x16 v;
    #pragma unroll
    for (int i = 0; i < 16; ++i) v[i] = 0.f;
    return v;
}

#define MFMA32 __builtin_amdgcn_mfma_f32_32x32x16_bf16

// ---------------------------------------------------------------------------
// Split-bf16 3-pass MFMA GEMM.  out[bz][n][o] = sum_k A[b][n][k] * B[o][k]
// A sources are [B*2048][CA] hi/lo bf16 (activation layout, k contiguous).
// B is [O][Ktot] hi/lo bf16 (weight layout, k contiguous; bBs = batch stride for yn).
// ASRC: 0 single (a1, stride CA); 1 cat2 (x3t 128 | G 128); 2 cat4 (x1 64|x2 64|x3 128|x4 256)
// EPI:  0 fp32 store; 1 bn4-scale+bias+lrelu -> split hi/lo store; 2 +bias fp32 store + colsum atomics
// Tile: 128(M=n) x 128(N=o) x BK=32, 4 waves as 2x2 of 64x64, 32x32x16 MFMA.
// ---------------------------------------------------------------------------
template<int ASRC, int EPI>
__global__ __launch_bounds__(256) void mgemm(
    const unsigned short* __restrict__ a1H, const unsigned short* __restrict__ a1L, int CA,
    const unsigned short* __restrict__ a2H, const unsigned short* __restrict__ a2L,
    const unsigned short* __restrict__ a3H, const unsigned short* __restrict__ a3L,
    const unsigned short* __restrict__ a4H, const unsigned short* __restrict__ a4L,
    const unsigned short* __restrict__ bH,  const unsigned short* __restrict__ bL, long bBs,
    int Ktot, int OC, int bbase,
    float* __restrict__ outF,
    unsigned short* __restrict__ oH, unsigned short* __restrict__ oL,
    const float* __restrict__ epg, const float* __restrict__ epb,
    float* __restrict__ cs1, float* __restrict__ cs2)
{
    __shared__ alignas(16) unsigned short lAh[4096], lAl[4096], lBh[4096], lBl[4096];
    const int t  = threadIdx.x;
    const int n0 = blockIdx.x * 128;
    const int o0 = blockIdx.y * 128;
    const int bz = blockIdx.z;
    const int b  = bbase + bz;

    const int lane = t & 63;
    const int h    = lane >> 5;
    const int l31  = lane & 31;
    const int wid  = t >> 6;
    const int wm   = wid >> 1;
    const int wn   = wid & 1;
    const int sw   = (l31 >> 1) & 3;            // LDS chunk swizzle for frag reads

    f32x16 acc00 = z16(), acc01 = z16(), acc10 = z16(), acc11 = z16();

    // staging chunk ids (16B each); wave-consecutive lanes -> consecutive LDS chunks
    const int q0 = t, q1 = t + 256;
    const int r0 = q0 >> 2, p0 = q0 & 3, c0s = p0 ^ ((r0 >> 1) & 3);
    const int r1 = q1 >> 2, p1 = q1 & 3, c1s = p1 ^ ((r1 >> 1) & 3);

    // frag read row bases (ushort index)
    const int rA0 = (wm * 64 + l31) * 32, rA1 = rA0 + 1024;
    const int rB0 = (wn * 64 + l31) * 32, rB1 = rB0 + 1024;

    for (int kc = 0; kc < Ktot; kc += 32) {
        const unsigned short *sAH, *sAL; int koff, Cs;
        if (ASRC == 0)      { sAH = a1H; sAL = a1L; koff = kc;       Cs = CA; }
        else if (ASRC == 1) {
            if (kc < 128)   { sAH = a1H; sAL = a1L; koff = kc;       Cs = 128; }
            else            { sAH = a2H; sAL = a2L; koff = kc - 128; Cs = 128; }
        } else {
            if (kc < 64)        { sAH = a1H; sAL = a1L; koff = kc;       Cs = 64;  }
            else if (kc < 128)  { sAH = a2H; sAL = a2L; koff = kc - 64;  Cs = 64;  }
            else if (kc < 256)  { sAH = a3H; sAL = a3L; koff = kc - 128; Cs = 128; }
            else                { sAH = a4H; sAL = a4L; koff = kc - 256; Cs = 256; }
        }
        __syncthreads();
        {
            long ga = ((long)b * N2 + n0 + r0) * Cs + koff + c0s * 8;
            gl16(sAH + ga, lAh + q0 * 8);
            gl16(sAL + ga, lAl + q0 * 8);
            long gb = (long)b * bBs + (long)(o0 + r0) * Ktot + kc + c0s * 8;
            gl16(bH + gb, lBh + q0 * 8);
            gl16(bL + gb, lBl + q0 * 8);
            ga = ((long)b * N2 + n0 + r1) * Cs + koff + c1s * 8;
            gl16(sAH + ga, lAh + q1 * 8);
            gl16(sAL + ga, lAl + q1 * 8);
            gb = (long)b * bBs + (long)(o0 + r1) * Ktot + kc + c1s * 8;
            gl16(bH + gb, lBh + q1 * 8);
            gl16(bL + gb, lBl + q1 * 8);
        }
        __syncthreads();
        #pragma unroll
        for (int s = 0; s < 2; ++s) {
            const int off = ((s * 2 + h) ^ sw) * 8;
            bf16x8 a0h = *(const bf16x8*)(lAh + rA0 + off);
            bf16x8 a0l = *(const bf16x8*)(lAl + rA0 + off);
            bf16x8 a1h_ = *(const bf16x8*)(lAh + rA1 + off);
            bf16x8 a1l_ = *(const bf16x8*)(lAl + rA1 + off);
            bf16x8 b0h = *(const bf16x8*)(lBh + rB0 + off);
            bf16x8 b0l = *(const bf16x8*)(lBl + rB0 + off);
            bf16x8 b1h = *(const bf16x8*)(lBh + rB1 + off);
            bf16x8 b1l = *(const bf16x8*)(lBl + rB1 + off);
            acc00 = MFMA32(a0h, b0h, acc00, 0, 0, 0);
            acc01 = MFMA32(a0h, b1h, acc01, 0, 0, 0);
            acc10 = MFMA32(a1h_, b0h, acc10, 0, 0, 0);
            acc11 = MFMA32(a1h_, b1h, acc11, 0, 0, 0);
            acc00 = MFMA32(a0h, b0l, acc00, 0, 0, 0);
            acc00 = MFMA32(a0l, b0h, acc00, 0, 0, 0);
            acc01 = MFMA32(a0h, b1l, acc01, 0, 0, 0);
            acc01 = MFMA32(a0l, b1h, acc01, 0, 0, 0);
            acc10 = MFMA32(a1h_, b0l, acc10, 0, 0, 0);
            acc10 = MFMA32(a1l_, b0h, acc10, 0, 0, 0);
            acc11 = MFMA32(a1h_, b1l, acc11, 0, 0, 0);
            acc11 = MFMA32(a1l_, b1h, acc11, 0, 0, 0);
        }
    }

    // epilogue: D col = lane&31 (o), row = (r&3) + 8*(r>>2) + 4*h (+ mi*32 + wm*64)
    #pragma unroll
    for (int ni = 0; ni < 2; ++ni) {
        const int o = o0 + wn * 64 + ni * 32 + l31;
        float sc = 0.f, sh = 0.f, bias = 0.f;
        if (EPI == 1) { sc = epg[o] * BN4_RS; sh = epb[o]; }
        if (EPI == 2) { bias = epb ? epb[o] : 0.f; }
        float s1 = 0.f, s2 = 0.f;
        #pragma unroll
        for (int mi = 0; mi < 2; ++mi) {
            #pragma unroll
            for (int r = 0; r < 16; ++r) {
                const int n = n0 + wm * 64 + mi * 32 + (r & 3) + 8 * (r >> 2) + 4 * h;
                float v = (ni == 0) ? (mi == 0 ? acc00[r] : acc10[r])
                                    : (mi == 0 ? acc01[r] : acc11[r]);
                const long oi = ((long)bz * N2 + n) * (long)OC + o;
                if (EPI == 0) {
                    outF[oi] = v;
                } else if (EPI == 1) {
                    v = fmaf(v, sc, sh);
                    v = v >= 0.f ? v : LRELU_S * v;
                    oH[oi] = bhi(v); oL[oi] = bhi(v - bhif(v));
                } else {
                    v += bias;
                    outF[oi] = v;
                    s1 += v; s2 = fmaf(v, v, s2);
                }
            }
        }
        if (EPI == 2) {
            s1 += __shfl_xor(s1, 32);
            s2 += __shfl_xor(s2, 32);
            if (h == 0) {
                atomicAdd(cs1 + bz * OC + o, s1);
                atomicAdd(cs2 + bz * OC + o, s2);
            }
        }
    }
}

// ---------------------------------------------------------------------------
// inverse norms over C=128 channels for x3 (z=0) and y3 (z=1)
__global__ void normK(const float* __restrict__ x3, const float* __restrict__ y3,
                      float* __restrict__ invnx, float* __restrict__ invny)
{
    const int n = blockIdx.x * 256 + threadIdx.x;
    const int b = blockIdx.y;
    const float* src = blockIdx.z ? y3 : x3;
    float ss = 0.f;
    for (int c = 0; c < 128; ++c) {
        float v = src[((long)b * 128 + c) * N2 + n];
        ss = fmaf(v, v, ss);
    }
    (blockIdx.z ? invny : invnx)[b * N2 + n] = rsqrtf(ss);
}

// ---------------------------------------------------------------------------
// transpose [C][2048] -> [2048][C] with bf16 split.  MODE bits:
//  1 = write unscaled hi/lo; 2 = write invn-scaled hi/lo; 4 = write fp32 transposed
template<int MODE>
__global__ __launch_bounds__(256) void tsplitK(
    const float* __restrict__ in, int C,
    unsigned short* __restrict__ tHi, unsigned short* __restrict__ tLo,
    const float* __restrict__ invn,
    unsigned short* __restrict__ sHi, unsigned short* __restrict__ sLo,
    float* __restrict__ tF)
{
    __shared__ float lt[64 * 65];
    const int t = threadIdx.x;
    const int n0 = blockIdx.x * 64, c0 = blockIdx.y * 64, b = blockIdx.z;
    {
        const int nl = t & 63;
        const int cb = t >> 6;
        #pragma unroll
        for (int i = 0; i < 16; ++i) {
            const int cl = cb + 4 * i;
            lt[nl * 65 + cl] = in[((long)b * C + c0 + cl) * N2 + n0 + nl];
        }
    }
    __syncthreads();
    const int cl = t & 63;
    const int nb = t >> 6;
    #pragma unroll
    for (int i = 0; i < 16; ++i) {
        const int nl = nb + 4 * i;
        const float v = lt[nl * 65 + cl];
        const long oi = ((long)b * N2 + n0 + nl) * C + c0 + cl;
        if (MODE & 1) { tHi[oi] = bhi(v); tLo[oi] = bhi(v - bhif(v)); }
        if (MODE & 2) {
            const float svv = v * invn[b * N2 + n0 + nl];
            sHi[oi] = bhi(svv); sLo[oi] = bhi(svv - bhif(svv));
        }
        if (MODE & 4) tF[oi] = v;
    }
}

// ---------------------------------------------------------------------------
// weight fold (w4) + bf16 split for all 5 weight tensors; blockIdx.y selects
__global__ void wsplitK(const float* __restrict__ w4, const float* __restrict__ w5,
    const float* __restrict__ wm1, const float* __restrict__ wm2, const float* __restrict__ wm3,
    unsigned short* __restrict__ w4h, unsigned short* __restrict__ w4l,
    unsigned short* __restrict__ w5h, unsigned short* __restrict__ w5l,
    unsigned short* __restrict__ m1h, unsigned short* __restrict__ m1l,
    unsigned short* __restrict__ m2h, unsigned short* __restrict__ m2l,
    unsigned short* __restrict__ m3h, unsigned short* __restrict__ m3l)
{
    const int y = blockIdx.y;
    const int idx = blockIdx.x * 256 + threadIdx.x;
    float v; unsigned short *dh, *dl;
    if (y == 0) {
        if (idx >= 256 * 256) return;
        const int k = idx & 255;
        v = w4[idx];
        if (k < 128) v -= w4[idx + 128];
        dh = w4h; dl = w4l;
    } else if (y == 1) {
        if (idx >= 512 * 512) return;
        v = w5[idx]; dh = w5h; dl = w5l;
    } else if (y == 2) {
        if (idx >= 512 * 512) return;
        v = wm1[idx]; dh = m1h; dl = m1l;
    } else if (y == 3) {
        if (idx >= 256 * 512) return;
        v = wm2[idx]; dh = m2h; dl = m2l;
    } else {
        if (idx >= 128 * 256) return;
        v = wm3[idx]; dh = m3h; dl = m3l;
    }
    dh[idx] = bhi(v); dl[idx] = bhi(v - bhif(v));
}

// ---------------------------------------------------------------------------
// top-20 of a 2048 simi row via 4-pass radix select + softmax weights.
// Row layout [bl][n][2048]. Thread t owns indices {4t..4t+3, 1024+4t..1024+4t+3}.
__global__ __launch_bounds__(256) void topkK(const float* __restrict__ simi,
    float* __restrict__ topw, int* __restrict__ topi, int bbase)
{
    __shared__ unsigned int hist[256];
    __shared__ unsigned int bcast[2];
    __shared__ unsigned int cnt[2];
    __shared__ float selv[20];
    __shared__ int   seli[20];
    const int t  = threadIdx.x;
    const int n  = blockIdx.x;
    const int bl = blockIdx.y;
    const float* row = simi + ((long)bl * N2 + n) * N2;

    float    f[8];
    unsigned u[8];
    {
        const float4 v0 = *(const float4*)(row + 4 * t);
        const float4 v1 = *(const float4*)(row + 1024 + 4 * t);
        f[0] = v0.x; f[1] = v0.y; f[2] = v0.z; f[3] = v0.w;
        f[4] = v1.x; f[5] = v1.y; f[6] = v1.z; f[7] = v1.w;
        #pragma unroll
        for (int i = 0; i < 8; ++i) {
            unsigned ub = __float_as_uint(f[i]);
            u[i] = ub ^ (((int)ub >> 31) | 0x80000000u);   // order-preserving flip
        }
    }

    unsigned prefix = 0;
    unsigned kneed  = 20;
    #pragma unroll
    for (int pass = 0; pass < 4; ++pass) {
        const int shift = 24 - 8 * pass;
        const unsigned pmask = (pass == 0) ? 0u : (0xFFFFFFFFu << (shift + 8));
        hist[t] = 0;
        __syncthreads();
        #pragma unroll
        for (int i = 0; i < 8; ++i)
            if ((u[i] & pmask) == prefix)
                atomicAdd(&hist[(u[i] >> shift) & 255], 1u);
        __syncthreads();
        if (t < 64) {
            const unsigned h0 = hist[4 * t], h1 = hist[4 * t + 1];
            const unsigned h2 = hist[4 * t + 2], h3 = hist[4 * t + 3];
            const unsigned s3 = h3, s2 = h2 + s3, s1 = h1 + s2, s0 = h0 + s1;
            unsigned inc = s0;
            #pragma unroll
            for (int off = 1; off < 64; off <<= 1) {
                const unsigned o = __shfl_down(inc, off);
                if (t + off < 64) inc += o;
            }
            const unsigned excl = inc - s0;               // count in lanes > t
            const unsigned sf[5] = {excl + s0, excl + s1, excl + s2, excl + s3, excl};
            #pragma unroll
            for (int j = 0; j < 4; ++j) {
                if (sf[j] >= kneed && sf[j + 1] < kneed) {
                    bcast[0] = 4 * t + j;
                    bcast[1] = kneed - sf[j + 1];
                }
            }
        }
        __syncthreads();
        prefix |= bcast[0] << shift;
        kneed   = bcast[1];
        __syncthreads();
    }

    if (t == 0) { cnt[0] = 0; cnt[1] = 0; }
    __syncthreads();
    const unsigned Tu = prefix;
    const int eqneed = (int)kneed;                        // equals to take
    const int gt     = 20 - eqneed;                       // strictly-greater count
    #pragma unroll
    for (int i = 0; i < 8; ++i) {
        const int idx = (i < 4) ? (4 * t + i) : (1024 + 4 * t + (i - 4));
        if (u[i] > Tu) {
            const unsigned s = atomicAdd(&cnt[0], 1u);
            selv[s] = f[i]; seli[s] = idx;
        } else if (u[i] == Tu) {
            const unsigned e = atomicAdd(&cnt[1], 1u);
            if ((int)e < eqneed) { selv[gt + e] = f[i]; seli[gt + e] = idx; }
        }
    }
    __syncthreads();

    if (t < 64) {
        const float v = (t < 20) ? selv[t] : -1e30f;
        float m = v;
        #pragma unroll
        for (int off = 1; off < 32; off <<= 1) m = fmaxf(m, __shfl_xor(m, off, 32));
        const float e = (t < 20) ? expf(v - m) : 0.f;
        float s = e;
        #pragma unroll
        for (int off = 1; off < 32; off <<= 1) s += __shfl_xor(s, off, 32);
        if (t < 20) {
            const long base = (((long)(bbase + bl)) * N2 + n) * 20;
            topw[base + t] = e / s;
            topi[base + t] = seli[t];
        }
    }
}

// ---------------------------------------------------------------------------
// G[n][c] = sum_k w_k * yT[idx_k][c], written as split bf16
__global__ __launch_bounds__(256) void aggK(const float* __restrict__ yT,
    const float* __restrict__ topw, const int* __restrict__ topi,
    unsigned short* __restrict__ Gh, unsigned short* __restrict__ Gl)
{
    const int t = threadIdx.x;
    const int c = t & 127, nh = t >> 7;
    const int n0 = blockIdx.x * 32;
    const int b  = blockIdx.y;
    for (int j = 0; j < 16; ++j) {
        const int n = n0 + 2 * j + nh;
        const long tb = ((long)b * N2 + n) * 20;
        float a = 0.f;
        for (int k = 0; k < 20; ++k)
            a = fmaf(topw[tb + k], yT[((long)b * N2 + topi[tb + k]) * 128 + c], a);
        const long oi = ((long)b * N2 + n) * 128 + c;
        Gh[oi] = bhi(a); Gl[oi] = bhi(a - bhif(a));
    }
}

// ---------------------------------------------------------------------------
// reduce per-column sums to per-(b,group) GN stats;  one block of 256 = 8b x 32g
__global__ void statsK(const float* __restrict__ cs1, const float* __restrict__ cs2,
    float* __restrict__ stats, int C)
{
    const int t = threadIdx.x;
    const int b = t >> 5, g = t & 31;
    const int cpg = C >> 5;
    float s1 = 0.f, s2 = 0.f;
    for (int j = 0; j < cpg; ++j) {
        s1 += cs1[b * C + g * cpg + j];
        s2 += cs2[b * C + g * cpg + j];
    }
    const float cnt = (float)(cpg * N2);
    const float mu = s1 / cnt;
    const float var = s2 / cnt - mu * mu;
    stats[t * 2] = mu;
    stats[t * 2 + 1] = rsqrtf(var + 1e-5f);
}

// ---------------------------------------------------------------------------
// GN apply + activation, fp32 [n][C] -> split bf16 [n][C].  ACT 0=lrelu 1=relu
template<int ACT, int LC>
__global__ void gnapplyK(const float* __restrict__ pre, const float* __restrict__ stats,
    const float* __restrict__ gamma, const float* __restrict__ beta,
    unsigned short* __restrict__ oH, unsigned short* __restrict__ oL)
{
    const long i4 = ((long)blockIdx.x * 256 + threadIdx.x) * 4;
    const int C = 1 << LC;
    const int c = (int)(i4 & (C - 1));
    const int bn = (int)(i4 >> LC);
    const int b = bn >> 11;
    const int g = c >> (LC - 5);
    const float mu = stats[(b * 32 + g) * 2];
    const float rs = stats[(b * 32 + g) * 2 + 1];
    const float4 gm = *(const float4*)(gamma + c);
    const float4 bt = *(const float4*)(beta + c);
    const float4 v = *(const float4*)(pre + i4);
    const float vals[4] = {v.x, v.y, v.z, v.w};
    const float gms[4] = {gm.x, gm.y, gm.z, gm.w};
    const float bts[4] = {bt.x, bt.y, bt.z, bt.w};
    unsigned short hs[4], ls[4];
    #pragma unroll
    for (int j = 0; j < 4; ++j) {
        float x = (vals[j] - mu) * (rs * gms[j]) + bts[j];
        x = (ACT == 0) ? (x >= 0.f ? x : LRELU_S * x) : (x >= 0.f ? x : 0.f);
        hs[j] = bhi(x); ls[j] = bhi(x - bhif(x));
    }
    ushort4 hh; hh.x = hs[0]; hh.y = hs[1]; hh.z = hs[2]; hh.w = hs[3];
    ushort4 ll; ll.x = ls[0]; ll.y = ls[1]; ll.z = ls[2]; ll.w = ls[3];
    *(ushort4*)(oH + i4) = hh;
    *(ushort4*)(oL + i4) = ll;
}

// ---------------------------------------------------------------------------
// final GN8 + relu + transpose to out[b][128][2048]
__global__ __launch_bounds__(256) void gnfinalK(const float* __restrict__ pre,
    const float* __restrict__ stats, const float* __restrict__ gamma,
    const float* __restrict__ beta, float* __restrict__ out)
{
    __shared__ float lt[64 * 65];
    const int t = threadIdx.x;
    const int n0 = blockIdx.x * 64, c0 = blockIdx.y * 64, b = blockIdx.z;
    {
        const int cl = t & 63;
        const int nb = t >> 6;
        const int c = c0 + cl;
        const int g = c >> 2;
        const float mu = stats[(b * 32 + g) * 2];
        const float rs = stats[(b * 32 + g) * 2 + 1];
        const float sc = rs * gamma[c], sh = beta[c] - mu * sc;
        #pragma unroll
        for (int i = 0; i < 16; ++i) {
            const int nl = nb + 4 * i;
            float v = pre[((long)b * N2 + n0 + nl) * 128 + c];
            v = v * sc + sh;
            lt[cl * 65 + nl] = v > 0.f ? v : 0.f;
        }
    }
    __syncthreads();
    const int nl = t & 63;
    const int cb = t >> 6;
    #pragma unroll
    for (int i = 0; i < 16; ++i) {
        const int cl = cb + 4 * i;
        out[((long)b * 128 + c0 + cl) * N2 + n0 + nl] = lt[cl * 65 + nl];
    }
}

// ---------------------------------------------------------------------------
// pooling stage 1: per (b, n-chunk of 64) partial max/sum over all 512 channels
// lc layout [b][n][512] split bf16; 256 threads = 128 c-quads x 2 row-parities
__global__ __launch_bounds__(256) void pool1K(const unsigned short* __restrict__ lcH,
    const unsigned short* __restrict__ lcL, float* __restrict__ pmax, float* __restrict__ psum)
{
    __shared__ float lmx[512], lsm[512];
    const int t  = threadIdx.x;
    const int cq = t & 127;          // channel quad: channels 4*cq..4*cq+3
    const int rp = t >> 7;           // row parity
    const int nch = blockIdx.x;      // 0..31 (64 rows each)
    const int b   = blockIdx.y;
    float mx[4] = {-1e30f, -1e30f, -1e30f, -1e30f};
    float sm[4] = {0.f, 0.f, 0.f, 0.f};
    for (int i = 0; i < 32; ++i) {
        const int n = nch * 64 + 2 * i + rp;
        const long base = ((long)b * N2 + n) * 512 + cq * 4;
        const ushort4 hh = *(const ushort4*)(lcH + base);
        const ushort4 ll = *(const ushort4*)(lcL + base);
        const float v0 = bf2f(hh.x) + bf2f(ll.x);
        const float v1 = bf2f(hh.y) + bf2f(ll.y);
        const float v2 = bf2f(hh.z) + bf2f(ll.z);
        const float v3 = bf2f(hh.w) + bf2f(ll.w);
        mx[0] = fmaxf(mx[0], v0); sm[0] += v0;
        mx[1] = fmaxf(mx[1], v1); sm[1] += v1;
        mx[2] = fmaxf(mx[2], v2); sm[2] += v2;
        mx[3] = fmaxf(mx[3], v3); sm[3] += v3;
    }
    if (rp) {
        #pragma unroll
        for (int j = 0; j < 4; ++j) { lmx[cq * 4 + j] = mx[j]; lsm[cq * 4 + j] = sm[j]; }
    }
    __syncthreads();
    if (!rp) {
        const long pb = ((long)(b * 32 + nch)) * 512 + cq * 4;
        #pragma unroll
        for (int j = 0; j < 4; ++j) {
            pmax[pb + j] = fmaxf(mx[j], lmx[cq * 4 + j]);
            psum[pb + j] = sm[j] + lsm[cq * 4 + j];
        }
    }
}

// pooling stage 2: reduce 32 chunk partials -> gv[b][1024] (max | mean)
__global__ void pool2K(const float* __restrict__ pmax, const float* __restrict__ psum,
                       float* __restrict__ gv)
{
    const int t = threadIdx.x;       // 256: 2 channels each
    const int b = blockIdx.x;
    float mx0 = -1e30f, mx1 = -1e30f, s0 = 0.f, s1 = 0.f;
    for (int nch = 0; nch < 32; ++nch) {
        const long pb = ((long)(b * 32 + nch)) * 512 + 2 * t;
        const float2 pm = *(const float2*)(pmax + pb);
        const float2 ps = *(const float2*)(psum + pb);
        mx0 = fmaxf(mx0, pm.x); mx1 = fmaxf(mx1, pm.y);
        s0 += ps.x; s1 += ps.y;
    }
    gv[b * 1024 + 2 * t]           = mx0;
    gv[b * 1024 + 2 * t + 1]       = mx1;
    gv[b * 1024 + 512 + 2 * t]     = s0 * (1.f / 2048.f);
    gv[b * 1024 + 512 + 2 * t + 1] = s1 * (1.f / 2048.f);
}

// ---------------------------------------------------------------------------
extern "C" void kernel_launch(void* const* d_in, const int* in_sizes, int n_in,
                              void* d_out, int out_size, void* d_ws, size_t ws_size,
                              hipStream_t stream)
{
    const float* x1    = (const float*)d_in[0];
    const float* x2    = (const float*)d_in[1];
    const float* x3    = (const float*)d_in[2];
    const float* y3    = (const float*)d_in[3];
    const float* w4    = (const float*)d_in[4];
    const float* bn4g  = (const float*)d_in[5];
    const float* bn4b  = (const float*)d_in[6];
    const float* w5    = (const float*)d_in[7];
    const float* gn5g  = (const float*)d_in[8];
    const float* gn5b  = (const float*)d_in[9];
    const float* wm1   = (const float*)d_in[10];
    const float* bm1   = (const float*)d_in[11];
    const float* gn6g  = (const float*)d_in[12];
    const float* gn6b  = (const float*)d_in[13];
    const float* wm2   = (const float*)d_in[14];
    const float* bm2   = (const float*)d_in[15];
    const float* gn7g  = (const float*)d_in[16];
    const float* gn7b  = (const float*)d_in[17];
    const float* wm3   = (const float*)d_in[18];
    const float* bm3   = (const float*)d_in[19];
    const float* gn8g  = (const float*)d_in[20];
    const float* gn8b  = (const float*)d_in[21];
    float* out = (float*)d_out;
    (void)in_sizes; (void)n_in; (void)out_size; (void)ws_size;

    char* ws = (char*)d_ws;
    // ---- arena (aliased regions; ~120 MB total) ----
    float*          bufPS = (float*)(ws + 0);                         // 33.55 MB: simi chunks, then GEMM pre
    unsigned short* lcH   = (unsigned short*)(ws + 33554432);         // 16.78 MB
    unsigned short* lcL   = (unsigned short*)(ws + 50331648);         // 16.78 MB
    const size_t R3 = 67108864;                                       // 33.55 MB region
    float*          yT    = (float*)(ws + R3);                        //  8.39 MB
    unsigned short* x3tH  = (unsigned short*)(ws + R3 + 8388608);
    unsigned short* x3tL  = (unsigned short*)(ws + R3 + 12582912);
    unsigned short* x1tH  = (unsigned short*)(ws + R3 + 16777216);
    unsigned short* x1tL  = (unsigned short*)(ws + R3 + 18874368);
    unsigned short* x2tH  = (unsigned short*)(ws + R3 + 20971520);
    unsigned short* x2tL  = (unsigned short*)(ws + R3 + 23068672);
    unsigned short* GH    = (unsigned short*)(ws + R3 + 25165824);
    unsigned short* GL    = (unsigned short*)(ws + R3 + 29360128);
    unsigned short* h1H   = (unsigned short*)(ws + R3);               // alias (after conv5/agg/conv4 done)
    unsigned short* h1L   = (unsigned short*)(ws + R3 + 16777216);
    const size_t R4 = 100663296;                                      // 16.78 MB region
    unsigned short* xnH   = (unsigned short*)(ws + R4);
    unsigned short* xnL   = (unsigned short*)(ws + R4 + 4194304);
    unsigned short* ynH   = (unsigned short*)(ws + R4 + 8388608);
    unsigned short* ynL   = (unsigned short*)(ws + R4 + 12582912);
    unsigned short* x4H   = (unsigned short*)(ws + R4);               // alias (after simi done)
    unsigned short* x4L   = (unsigned short*)(ws + R4 + 8388608);
    unsigned short* h2H   = (unsigned short*)(ws + R4);               // alias (after conv5 done)
    unsigned short* h2L   = (unsigned short*)(ws + R4 + 8388608);
    const size_t W = 117440512;
    unsigned short* w4pH = (unsigned short*)(ws + W);
    unsigned short* w4pL = (unsigned short*)(ws + W + 131072);
    unsigned short* w5H  = (unsigned short*)(ws + W + 262144);
    unsigned short* w5L  = (unsigned short*)(ws + W + 786432);
    unsigned short* m1H  = (unsigned short*)(ws + W + 1310720);
    unsigned short* m1L  = (unsigned short*)(ws + W + 1835008);
    unsigned short* m2H  = (unsigned short*)(ws + W + 2359296);
    unsigned short* m2L  = (unsigned short*)(ws + W + 2621440);
    unsigned short* m3H  = (unsigned short*)(ws + W + 2883584);
    unsigned short* m3L  = (unsigned short*)(ws + W + 2949120);
    const size_t M = W + 3145728;
    float* invnx = (float*)(ws + M);
    float* invny = (float*)(ws + M + 65536);
    float* topw  = (float*)(ws + M + 131072);
    int*   topi  = (int*)  (ws + M + 1441792);
    float* csb   = (float*)(ws + M + 2752512);                        // 128 KB
    float* cs1_5 = csb,          *cs2_5 = csb + 4096;
    float* cs1_6 = csb + 8192,   *cs2_6 = csb + 12288;
    float* cs1_7 = csb + 16384,  *cs2_7 = csb + 20480;
    float* cs1_8 = csb + 24576,  *cs2_8 = csb + 28672;
    float* stats5 = (float*)(ws + M + 2883584);
    float* stats6 = stats5 + 512;
    float* stats7 = stats5 + 1024;
    float* stats8 = stats5 + 1536;
    float* pmax  = (float*)(ws + M + 2891776);                        // 512 KB
    float* psum  = (float*)(ws + M + 3416064);                        // 512 KB

    const dim3 B256(256);
    const unsigned short* nu = nullptr;

    // 0. zero colsum accumulators (ws is poisoned each launch)
    hipMemsetAsync(csb, 0, 131072, stream);

    // 1. norms, transposes + bf16 splits, weight folds/splits
    normK<<<dim3(8, 8, 2), B256, 0, stream>>>(x3, y3, invnx, invny);
    tsplitK<6><<<dim3(32, 2, 8), B256, 0, stream>>>(y3, 128, nullptr, nullptr, invny, ynH, ynL, yT);
    tsplitK<3><<<dim3(32, 2, 8), B256, 0, stream>>>(x3, 128, x3tH, x3tL, invnx, xnH, xnL, nullptr);
    tsplitK<1><<<dim3(32, 1, 8), B256, 0, stream>>>(x1, 64, x1tH, x1tL, nullptr, nullptr, nullptr, nullptr);
    tsplitK<1><<<dim3(32, 1, 8), B256, 0, stream>>>(x2, 64, x2tH, x2tL, nullptr, nullptr, nullptr, nullptr);
    wsplitK<<<dim3(1024, 5), B256, 0, stream>>>(w4, w5, wm1, wm2, wm3,
        w4pH, w4pL, w5H, w5L, m1H, m1L, m2H, m2L, m3H, m3L);

    // 2. simi (split-bf16 MFMA) + radix topk, 2 batches per chunk
    for (int ch = 0; ch < 4; ++ch) {
        mgemm<0, 0><<<dim3(16, 16, 2), B256, 0, stream>>>(
            xnH, xnL, 128, nu, nu, nu, nu, nu, nu,
            ynH, ynL, (long)N2 * 128, 128, 2048, ch * 2,
            bufPS, nullptr, nullptr, nullptr, nullptr, nullptr, nullptr);
        topkK<<<dim3(2048, 2), B256, 0, stream>>>(bufPS, topw, topi, ch * 2);
    }

    // 3. gather-aggregate G (split bf16)
    aggK<<<dim3(64, 8), B256, 0, stream>>>(yT, topw, topi, GH, GL);

    // 4. conv4 (+BN eval + lrelu) over [x3 | G] with folded W4' -> x4 hi/lo
    mgemm<1, 1><<<dim3(16, 2, 8), B256, 0, stream>>>(
        x3tH, x3tL, 128, GH, GL, nu, nu, nu, nu,
        w4pH, w4pL, 0, 256, 256, 0,
        nullptr, x4H, x4L, bn4g, bn4b, nullptr, nullptr);

    // 5. conv5 over [x1|x2|x3|x4] -> pre (bufPS) + colsums; GN5 + lrelu -> lc
    mgemm<2, 2><<<dim3(16, 4, 8), B256, 0, stream>>>(
        x1tH, x1tL, 64, x2tH, x2tL, x3tH, x3tL, x4H, x4L,
        w5H, w5L, 0, 512, 512, 0,
        bufPS, nullptr, nullptr, nullptr, nullptr, cs1_5, cs2_5);
    statsK<<<1, B256, 0, stream>>>(cs1_5, cs2_5, stats5, 512);
    gnapplyK<0, 9><<<8192, B256, 0, stream>>>(bufPS, stats5, gn5g, gn5b, lcH, lcL);

    // 6. global pooling -> gv section of output (two-stage, 256 blocks)
    pool1K<<<dim3(32, 8), B256, 0, stream>>>(lcH, lcL, pmax, psum);
    pool2K<<<dim3(8), B256, 0, stream>>>(pmax, psum, out + (long)8 * 128 * 2048);

    // 7. mlp1 -> pre + colsums; GN6 + relu -> h1
    mgemm<0, 2><<<dim3(16, 4, 8), B256, 0, stream>>>(
        lcH, lcL, 512, nu, nu, nu, nu, nu, nu,
        m1H, m1L, 0, 512, 512, 0,
        bufPS, nullptr, nullptr, nullptr, bm1, cs1_6, cs2_6);
    statsK<<<1, B256, 0, stream>>>(cs1_6, cs2_6, stats6, 512);
    gnapplyK<1, 9><<<8192, B256, 0, stream>>>(bufPS, stats6, gn6g, gn6b, h1H, h1L);

    // 8. mlp2 -> pre + colsums; GN7 + relu -> h2
    mgemm<0, 2><<<dim3(16, 2, 8), B256, 0, stream>>>(
        h1H, h1L, 512, nu, nu, nu, nu, nu, nu,
        m2H, m2L, 0, 512, 256, 0,
        bufPS, nullptr, nullptr, nullptr, bm2, cs1_7, cs2_7);
    statsK<<<1, B256, 0, stream>>>(cs1_7, cs2_7, stats7, 256);
    gnapplyK<1, 8><<<4096, B256, 0, stream>>>(bufPS, stats7, gn7g, gn7b, h2H, h2L);

    // 9. mlp3 -> pre + colsums; GN8 + relu + transpose -> emb (d_out)
    mgemm<0, 2><<<dim3(16, 1, 8), B256, 0, stream>>>(
        h2H, h2L, 256, nu, nu, nu, nu, nu, nu,
        m3H, m3L, 0, 256, 128, 0,
        bufPS, nullptr, nullptr, nullptr, bm3, cs1_8, cs2_8);
    statsK<<<1, B256, 0, stream>>>(cs1_8, cs2_8, stats8, 128);
    gnfinalK<<<dim3(32, 2, 8), B256, 0, stream>>>(bufPS, stats8, gn8g, gn8b, out);
}

// Round 6
// 472.799 us; speedup vs baseline: 2.5490x; 1.1843x over previous
//
#include <hip/hip_runtime.h>
#include <math.h>

#define N2 2048
#define LRELU_S 0.2f
#define BN4_RS 0.9999950000374997f   // rsqrt(1+1e-5)

typedef short bf16x8 __attribute__((ext_vector_type(8)));
typedef float f32x16 __attribute__((ext_vector_type(16)));

__device__ __forceinline__ unsigned short bhi(float v) { return (unsigned short)(__float_as_uint(v) >> 16); }
__device__ __forceinline__ float bhif(float v) { return __uint_as_float(__float_as_uint(v) & 0xFFFF0000u); }
__device__ __forceinline__ float bf2f(unsigned short u) { return __uint_as_float(((unsigned int)u) << 16); }

__device__ __forceinline__ void gl16(const void* g, void* l) {
    __builtin_amdgcn_global_load_lds((const __attribute__((address_space(1))) unsigned int*)g,
                                     (__attribute__((address_space(3))) unsigned int*)l, 16, 0, 0);
}

__device__ __forceinline__ f32x16 z16() {
    f32x16 v;
    #pragma unroll
    for (int i = 0; i < 16; ++i) v[i] = 0.f;
    return v;
}

#define MFMA32 __builtin_amdgcn_mfma_f32_32x32x16_bf16

// ---------------------------------------------------------------------------
// Split-bf16 3-pass MFMA GEMM.  out[bz][n][o] = sum_k A[b][n][k] * B[o][k]
// A sources are [B*2048][CA] hi/lo bf16 (activation layout, k contiguous).
// B is [O][Ktot] hi/lo bf16 (weight layout, k contiguous; bBs = batch stride for yn).
// ASRC: 0 single (a1, stride CA); 1 cat2 (x3t 128 | G 128); 2 cat4 (x1 64|x2 64|x3 128|x4 256)
// EPI:  0 fp32 store; 1 bn4-scale+bias+lrelu -> split hi/lo store; 2 +bias fp32 store + colsum atomics
// Tile: 128(M=n) x 128(N=o) x BK=32, 4 waves as 2x2 of 64x64, 32x32x16 MFMA.
// ---------------------------------------------------------------------------
template<int ASRC, int EPI>
__global__ __launch_bounds__(256) void mgemm(
    const unsigned short* __restrict__ a1H, const unsigned short* __restrict__ a1L, int CA,
    const unsigned short* __restrict__ a2H, const unsigned short* __restrict__ a2L,
    const unsigned short* __restrict__ a3H, const unsigned short* __restrict__ a3L,
    const unsigned short* __restrict__ a4H, const unsigned short* __restrict__ a4L,
    const unsigned short* __restrict__ bH,  const unsigned short* __restrict__ bL, long bBs,
    int Ktot, int OC, int bbase,
    float* __restrict__ outF,
    unsigned short* __restrict__ oH, unsigned short* __restrict__ oL,
    const float* __restrict__ epg, const float* __restrict__ epb,
    float* __restrict__ cs1, float* __restrict__ cs2)
{
    __shared__ alignas(16) unsigned short lAh[4096], lAl[4096], lBh[4096], lBl[4096];
    const int t  = threadIdx.x;
    const int n0 = blockIdx.x * 128;
    const int o0 = blockIdx.y * 128;
    const int bz = blockIdx.z;
    const int b  = bbase + bz;

    const int lane = t & 63;
    const int h    = lane >> 5;
    const int l31  = lane & 31;
    const int wid  = t >> 6;
    const int wm   = wid >> 1;
    const int wn   = wid & 1;
    const int sw   = (l31 >> 1) & 3;            // LDS chunk swizzle for frag reads

    f32x16 acc00 = z16(), acc01 = z16(), acc10 = z16(), acc11 = z16();

    // staging chunk ids (16B each); wave-consecutive lanes -> consecutive LDS chunks
    const int q0 = t, q1 = t + 256;
    const int r0 = q0 >> 2, p0 = q0 & 3, c0s = p0 ^ ((r0 >> 1) & 3);
    const int r1 = q1 >> 2, p1 = q1 & 3, c1s = p1 ^ ((r1 >> 1) & 3);

    // frag read row bases (ushort index)
    const int rA0 = (wm * 64 + l31) * 32, rA1 = rA0 + 1024;
    const int rB0 = (wn * 64 + l31) * 32, rB1 = rB0 + 1024;

    for (int kc = 0; kc < Ktot; kc += 32) {
        const unsigned short *sAH, *sAL; int koff, Cs;
        if (ASRC == 0)      { sAH = a1H; sAL = a1L; koff = kc;       Cs = CA; }
        else if (ASRC == 1) {
            if (kc < 128)   { sAH = a1H; sAL = a1L; koff = kc;       Cs = 128; }
            else            { sAH = a2H; sAL = a2L; koff = kc - 128; Cs = 128; }
        } else {
            if (kc < 64)        { sAH = a1H; sAL = a1L; koff = kc;       Cs = 64;  }
            else if (kc < 128)  { sAH = a2H; sAL = a2L; koff = kc - 64;  Cs = 64;  }
            else if (kc < 256)  { sAH = a3H; sAL = a3L; koff = kc - 128; Cs = 128; }
            else                { sAH = a4H; sAL = a4L; koff = kc - 256; Cs = 256; }
        }
        __syncthreads();
        {
            long ga = ((long)b * N2 + n0 + r0) * Cs + koff + c0s * 8;
            gl16(sAH + ga, lAh + q0 * 8);
            gl16(sAL + ga, lAl + q0 * 8);
            long gb = (long)b * bBs + (long)(o0 + r0) * Ktot + kc + c0s * 8;
            gl16(bH + gb, lBh + q0 * 8);
            gl16(bL + gb, lBl + q0 * 8);
            ga = ((long)b * N2 + n0 + r1) * Cs + koff + c1s * 8;
            gl16(sAH + ga, lAh + q1 * 8);
            gl16(sAL + ga, lAl + q1 * 8);
            gb = (long)b * bBs + (long)(o0 + r1) * Ktot + kc + c1s * 8;
            gl16(bH + gb, lBh + q1 * 8);
            gl16(bL + gb, lBl + q1 * 8);
        }
        __syncthreads();
        #pragma unroll
        for (int s = 0; s < 2; ++s) {
            const int off = ((s * 2 + h) ^ sw) * 8;
            bf16x8 a0h = *(const bf16x8*)(lAh + rA0 + off);
            bf16x8 a0l = *(const bf16x8*)(lAl + rA0 + off);
            bf16x8 a1h_ = *(const bf16x8*)(lAh + rA1 + off);
            bf16x8 a1l_ = *(const bf16x8*)(lAl + rA1 + off);
            bf16x8 b0h = *(const bf16x8*)(lBh + rB0 + off);
            bf16x8 b0l = *(const bf16x8*)(lBl + rB0 + off);
            bf16x8 b1h = *(const bf16x8*)(lBh + rB1 + off);
            bf16x8 b1l = *(const bf16x8*)(lBl + rB1 + off);
            acc00 = MFMA32(a0h, b0h, acc00, 0, 0, 0);
            acc01 = MFMA32(a0h, b1h, acc01, 0, 0, 0);
            acc10 = MFMA32(a1h_, b0h, acc10, 0, 0, 0);
            acc11 = MFMA32(a1h_, b1h, acc11, 0, 0, 0);
            acc00 = MFMA32(a0h, b0l, acc00, 0, 0, 0);
            acc00 = MFMA32(a0l, b0h, acc00, 0, 0, 0);
            acc01 = MFMA32(a0h, b1l, acc01, 0, 0, 0);
            acc01 = MFMA32(a0l, b1h, acc01, 0, 0, 0);
            acc10 = MFMA32(a1h_, b0l, acc10, 0, 0, 0);
            acc10 = MFMA32(a1l_, b0h, acc10, 0, 0, 0);
            acc11 = MFMA32(a1h_, b1l, acc11, 0, 0, 0);
            acc11 = MFMA32(a1l_, b1h, acc11, 0, 0, 0);
        }
    }

    // epilogue: D col = lane&31 (o), row = (r&3) + 8*(r>>2) + 4*h (+ mi*32 + wm*64)
    #pragma unroll
    for (int ni = 0; ni < 2; ++ni) {
        const int o = o0 + wn * 64 + ni * 32 + l31;
        float sc = 0.f, sh = 0.f, bias = 0.f;
        if (EPI == 1) { sc = epg[o] * BN4_RS; sh = epb[o]; }
        if (EPI == 2) { bias = epb ? epb[o] : 0.f; }
        float s1 = 0.f, s2 = 0.f;
        #pragma unroll
        for (int mi = 0; mi < 2; ++mi) {
            #pragma unroll
            for (int r = 0; r < 16; ++r) {
                const int n = n0 + wm * 64 + mi * 32 + (r & 3) + 8 * (r >> 2) + 4 * h;
                float v = (ni == 0) ? (mi == 0 ? acc00[r] : acc10[r])
                                    : (mi == 0 ? acc01[r] : acc11[r]);
                const long oi = ((long)bz * N2 + n) * (long)OC + o;
                if (EPI == 0) {
                    outF[oi] = v;
                } else if (EPI == 1) {
                    v = fmaf(v, sc, sh);
                    v = v >= 0.f ? v : LRELU_S * v;
                    oH[oi] = bhi(v); oL[oi] = bhi(v - bhif(v));
                } else {
                    v += bias;
                    outF[oi] = v;
                    s1 += v; s2 = fmaf(v, v, s2);
                }
            }
        }
        if (EPI == 2) {
            s1 += __shfl_xor(s1, 32);
            s2 += __shfl_xor(s2, 32);
            if (h == 0) {
                atomicAdd(cs1 + bz * OC + o, s1);
                atomicAdd(cs2 + bz * OC + o, s2);
            }
        }
    }
}

// ---------------------------------------------------------------------------
// inverse norms over C=128 channels for x3 (z=0) and y3 (z=1)
__global__ void normK(const float* __restrict__ x3, const float* __restrict__ y3,
                      float* __restrict__ invnx, float* __restrict__ invny)
{
    const int n = blockIdx.x * 256 + threadIdx.x;
    const int b = blockIdx.y;
    const float* src = blockIdx.z ? y3 : x3;
    float ss = 0.f;
    for (int c = 0; c < 128; ++c) {
        float v = src[((long)b * 128 + c) * N2 + n];
        ss = fmaf(v, v, ss);
    }
    (blockIdx.z ? invny : invnx)[b * N2 + n] = rsqrtf(ss);
}

// ---------------------------------------------------------------------------
// transpose [C][2048] -> [2048][C] with bf16 split.  MODE bits:
//  1 = write unscaled hi/lo; 2 = write invn-scaled hi/lo; 4 = write fp32 transposed
template<int MODE>
__global__ __launch_bounds__(256) void tsplitK(
    const float* __restrict__ in, int C,
    unsigned short* __restrict__ tHi, unsigned short* __restrict__ tLo,
    const float* __restrict__ invn,
    unsigned short* __restrict__ sHi, unsigned short* __restrict__ sLo,
    float* __restrict__ tF)
{
    __shared__ float lt[64 * 65];
    const int t = threadIdx.x;
    const int n0 = blockIdx.x * 64, c0 = blockIdx.y * 64, b = blockIdx.z;
    {
        const int nl = t & 63;
        const int cb = t >> 6;
        #pragma unroll
        for (int i = 0; i < 16; ++i) {
            const int cl = cb + 4 * i;
            lt[nl * 65 + cl] = in[((long)b * C + c0 + cl) * N2 + n0 + nl];
        }
    }
    __syncthreads();
    const int cl = t & 63;
    const int nb = t >> 6;
    #pragma unroll
    for (int i = 0; i < 16; ++i) {
        const int nl = nb + 4 * i;
        const float v = lt[nl * 65 + cl];
        const long oi = ((long)b * N2 + n0 + nl) * C + c0 + cl;
        if (MODE & 1) { tHi[oi] = bhi(v); tLo[oi] = bhi(v - bhif(v)); }
        if (MODE & 2) {
            const float svv = v * invn[b * N2 + n0 + nl];
            sHi[oi] = bhi(svv); sLo[oi] = bhi(svv - bhif(svv));
        }
        if (MODE & 4) tF[oi] = v;
    }
}

// ---------------------------------------------------------------------------
// weight fold (w4) + bf16 split for all 5 weight tensors; blockIdx.y selects
__global__ void wsplitK(const float* __restrict__ w4, const float* __restrict__ w5,
    const float* __restrict__ wm1, const float* __restrict__ wm2, const float* __restrict__ wm3,
    unsigned short* __restrict__ w4h, unsigned short* __restrict__ w4l,
    unsigned short* __restrict__ w5h, unsigned short* __restrict__ w5l,
    unsigned short* __restrict__ m1h, unsigned short* __restrict__ m1l,
    unsigned short* __restrict__ m2h, unsigned short* __restrict__ m2l,
    unsigned short* __restrict__ m3h, unsigned short* __restrict__ m3l)
{
    const int y = blockIdx.y;
    const int idx = blockIdx.x * 256 + threadIdx.x;
    float v; unsigned short *dh, *dl;
    if (y == 0) {
        if (idx >= 256 * 256) return;
        const int k = idx & 255;
        v = w4[idx];
        if (k < 128) v -= w4[idx + 128];
        dh = w4h; dl = w4l;
    } else if (y == 1) {
        if (idx >= 512 * 512) return;
        v = w5[idx]; dh = w5h; dl = w5l;
    } else if (y == 2) {
        if (idx >= 512 * 512) return;
        v = wm1[idx]; dh = m1h; dl = m1l;
    } else if (y == 3) {
        if (idx >= 256 * 512) return;
        v = wm2[idx]; dh = m2h; dl = m2l;
    } else {
        if (idx >= 128 * 256) return;
        v = wm3[idx]; dh = m3h; dl = m3l;
    }
    dh[idx] = bhi(v); dl[idx] = bhi(v - bhif(v));
}

// ---------------------------------------------------------------------------
// top-20 of a 2048 simi row via 4-pass radix select + softmax weights.
// Row layout [bl][n][2048]. Thread t owns indices {4t..4t+3, 1024+4t..1024+4t+3}.
__global__ __launch_bounds__(256) void topkK(const float* __restrict__ simi,
    float* __restrict__ topw, int* __restrict__ topi, int bbase)
{
    __shared__ unsigned int hist[256];
    __shared__ unsigned int bcast[2];
    __shared__ unsigned int cnt[2];
    __shared__ float selv[20];
    __shared__ int   seli[20];
    const int t  = threadIdx.x;
    const int n  = blockIdx.x;
    const int bl = blockIdx.y;
    const float* row = simi + ((long)bl * N2 + n) * N2;

    float    f[8];
    unsigned u[8];
    {
        const float4 v0 = *(const float4*)(row + 4 * t);
        const float4 v1 = *(const float4*)(row + 1024 + 4 * t);
        f[0] = v0.x; f[1] = v0.y; f[2] = v0.z; f[3] = v0.w;
        f[4] = v1.x; f[5] = v1.y; f[6] = v1.z; f[7] = v1.w;
        #pragma unroll
        for (int i = 0; i < 8; ++i) {
            unsigned ub = __float_as_uint(f[i]);
            u[i] = ub ^ (((int)ub >> 31) | 0x80000000u);   // order-preserving flip
        }
    }

    unsigned prefix = 0;
    unsigned kneed  = 20;
    #pragma unroll
    for (int pass = 0; pass < 4; ++pass) {
        const int shift = 24 - 8 * pass;
        const unsigned pmask = (pass == 0) ? 0u : (0xFFFFFFFFu << (shift + 8));
        hist[t] = 0;
        __syncthreads();
        #pragma unroll
        for (int i = 0; i < 8; ++i)
            if ((u[i] & pmask) == prefix)
                atomicAdd(&hist[(u[i] >> shift) & 255], 1u);
        __syncthreads();
        if (t < 64) {
            const unsigned h0 = hist[4 * t], h1 = hist[4 * t + 1];
            const unsigned h2 = hist[4 * t + 2], h3 = hist[4 * t + 3];
            const unsigned s3 = h3, s2 = h2 + s3, s1 = h1 + s2, s0 = h0 + s1;
            unsigned inc = s0;
            #pragma unroll
            for (int off = 1; off < 64; off <<= 1) {
                const unsigned o = __shfl_down(inc, off);
                if (t + off < 64) inc += o;
            }
            const unsigned excl = inc - s0;               // count in lanes > t
            const unsigned sf[5] = {excl + s0, excl + s1, excl + s2, excl + s3, excl};
            #pragma unroll
            for (int j = 0; j < 4; ++j) {
                if (sf[j] >= kneed && sf[j + 1] < kneed) {
                    bcast[0] = 4 * t + j;
                    bcast[1] = kneed - sf[j + 1];
                }
            }
        }
        __syncthreads();
        prefix |= bcast[0] << shift;
        kneed   = bcast[1];
        __syncthreads();
    }

    if (t == 0) { cnt[0] = 0; cnt[1] = 0; }
    __syncthreads();
    const unsigned Tu = prefix;
    const int eqneed = (int)kneed;                        // equals to take
    const int gt     = 20 - eqneed;                       // strictly-greater count
    #pragma unroll
    for (int i = 0; i < 8; ++i) {
        const int idx = (i < 4) ? (4 * t + i) : (1024 + 4 * t + (i - 4));
        if (u[i] > Tu) {
            const unsigned s = atomicAdd(&cnt[0], 1u);
            selv[s] = f[i]; seli[s] = idx;
        } else if (u[i] == Tu) {
            const unsigned e = atomicAdd(&cnt[1], 1u);
            if ((int)e < eqneed) { selv[gt + e] = f[i]; seli[gt + e] = idx; }
        }
    }
    __syncthreads();

    if (t < 64) {
        const float v = (t < 20) ? selv[t] : -1e30f;
        float m = v;
        #pragma unroll
        for (int off = 1; off < 32; off <<= 1) m = fmaxf(m, __shfl_xor(m, off, 32));
        const float e = (t < 20) ? expf(v - m) : 0.f;
        float s = e;
        #pragma unroll
        for (int off = 1; off < 32; off <<= 1) s += __shfl_xor(s, off, 32);
        if (t < 20) {
            const long base = (((long)(bbase + bl)) * N2 + n) * 20;
            topw[base + t] = e / s;
            topi[base + t] = seli[t];
        }
    }
}

// ---------------------------------------------------------------------------
// G[n][c] = sum_k w_k * yT[idx_k][c], written as split bf16.
// Grid (8 b, 256 chunks) -- b fastest so consecutive blocks (round-robin XCD)
// work on different batches: XCD i caches mostly yT[b==i] (1 MB, L2-resident).
// Block: 256 thr = 32 c-quads (float4) x 8 n.  20 independent float4 gathers.
__global__ __launch_bounds__(256) void aggK(const float* __restrict__ yT,
    const float* __restrict__ topw, const int* __restrict__ topi,
    unsigned short* __restrict__ Gh, unsigned short* __restrict__ Gl)
{
    const int t  = threadIdx.x;
    const int c4 = (t & 31) * 4;
    const int ns = t >> 5;                   // 0..7
    const int b  = blockIdx.x;               // fastest grid dim
    const int n  = blockIdx.y * 8 + ns;
    const long tb = ((long)b * N2 + n) * 20;
    const float* yb = yT + (long)b * N2 * 128 + c4;

    float a0 = 0.f, a1 = 0.f, a2 = 0.f, a3 = 0.f;
    #pragma unroll
    for (int k = 0; k < 20; ++k) {
        const float w  = topw[tb + k];
        const int  idx = topi[tb + k];
        const float4 v = *(const float4*)(yb + (long)idx * 128);
        a0 = fmaf(w, v.x, a0);
        a1 = fmaf(w, v.y, a1);
        a2 = fmaf(w, v.z, a2);
        a3 = fmaf(w, v.w, a3);
    }
    const long oi = ((long)b * N2 + n) * 128 + c4;
    ushort4 hh, ll;
    hh.x = bhi(a0); ll.x = bhi(a0 - bhif(a0));
    hh.y = bhi(a1); ll.y = bhi(a1 - bhif(a1));
    hh.z = bhi(a2); ll.z = bhi(a2 - bhif(a2));
    hh.w = bhi(a3); ll.w = bhi(a3 - bhif(a3));
    *(ushort4*)(Gh + oi) = hh;
    *(ushort4*)(Gl + oi) = ll;
}

// ---------------------------------------------------------------------------
// reduce per-column sums to per-(b,group) GN stats;  one block of 256 = 8b x 32g
__global__ void statsK(const float* __restrict__ cs1, const float* __restrict__ cs2,
    float* __restrict__ stats, int C)
{
    const int t = threadIdx.x;
    const int b = t >> 5, g = t & 31;
    const int cpg = C >> 5;
    float s1 = 0.f, s2 = 0.f;
    for (int j = 0; j < cpg; ++j) {
        s1 += cs1[b * C + g * cpg + j];
        s2 += cs2[b * C + g * cpg + j];
    }
    const float cnt = (float)(cpg * N2);
    const float mu = s1 / cnt;
    const float var = s2 / cnt - mu * mu;
    stats[t * 2] = mu;
    stats[t * 2 + 1] = rsqrtf(var + 1e-5f);
}

// ---------------------------------------------------------------------------
// GN apply + activation, fp32 [n][C] -> split bf16 [n][C].  ACT 0=lrelu 1=relu
template<int ACT, int LC>
__global__ void gnapplyK(const float* __restrict__ pre, const float* __restrict__ stats,
    const float* __restrict__ gamma, const float* __restrict__ beta,
    unsigned short* __restrict__ oH, unsigned short* __restrict__ oL)
{
    const long i4 = ((long)blockIdx.x * 256 + threadIdx.x) * 4;
    const int C = 1 << LC;
    const int c = (int)(i4 & (C - 1));
    const int bn = (int)(i4 >> LC);
    const int b = bn >> 11;
    const int g = c >> (LC - 5);
    const float mu = stats[(b * 32 + g) * 2];
    const float rs = stats[(b * 32 + g) * 2 + 1];
    const float4 gm = *(const float4*)(gamma + c);
    const float4 bt = *(const float4*)(beta + c);
    const float4 v = *(const float4*)(pre + i4);
    const float vals[4] = {v.x, v.y, v.z, v.w};
    const float gms[4] = {gm.x, gm.y, gm.z, gm.w};
    const float bts[4] = {bt.x, bt.y, bt.z, bt.w};
    unsigned short hs[4], ls[4];
    #pragma unroll
    for (int j = 0; j < 4; ++j) {
        float x = (vals[j] - mu) * (rs * gms[j]) + bts[j];
        x = (ACT == 0) ? (x >= 0.f ? x : LRELU_S * x) : (x >= 0.f ? x : 0.f);
        hs[j] = bhi(x); ls[j] = bhi(x - bhif(x));
    }
    ushort4 hh; hh.x = hs[0]; hh.y = hs[1]; hh.z = hs[2]; hh.w = hs[3];
    ushort4 ll; ll.x = ls[0]; ll.y = ls[1]; ll.z = ls[2]; ll.w = ls[3];
    *(ushort4*)(oH + i4) = hh;
    *(ushort4*)(oL + i4) = ll;
}

// ---------------------------------------------------------------------------
// final GN8 + relu + transpose to out[b][128][2048]
__global__ __launch_bounds__(256) void gnfinalK(const float* __restrict__ pre,
    const float* __restrict__ stats, const float* __restrict__ gamma,
    const float* __restrict__ beta, float* __restrict__ out)
{
    __shared__ float lt[64 * 65];
    const int t = threadIdx.x;
    const int n0 = blockIdx.x * 64, c0 = blockIdx.y * 64, b = blockIdx.z;
    {
        const int cl = t & 63;
        const int nb = t >> 6;
        const int c = c0 + cl;
        const int g = c >> 2;
        const float mu = stats[(b * 32 + g) * 2];
        const float rs = stats[(b * 32 + g) * 2 + 1];
        const float sc = rs * gamma[c], sh = beta[c] - mu * sc;
        #pragma unroll
        for (int i = 0; i < 16; ++i) {
            const int nl = nb + 4 * i;
            float v = pre[((long)b * N2 + n0 + nl) * 128 + c];
            v = v * sc + sh;
            lt[cl * 65 + nl] = v > 0.f ? v : 0.f;
        }
    }
    __syncthreads();
    const int nl = t & 63;
    const int cb = t >> 6;
    #pragma unroll
    for (int i = 0; i < 16; ++i) {
        const int cl = cb + 4 * i;
        out[((long)b * 128 + c0 + cl) * N2 + n0 + nl] = lt[cl * 65 + nl];
    }
}

// ---------------------------------------------------------------------------
// pooling stage 1: per (b, n-chunk of 64) partial max/sum over all 512 channels
// lc layout [b][n][512] split bf16; 256 threads = 128 c-quads x 2 row-parities
__global__ __launch_bounds__(256) void pool1K(const unsigned short* __restrict__ lcH,
    const unsigned short* __restrict__ lcL, float* __restrict__ pmax, float* __restrict__ psum)
{
    __shared__ float lmx[512], lsm[512];
    const int t  = threadIdx.x;
    const int cq = t & 127;          // channel quad: channels 4*cq..4*cq+3
    const int rp = t >> 7;           // row parity
    const int nch = blockIdx.x;      // 0..31 (64 rows each)
    const int b   = blockIdx.y;
    float mx[4] = {-1e30f, -1e30f, -1e30f, -1e30f};
    float sm[4] = {0.f, 0.f, 0.f, 0.f};
    for (int i = 0; i < 32; ++i) {
        const int n = nch * 64 + 2 * i + rp;
        const long base = ((long)b * N2 + n) * 512 + cq * 4;
        const ushort4 hh = *(const ushort4*)(lcH + base);
        const ushort4 ll = *(const ushort4*)(lcL + base);
        const float v0 = bf2f(hh.x) + bf2f(ll.x);
        const float v1 = bf2f(hh.y) + bf2f(ll.y);
        const float v2 = bf2f(hh.z) + bf2f(ll.z);
        const float v3 = bf2f(hh.w) + bf2f(ll.w);
        mx[0] = fmaxf(mx[0], v0); sm[0] += v0;
        mx[1] = fmaxf(mx[1], v1); sm[1] += v1;
        mx[2] = fmaxf(mx[2], v2); sm[2] += v2;
        mx[3] = fmaxf(mx[3], v3); sm[3] += v3;
    }
    if (rp) {
        #pragma unroll
        for (int j = 0; j < 4; ++j) { lmx[cq * 4 + j] = mx[j]; lsm[cq * 4 + j] = sm[j]; }
    }
    __syncthreads();
    if (!rp) {
        const long pb = ((long)(b * 32 + nch)) * 512 + cq * 4;
        #pragma unroll
        for (int j = 0; j < 4; ++j) {
            pmax[pb + j] = fmaxf(mx[j], lmx[cq * 4 + j]);
            psum[pb + j] = sm[j] + lsm[cq * 4 + j];
        }
    }
}

// pooling stage 2: reduce 32 chunk partials -> gv[b][1024] (max | mean)
__global__ void pool2K(const float* __restrict__ pmax, const float* __restrict__ psum,
                       float* __restrict__ gv)
{
    const int t = threadIdx.x;       // 256: 2 channels each
    const int b = blockIdx.x;
    float mx0 = -1e30f, mx1 = -1e30f, s0 = 0.f, s1 = 0.f;
    for (int nch = 0; nch < 32; ++nch) {
        const long pb = ((long)(b * 32 + nch)) * 512 + 2 * t;
        const float2 pm = *(const float2*)(pmax + pb);
        const float2 ps = *(const float2*)(psum + pb);
        mx0 = fmaxf(mx0, pm.x); mx1 = fmaxf(mx1, pm.y);
        s0 += ps.x; s1 += ps.y;
    }
    gv[b * 1024 + 2 * t]           = mx0;
    gv[b * 1024 + 2 * t + 1]       = mx1;
    gv[b * 1024 + 512 + 2 * t]     = s0 * (1.f / 2048.f);
    gv[b * 1024 + 512 + 2 * t + 1] = s1 * (1.f / 2048.f);
}

// ---------------------------------------------------------------------------
extern "C" void kernel_launch(void* const* d_in, const int* in_sizes, int n_in,
                              void* d_out, int out_size, void* d_ws, size_t ws_size,
                              hipStream_t stream)
{
    const float* x1    = (const float*)d_in[0];
    const float* x2    = (const float*)d_in[1];
    const float* x3    = (const float*)d_in[2];
    const float* y3    = (const float*)d_in[3];
    const float* w4    = (const float*)d_in[4];
    const float* bn4g  = (const float*)d_in[5];
    const float* bn4b  = (const float*)d_in[6];
    const float* w5    = (const float*)d_in[7];
    const float* gn5g  = (const float*)d_in[8];
    const float* gn5b  = (const float*)d_in[9];
    const float* wm1   = (const float*)d_in[10];
    const float* bm1   = (const float*)d_in[11];
    const float* gn6g  = (const float*)d_in[12];
    const float* gn6b  = (const float*)d_in[13];
    const float* wm2   = (const float*)d_in[14];
    const float* bm2   = (const float*)d_in[15];
    const float* gn7g  = (const float*)d_in[16];
    const float* gn7b  = (const float*)d_in[17];
    const float* wm3   = (const float*)d_in[18];
    const float* bm3   = (const float*)d_in[19];
    const float* gn8g  = (const float*)d_in[20];
    const float* gn8b  = (const float*)d_in[21];
    float* out = (float*)d_out;
    (void)in_sizes; (void)n_in; (void)out_size; (void)ws_size;

    char* ws = (char*)d_ws;
    // ---- arena (aliased regions; ~120 MB total) ----
    float*          bufPS = (float*)(ws + 0);                         // 33.55 MB: simi chunks, then GEMM pre
    unsigned short* lcH   = (unsigned short*)(ws + 33554432);         // 16.78 MB
    unsigned short* lcL   = (unsigned short*)(ws + 50331648);         // 16.78 MB
    const size_t R3 = 67108864;                                       // 33.55 MB region
    float*          yT    = (float*)(ws + R3);                        //  8.39 MB
    unsigned short* x3tH  = (unsigned short*)(ws + R3 + 8388608);
    unsigned short* x3tL  = (unsigned short*)(ws + R3 + 12582912);
    unsigned short* x1tH  = (unsigned short*)(ws + R3 + 16777216);
    unsigned short* x1tL  = (unsigned short*)(ws + R3 + 18874368);
    unsigned short* x2tH  = (unsigned short*)(ws + R3 + 20971520);
    unsigned short* x2tL  = (unsigned short*)(ws + R3 + 23068672);
    unsigned short* GH    = (unsigned short*)(ws + R3 + 25165824);
    unsigned short* GL    = (unsigned short*)(ws + R3 + 29360128);
    unsigned short* h1H   = (unsigned short*)(ws + R3);               // alias (after conv5/agg/conv4 done)
    unsigned short* h1L   = (unsigned short*)(ws + R3 + 16777216);
    const size_t R4 = 100663296;                                      // 16.78 MB region
    unsigned short* xnH   = (unsigned short*)(ws + R4);
    unsigned short* xnL   = (unsigned short*)(ws + R4 + 4194304);
    unsigned short* ynH   = (unsigned short*)(ws + R4 + 8388608);
    unsigned short* ynL   = (unsigned short*)(ws + R4 + 12582912);
    unsigned short* x4H   = (unsigned short*)(ws + R4);               // alias (after simi done)
    unsigned short* x4L   = (unsigned short*)(ws + R4 + 8388608);
    unsigned short* h2H   = (unsigned short*)(ws + R4);               // alias (after conv5 done)
    unsigned short* h2L   = (unsigned short*)(ws + R4 + 8388608);
    const size_t W = 117440512;
    unsigned short* w4pH = (unsigned short*)(ws + W);
    unsigned short* w4pL = (unsigned short*)(ws + W + 131072);
    unsigned short* w5H  = (unsigned short*)(ws + W + 262144);
    unsigned short* w5L  = (unsigned short*)(ws + W + 786432);
    unsigned short* m1H  = (unsigned short*)(ws + W + 1310720);
    unsigned short* m1L  = (unsigned short*)(ws + W + 1835008);
    unsigned short* m2H  = (unsigned short*)(ws + W + 2359296);
    unsigned short* m2L  = (unsigned short*)(ws + W + 2621440);
    unsigned short* m3H  = (unsigned short*)(ws + W + 2883584);
    unsigned short* m3L  = (unsigned short*)(ws + W + 2949120);
    const size_t M = W + 3145728;
    float* invnx = (float*)(ws + M);
    float* invny = (float*)(ws + M + 65536);
    float* topw  = (float*)(ws + M + 131072);
    int*   topi  = (int*)  (ws + M + 1441792);
    float* csb   = (float*)(ws + M + 2752512);                        // 128 KB
    float* cs1_5 = csb,          *cs2_5 = csb + 4096;
    float* cs1_6 = csb + 8192,   *cs2_6 = csb + 12288;
    float* cs1_7 = csb + 16384,  *cs2_7 = csb + 20480;
    float* cs1_8 = csb + 24576,  *cs2_8 = csb + 28672;
    float* stats5 = (float*)(ws + M + 2883584);
    float* stats6 = stats5 + 512;
    float* stats7 = stats5 + 1024;
    float* stats8 = stats5 + 1536;
    float* pmax  = (float*)(ws + M + 2891776);                        // 512 KB
    float* psum  = (float*)(ws + M + 3416064);                        // 512 KB

    const dim3 B256(256);
    const unsigned short* nu = nullptr;

    // 0. zero colsum accumulators (ws is poisoned each launch)
    hipMemsetAsync(csb, 0, 131072, stream);

    // 1. norms, transposes + bf16 splits, weight folds/splits
    normK<<<dim3(8, 8, 2), B256, 0, stream>>>(x3, y3, invnx, invny);
    tsplitK<6><<<dim3(32, 2, 8), B256, 0, stream>>>(y3, 128, nullptr, nullptr, invny, ynH, ynL, yT);
    tsplitK<3><<<dim3(32, 2, 8), B256, 0, stream>>>(x3, 128, x3tH, x3tL, invnx, xnH, xnL, nullptr);
    tsplitK<1><<<dim3(32, 1, 8), B256, 0, stream>>>(x1, 64, x1tH, x1tL, nullptr, nullptr, nullptr, nullptr);
    tsplitK<1><<<dim3(32, 1, 8), B256, 0, stream>>>(x2, 64, x2tH, x2tL, nullptr, nullptr, nullptr, nullptr);
    wsplitK<<<dim3(1024, 5), B256, 0, stream>>>(w4, w5, wm1, wm2, wm3,
        w4pH, w4pL, w5H, w5L, m1H, m1L, m2H, m2L, m3H, m3L);

    // 2. simi (split-bf16 MFMA) + radix topk, 2 batches per chunk
    for (int ch = 0; ch < 4; ++ch) {
        mgemm<0, 0><<<dim3(16, 16, 2), B256, 0, stream>>>(
            xnH, xnL, 128, nu, nu, nu, nu, nu, nu,
            ynH, ynL, (long)N2 * 128, 128, 2048, ch * 2,
            bufPS, nullptr, nullptr, nullptr, nullptr, nullptr, nullptr);
        topkK<<<dim3(2048, 2), B256, 0, stream>>>(bufPS, topw, topi, ch * 2);
    }

    // 3. gather-aggregate G (split bf16); b fastest for XCD-L2 locality
    aggK<<<dim3(8, 256), B256, 0, stream>>>(yT, topw, topi, GH, GL);

    // 4. conv4 (+BN eval + lrelu) over [x3 | G] with folded W4' -> x4 hi/lo
    mgemm<1, 1><<<dim3(16, 2, 8), B256, 0, stream>>>(
        x3tH, x3tL, 128, GH, GL, nu, nu, nu, nu,
        w4pH, w4pL, 0, 256, 256, 0,
        nullptr, x4H, x4L, bn4g, bn4b, nullptr, nullptr);

    // 5. conv5 over [x1|x2|x3|x4] -> pre (bufPS) + colsums; GN5 + lrelu -> lc
    mgemm<2, 2><<<dim3(16, 4, 8), B256, 0, stream>>>(
        x1tH, x1tL, 64, x2tH, x2tL, x3tH, x3tL, x4H, x4L,
        w5H, w5L, 0, 512, 512, 0,
        bufPS, nullptr, nullptr, nullptr, nullptr, cs1_5, cs2_5);
    statsK<<<1, B256, 0, stream>>>(cs1_5, cs2_5, stats5, 512);
    gnapplyK<0, 9><<<8192, B256, 0, stream>>>(bufPS, stats5, gn5g, gn5b, lcH, lcL);

    // 6. global pooling -> gv section of output (two-stage, 256 blocks)
    pool1K<<<dim3(32, 8), B256, 0, stream>>>(lcH, lcL, pmax, psum);
    pool2K<<<dim3(8), B256, 0, stream>>>(pmax, psum, out + (long)8 * 128 * 2048);

    // 7. mlp1 -> pre + colsums; GN6 + relu -> h1
    mgemm<0, 2><<<dim3(16, 4, 8), B256, 0, stream>>>(
        lcH, lcL, 512, nu, nu, nu, nu, nu, nu,
        m1H, m1L, 0, 512, 512, 0,
        bufPS, nullptr, nullptr, nullptr, bm1, cs1_6, cs2_6);
    statsK<<<1, B256, 0, stream>>>(cs1_6, cs2_6, stats6, 512);
    gnapplyK<1, 9><<<8192, B256, 0, stream>>>(bufPS, stats6, gn6g, gn6b, h1H, h1L);

    // 8. mlp2 -> pre + colsums; GN7 + relu -> h2
    mgemm<0, 2><<<dim3(16, 2, 8), B256, 0, stream>>>(
        h1H, h1L, 512, nu, nu, nu, nu, nu, nu,
        m2H, m2L, 0, 512, 256, 0,
        bufPS, nullptr, nullptr, nullptr, bm2, cs1_7, cs2_7);
    statsK<<<1, B256, 0, stream>>>(cs1_7, cs2_7, stats7, 256);
    gnapplyK<1, 8><<<4096, B256, 0, stream>>>(bufPS, stats7, gn7g, gn7b, h2H, h2L);

    // 9. mlp3 -> pre + colsums; GN8 + relu + transpose -> emb (d_out)
    mgemm<0, 2><<<dim3(16, 1, 8), B256, 0, stream>>>(
        h2H, h2L, 256, nu, nu, nu, nu, nu, nu,
        m3H, m3L, 0, 256, 128, 0,
        bufPS, nullptr, nullptr, nullptr, bm3, cs1_8, cs2_8);
    statsK<<<1, B256, 0, stream>>>(cs1_8, cs2_8, stats8, 128);
    gnfinalK<<<dim3(32, 2, 8), B256, 0, stream>>>(bufPS, stats8, gn8g, gn8b, out);
}

// Round 7
// 389.472 us; speedup vs baseline: 3.0944x; 1.2140x over previous
//
#include <hip/hip_runtime.h>
#include <math.h>

#define N2 2048
#define LRELU_S 0.2f
#define BN4_RS 0.9999950000374997f   // rsqrt(1+1e-5)

typedef short bf16x8 __attribute__((ext_vector_type(8)));
typedef float f32x16 __attribute__((ext_vector_type(16)));

__device__ __forceinline__ unsigned short bhi(float v) { return (unsigned short)(__float_as_uint(v) >> 16); }
__device__ __forceinline__ float bhif(float v) { return __uint_as_float(__float_as_uint(v) & 0xFFFF0000u); }
__device__ __forceinline__ float bf2f(unsigned short u) { return __uint_as_float(((unsigned int)u) << 16); }

__device__ __forceinline__ void gl16(const void* g, void* l) {
    __builtin_amdgcn_global_load_lds((const __attribute__((address_space(1))) unsigned int*)g,
                                     (__attribute__((address_space(3))) unsigned int*)l, 16, 0, 0);
}

__device__ __forceinline__ f32x16 z16() {
    f32x16 v;
    #pragma unroll
    for (int i = 0; i < 16; ++i) v[i] = 0.f;
    return v;
}

#define MFMA32 __builtin_amdgcn_mfma_f32_32x32x16_bf16

// ---------------------------------------------------------------------------
// Split-bf16 MFMA GEMM.  out[bz][n][o] = sum_k A[b][n][k] * B[o][k]
// PASSES: 3 = hi*hi + hi*lo + lo*hi (err ~2^-16, used for simi/topk selection)
//         1 = hi*hi only            (err ~2^-9, conv/mlp path; GN absorbs it)
// ASRC: 0 single (a1, stride CA); 1 cat2 (x3t 128 | G 128); 2 cat4 (x1|x2|x3|x4)
// EPI:  0 fp32 store; 1 bn4+lrelu -> hi bf16 store; 2 +bias fp32 store + colsum atomics
// Tile: 128(M=n) x 128(N=o) x BK=32, 4 waves as 2x2 of 64x64, 32x32x16 MFMA.
// ---------------------------------------------------------------------------
template<int ASRC, int EPI, int PASSES>
__global__ __launch_bounds__(256) void mgemm(
    const unsigned short* __restrict__ a1H, const unsigned short* __restrict__ a1L, int CA,
    const unsigned short* __restrict__ a2H, const unsigned short* __restrict__ a2L,
    const unsigned short* __restrict__ a3H, const unsigned short* __restrict__ a3L,
    const unsigned short* __restrict__ a4H, const unsigned short* __restrict__ a4L,
    const unsigned short* __restrict__ bH,  const unsigned short* __restrict__ bL, long bBs,
    int Ktot, int OC, int bbase,
    float* __restrict__ outF, unsigned short* __restrict__ oH,
    const float* __restrict__ epg, const float* __restrict__ epb,
    float* __restrict__ cs1, float* __restrict__ cs2)
{
    __shared__ alignas(16) unsigned short lAh[4096], lBh[4096];
    __shared__ alignas(16) unsigned short lAl[PASSES == 3 ? 4096 : 16];
    __shared__ alignas(16) unsigned short lBl[PASSES == 3 ? 4096 : 16];
    const int t  = threadIdx.x;
    const int n0 = blockIdx.x * 128;
    const int o0 = blockIdx.y * 128;
    const int bz = blockIdx.z;
    const int b  = bbase + bz;

    const int lane = t & 63;
    const int h    = lane >> 5;
    const int l31  = lane & 31;
    const int wid  = t >> 6;
    const int wm   = wid >> 1;
    const int wn   = wid & 1;
    const int sw   = (l31 >> 1) & 3;            // LDS chunk swizzle for frag reads

    f32x16 acc00 = z16(), acc01 = z16(), acc10 = z16(), acc11 = z16();

    // staging chunk ids (16B each); wave-consecutive lanes -> consecutive LDS chunks
    const int q0 = t, q1 = t + 256;
    const int r0 = q0 >> 2, p0 = q0 & 3, c0s = p0 ^ ((r0 >> 1) & 3);
    const int r1 = q1 >> 2, p1 = q1 & 3, c1s = p1 ^ ((r1 >> 1) & 3);

    // frag read row bases (ushort index)
    const int rA0 = (wm * 64 + l31) * 32, rA1 = rA0 + 1024;
    const int rB0 = (wn * 64 + l31) * 32, rB1 = rB0 + 1024;

    for (int kc = 0; kc < Ktot; kc += 32) {
        const unsigned short *sAH, *sAL; int koff, Cs;
        if (ASRC == 0)      { sAH = a1H; sAL = a1L; koff = kc;       Cs = CA; }
        else if (ASRC == 1) {
            if (kc < 128)   { sAH = a1H; sAL = a1L; koff = kc;       Cs = 128; }
            else            { sAH = a2H; sAL = a2L; koff = kc - 128; Cs = 128; }
        } else {
            if (kc < 64)        { sAH = a1H; sAL = a1L; koff = kc;       Cs = 64;  }
            else if (kc < 128)  { sAH = a2H; sAL = a2L; koff = kc - 64;  Cs = 64;  }
            else if (kc < 256)  { sAH = a3H; sAL = a3L; koff = kc - 128; Cs = 128; }
            else                { sAH = a4H; sAL = a4L; koff = kc - 256; Cs = 256; }
        }
        __syncthreads();
        {
            long ga = ((long)b * N2 + n0 + r0) * Cs + koff + c0s * 8;
            long gb = (long)b * bBs + (long)(o0 + r0) * Ktot + kc + c0s * 8;
            gl16(sAH + ga, lAh + q0 * 8);
            gl16(bH + gb, lBh + q0 * 8);
            if (PASSES == 3) { gl16(sAL + ga, lAl + q0 * 8); gl16(bL + gb, lBl + q0 * 8); }
            long ga1 = ((long)b * N2 + n0 + r1) * Cs + koff + c1s * 8;
            long gb1 = (long)b * bBs + (long)(o0 + r1) * Ktot + kc + c1s * 8;
            gl16(sAH + ga1, lAh + q1 * 8);
            gl16(bH + gb1, lBh + q1 * 8);
            if (PASSES == 3) { gl16(sAL + ga1, lAl + q1 * 8); gl16(bL + gb1, lBl + q1 * 8); }
        }
        __syncthreads();
        #pragma unroll
        for (int s = 0; s < 2; ++s) {
            const int off = ((s * 2 + h) ^ sw) * 8;
            bf16x8 a0h = *(const bf16x8*)(lAh + rA0 + off);
            bf16x8 a1h_ = *(const bf16x8*)(lAh + rA1 + off);
            bf16x8 b0h = *(const bf16x8*)(lBh + rB0 + off);
            bf16x8 b1h = *(const bf16x8*)(lBh + rB1 + off);
            acc00 = MFMA32(a0h, b0h, acc00, 0, 0, 0);
            acc01 = MFMA32(a0h, b1h, acc01, 0, 0, 0);
            acc10 = MFMA32(a1h_, b0h, acc10, 0, 0, 0);
            acc11 = MFMA32(a1h_, b1h, acc11, 0, 0, 0);
            if (PASSES == 3) {
                bf16x8 a0l = *(const bf16x8*)(lAl + rA0 + off);
                bf16x8 a1l_ = *(const bf16x8*)(lAl + rA1 + off);
                bf16x8 b0l = *(const bf16x8*)(lBl + rB0 + off);
                bf16x8 b1l = *(const bf16x8*)(lBl + rB1 + off);
                acc00 = MFMA32(a0h, b0l, acc00, 0, 0, 0);
                acc00 = MFMA32(a0l, b0h, acc00, 0, 0, 0);
                acc01 = MFMA32(a0h, b1l, acc01, 0, 0, 0);
                acc01 = MFMA32(a0l, b1h, acc01, 0, 0, 0);
                acc10 = MFMA32(a1h_, b0l, acc10, 0, 0, 0);
                acc10 = MFMA32(a1l_, b0h, acc10, 0, 0, 0);
                acc11 = MFMA32(a1h_, b1l, acc11, 0, 0, 0);
                acc11 = MFMA32(a1l_, b1h, acc11, 0, 0, 0);
            }
        }
    }

    // epilogue: D col = lane&31 (o), row = (r&3) + 8*(r>>2) + 4*h (+ mi*32 + wm*64)
    #pragma unroll
    for (int ni = 0; ni < 2; ++ni) {
        const int o = o0 + wn * 64 + ni * 32 + l31;
        float sc = 0.f, sh = 0.f, bias = 0.f;
        if (EPI == 1) { sc = epg[o] * BN4_RS; sh = epb[o]; }
        if (EPI == 2) { bias = epb ? epb[o] : 0.f; }
        float s1 = 0.f, s2 = 0.f;
        #pragma unroll
        for (int mi = 0; mi < 2; ++mi) {
            #pragma unroll
            for (int r = 0; r < 16; ++r) {
                const int n = n0 + wm * 64 + mi * 32 + (r & 3) + 8 * (r >> 2) + 4 * h;
                float v = (ni == 0) ? (mi == 0 ? acc00[r] : acc10[r])
                                    : (mi == 0 ? acc01[r] : acc11[r]);
                const long oi = ((long)bz * N2 + n) * (long)OC + o;
                if (EPI == 0) {
                    outF[oi] = v;
                } else if (EPI == 1) {
                    v = fmaf(v, sc, sh);
                    v = v >= 0.f ? v : LRELU_S * v;
                    oH[oi] = bhi(v);
                } else {
                    v += bias;
                    outF[oi] = v;
                    s1 += v; s2 = fmaf(v, v, s2);
                }
            }
        }
        if (EPI == 2) {
            s1 += __shfl_xor(s1, 32);
            s2 += __shfl_xor(s2, 32);
            if (h == 0) {
                atomicAdd(cs1 + bz * OC + o, s1);
                atomicAdd(cs2 + bz * OC + o, s2);
            }
        }
    }
}

// ---------------------------------------------------------------------------
// inverse norms over C=128 channels for x3 (z=0) and y3 (z=1)
__global__ void normK(const float* __restrict__ x3, const float* __restrict__ y3,
                      float* __restrict__ invnx, float* __restrict__ invny)
{
    const int n = blockIdx.x * 256 + threadIdx.x;
    const int b = blockIdx.y;
    const float* src = blockIdx.z ? y3 : x3;
    float ss = 0.f;
    for (int c = 0; c < 128; ++c) {
        float v = src[((long)b * 128 + c) * N2 + n];
        ss = fmaf(v, v, ss);
    }
    (blockIdx.z ? invny : invnx)[b * N2 + n] = rsqrtf(ss);
}

// ---------------------------------------------------------------------------
// transpose [C][2048] -> [2048][C].  MODE bits:
//  1 = write hi bf16; 2 = write invn-scaled hi+lo bf16; 4 = write fp32
template<int MODE>
__global__ __launch_bounds__(256) void tsplitK(
    const float* __restrict__ in, int C,
    unsigned short* __restrict__ tHi, const float* __restrict__ invn,
    unsigned short* __restrict__ sHi, unsigned short* __restrict__ sLo,
    float* __restrict__ tF)
{
    __shared__ float lt[64 * 65];
    const int t = threadIdx.x;
    const int n0 = blockIdx.x * 64, c0 = blockIdx.y * 64, b = blockIdx.z;
    {
        const int nl = t & 63;
        const int cb = t >> 6;
        #pragma unroll
        for (int i = 0; i < 16; ++i) {
            const int cl = cb + 4 * i;
            lt[nl * 65 + cl] = in[((long)b * C + c0 + cl) * N2 + n0 + nl];
        }
    }
    __syncthreads();
    const int cl = t & 63;
    const int nb = t >> 6;
    #pragma unroll
    for (int i = 0; i < 16; ++i) {
        const int nl = nb + 4 * i;
        const float v = lt[nl * 65 + cl];
        const long oi = ((long)b * N2 + n0 + nl) * C + c0 + cl;
        if (MODE & 1) tHi[oi] = bhi(v);
        if (MODE & 2) {
            const float svv = v * invn[b * N2 + n0 + nl];
            sHi[oi] = bhi(svv); sLo[oi] = bhi(svv - bhif(svv));
        }
        if (MODE & 4) tF[oi] = v;
    }
}

// ---------------------------------------------------------------------------
// weight fold (w4) + bf16 hi split for all 5 weight tensors
__global__ void wsplitK(const float* __restrict__ w4, const float* __restrict__ w5,
    const float* __restrict__ wm1, const float* __restrict__ wm2, const float* __restrict__ wm3,
    unsigned short* __restrict__ w4h, unsigned short* __restrict__ w5h,
    unsigned short* __restrict__ m1h, unsigned short* __restrict__ m2h,
    unsigned short* __restrict__ m3h)
{
    const int y = blockIdx.y;
    const int idx = blockIdx.x * 256 + threadIdx.x;
    float v; unsigned short* dh;
    if (y == 0) {
        if (idx >= 256 * 256) return;
        const int k = idx & 255;
        v = w4[idx];
        if (k < 128) v -= w4[idx + 128];
        dh = w4h;
    } else if (y == 1) {
        if (idx >= 512 * 512) return;
        v = w5[idx]; dh = w5h;
    } else if (y == 2) {
        if (idx >= 512 * 512) return;
        v = wm1[idx]; dh = m1h;
    } else if (y == 3) {
        if (idx >= 256 * 512) return;
        v = wm2[idx]; dh = m2h;
    } else {
        if (idx >= 128 * 256) return;
        v = wm3[idx]; dh = m3h;
    }
    dh[idx] = bhi(v);
}

// ---------------------------------------------------------------------------
// top-20 of a 2048 simi row via 4-pass radix select + softmax weights.
__global__ __launch_bounds__(256) void topkK(const float* __restrict__ simi,
    float* __restrict__ topw, int* __restrict__ topi, int bbase)
{
    __shared__ unsigned int hist[256];
    __shared__ unsigned int bcast[2];
    __shared__ unsigned int cnt[2];
    __shared__ float selv[20];
    __shared__ int   seli[20];
    const int t  = threadIdx.x;
    const int n  = blockIdx.x;
    const int bl = blockIdx.y;
    const float* row = simi + ((long)bl * N2 + n) * N2;

    float    f[8];
    unsigned u[8];
    {
        const float4 v0 = *(const float4*)(row + 4 * t);
        const float4 v1 = *(const float4*)(row + 1024 + 4 * t);
        f[0] = v0.x; f[1] = v0.y; f[2] = v0.z; f[3] = v0.w;
        f[4] = v1.x; f[5] = v1.y; f[6] = v1.z; f[7] = v1.w;
        #pragma unroll
        for (int i = 0; i < 8; ++i) {
            unsigned ub = __float_as_uint(f[i]);
            u[i] = ub ^ (((int)ub >> 31) | 0x80000000u);   // order-preserving flip
        }
    }

    unsigned prefix = 0;
    unsigned kneed  = 20;
    #pragma unroll
    for (int pass = 0; pass < 4; ++pass) {
        const int shift = 24 - 8 * pass;
        const unsigned pmask = (pass == 0) ? 0u : (0xFFFFFFFFu << (shift + 8));
        hist[t] = 0;
        __syncthreads();
        #pragma unroll
        for (int i = 0; i < 8; ++i)
            if ((u[i] & pmask) == prefix)
                atomicAdd(&hist[(u[i] >> shift) & 255], 1u);
        __syncthreads();
        if (t < 64) {
            const unsigned h0 = hist[4 * t], h1 = hist[4 * t + 1];
            const unsigned h2 = hist[4 * t + 2], h3 = hist[4 * t + 3];
            const unsigned s3 = h3, s2 = h2 + s3, s1 = h1 + s2, s0 = h0 + s1;
            unsigned inc = s0;
            #pragma unroll
            for (int off = 1; off < 64; off <<= 1) {
                const unsigned o = __shfl_down(inc, off);
                if (t + off < 64) inc += o;
            }
            const unsigned excl = inc - s0;               // count in lanes > t
            const unsigned sf[5] = {excl + s0, excl + s1, excl + s2, excl + s3, excl};
            #pragma unroll
            for (int j = 0; j < 4; ++j) {
                if (sf[j] >= kneed && sf[j + 1] < kneed) {
                    bcast[0] = 4 * t + j;
                    bcast[1] = kneed - sf[j + 1];
                }
            }
        }
        __syncthreads();
        prefix |= bcast[0] << shift;
        kneed   = bcast[1];
        __syncthreads();
    }

    if (t == 0) { cnt[0] = 0; cnt[1] = 0; }
    __syncthreads();
    const unsigned Tu = prefix;
    const int eqneed = (int)kneed;                        // equals to take
    const int gt     = 20 - eqneed;                       // strictly-greater count
    #pragma unroll
    for (int i = 0; i < 8; ++i) {
        const int idx = (i < 4) ? (4 * t + i) : (1024 + 4 * t + (i - 4));
        if (u[i] > Tu) {
            const unsigned s = atomicAdd(&cnt[0], 1u);
            selv[s] = f[i]; seli[s] = idx;
        } else if (u[i] == Tu) {
            const unsigned e = atomicAdd(&cnt[1], 1u);
            if ((int)e < eqneed) { selv[gt + e] = f[i]; seli[gt + e] = idx; }
        }
    }
    __syncthreads();

    if (t < 64) {
        const float v = (t < 20) ? selv[t] : -1e30f;
        float m = v;
        #pragma unroll
        for (int off = 1; off < 32; off <<= 1) m = fmaxf(m, __shfl_xor(m, off, 32));
        const float e = (t < 20) ? expf(v - m) : 0.f;
        float s = e;
        #pragma unroll
        for (int off = 1; off < 32; off <<= 1) s += __shfl_xor(s, off, 32);
        if (t < 20) {
            const long base = (((long)(bbase + bl)) * N2 + n) * 20;
            topw[base + t] = e / s;
            topi[base + t] = seli[t];
        }
    }
}

// ---------------------------------------------------------------------------
// G[n][c] = sum_k w_k * yT[idx_k][c], hi bf16 out.  b fastest for XCD-L2 locality.
__global__ __launch_bounds__(256) void aggK(const float* __restrict__ yT,
    const float* __restrict__ topw, const int* __restrict__ topi,
    unsigned short* __restrict__ Gh)
{
    const int t  = threadIdx.x;
    const int c4 = (t & 31) * 4;
    const int ns = t >> 5;                   // 0..7
    const int b  = blockIdx.x;               // fastest grid dim
    const int n  = blockIdx.y * 8 + ns;
    const long tb = ((long)b * N2 + n) * 20;
    const float* yb = yT + (long)b * N2 * 128 + c4;

    float a0 = 0.f, a1 = 0.f, a2 = 0.f, a3 = 0.f;
    #pragma unroll
    for (int k = 0; k < 20; ++k) {
        const float w  = topw[tb + k];
        const int  idx = topi[tb + k];
        const float4 v = *(const float4*)(yb + (long)idx * 128);
        a0 = fmaf(w, v.x, a0);
        a1 = fmaf(w, v.y, a1);
        a2 = fmaf(w, v.z, a2);
        a3 = fmaf(w, v.w, a3);
    }
    const long oi = ((long)b * N2 + n) * 128 + c4;
    ushort4 hh;
    hh.x = bhi(a0); hh.y = bhi(a1); hh.z = bhi(a2); hh.w = bhi(a3);
    *(ushort4*)(Gh + oi) = hh;
}

// ---------------------------------------------------------------------------
// reduce per-column sums to per-(b,group) GN stats;  one block of 256 = 8b x 32g
__global__ void statsK(const float* __restrict__ cs1, const float* __restrict__ cs2,
    float* __restrict__ stats, int C)
{
    const int t = threadIdx.x;
    const int b = t >> 5, g = t & 31;
    const int cpg = C >> 5;
    float s1 = 0.f, s2 = 0.f;
    for (int j = 0; j < cpg; ++j) {
        s1 += cs1[b * C + g * cpg + j];
        s2 += cs2[b * C + g * cpg + j];
    }
    const float cnt = (float)(cpg * N2);
    const float mu = s1 / cnt;
    const float var = s2 / cnt - mu * mu;
    stats[t * 2] = mu;
    stats[t * 2 + 1] = rsqrtf(var + 1e-5f);
}

// ---------------------------------------------------------------------------
// GN apply + activation, fp32 [n][C] -> hi bf16 [n][C].  ACT 0=lrelu 1=relu
template<int ACT, int LC>
__global__ void gnapplyK(const float* __restrict__ pre, const float* __restrict__ stats,
    const float* __restrict__ gamma, const float* __restrict__ beta,
    unsigned short* __restrict__ oH)
{
    const long i4 = ((long)blockIdx.x * 256 + threadIdx.x) * 4;
    const int C = 1 << LC;
    const int c = (int)(i4 & (C - 1));
    const int bn = (int)(i4 >> LC);
    const int b = bn >> 11;
    const int g = c >> (LC - 5);
    const float mu = stats[(b * 32 + g) * 2];
    const float rs = stats[(b * 32 + g) * 2 + 1];
    const float4 gm = *(const float4*)(gamma + c);
    const float4 bt = *(const float4*)(beta + c);
    const float4 v = *(const float4*)(pre + i4);
    const float vals[4] = {v.x, v.y, v.z, v.w};
    const float gms[4] = {gm.x, gm.y, gm.z, gm.w};
    const float bts[4] = {bt.x, bt.y, bt.z, bt.w};
    unsigned short hs[4];
    #pragma unroll
    for (int j = 0; j < 4; ++j) {
        float x = (vals[j] - mu) * (rs * gms[j]) + bts[j];
        x = (ACT == 0) ? (x >= 0.f ? x : LRELU_S * x) : (x >= 0.f ? x : 0.f);
        hs[j] = bhi(x);
    }
    ushort4 hh; hh.x = hs[0]; hh.y = hs[1]; hh.z = hs[2]; hh.w = hs[3];
    *(ushort4*)(oH + i4) = hh;
}

// ---------------------------------------------------------------------------
// final GN8 + relu + transpose to out[b][128][2048]
__global__ __launch_bounds__(256) void gnfinalK(const float* __restrict__ pre,
    const float* __restrict__ stats, const float* __restrict__ gamma,
    const float* __restrict__ beta, float* __restrict__ out)
{
    __shared__ float lt[64 * 65];
    const int t = threadIdx.x;
    const int n0 = blockIdx.x * 64, c0 = blockIdx.y * 64, b = blockIdx.z;
    {
        const int cl = t & 63;
        const int nb = t >> 6;
        const int c = c0 + cl;
        const int g = c >> 2;
        const float mu = stats[(b * 32 + g) * 2];
        const float rs = stats[(b * 32 + g) * 2 + 1];
        const float sc = rs * gamma[c], sh = beta[c] - mu * sc;
        #pragma unroll
        for (int i = 0; i < 16; ++i) {
            const int nl = nb + 4 * i;
            float v = pre[((long)b * N2 + n0 + nl) * 128 + c];
            v = v * sc + sh;
            lt[cl * 65 + nl] = v > 0.f ? v : 0.f;
        }
    }
    __syncthreads();
    const int nl = t & 63;
    const int cb = t >> 6;
    #pragma unroll
    for (int i = 0; i < 16; ++i) {
        const int cl = cb + 4 * i;
        out[((long)b * 128 + c0 + cl) * N2 + n0 + nl] = lt[cl * 65 + nl];
    }
}

// ---------------------------------------------------------------------------
// pooling stage 1: per (b, n-chunk of 64) partial max/sum over all 512 channels
__global__ __launch_bounds__(256) void pool1K(const unsigned short* __restrict__ lcH,
    float* __restrict__ pmax, float* __restrict__ psum)
{
    __shared__ float lmx[512], lsm[512];
    const int t  = threadIdx.x;
    const int cq = t & 127;          // channel quad
    const int rp = t >> 7;           // row parity
    const int nch = blockIdx.x;      // 0..31 (64 rows each)
    const int b   = blockIdx.y;
    float mx[4] = {-1e30f, -1e30f, -1e30f, -1e30f};
    float sm[4] = {0.f, 0.f, 0.f, 0.f};
    for (int i = 0; i < 32; ++i) {
        const int n = nch * 64 + 2 * i + rp;
        const long base = ((long)b * N2 + n) * 512 + cq * 4;
        const ushort4 hh = *(const ushort4*)(lcH + base);
        const float v0 = bf2f(hh.x);
        const float v1 = bf2f(hh.y);
        const float v2 = bf2f(hh.z);
        const float v3 = bf2f(hh.w);
        mx[0] = fmaxf(mx[0], v0); sm[0] += v0;
        mx[1] = fmaxf(mx[1], v1); sm[1] += v1;
        mx[2] = fmaxf(mx[2], v2); sm[2] += v2;
        mx[3] = fmaxf(mx[3], v3); sm[3] += v3;
    }
    if (rp) {
        #pragma unroll
        for (int j = 0; j < 4; ++j) { lmx[cq * 4 + j] = mx[j]; lsm[cq * 4 + j] = sm[j]; }
    }
    __syncthreads();
    if (!rp) {
        const long pb = ((long)(b * 32 + nch)) * 512 + cq * 4;
        #pragma unroll
        for (int j = 0; j < 4; ++j) {
            pmax[pb + j] = fmaxf(mx[j], lmx[cq * 4 + j]);
            psum[pb + j] = sm[j] + lsm[cq * 4 + j];
        }
    }
}

// pooling stage 2: reduce 32 chunk partials -> gv[b][1024] (max | mean)
__global__ void pool2K(const float* __restrict__ pmax, const float* __restrict__ psum,
                       float* __restrict__ gv)
{
    const int t = threadIdx.x;       // 256: 2 channels each
    const int b = blockIdx.x;
    float mx0 = -1e30f, mx1 = -1e30f, s0 = 0.f, s1 = 0.f;
    for (int nch = 0; nch < 32; ++nch) {
        const long pb = ((long)(b * 32 + nch)) * 512 + 2 * t;
        const float2 pm = *(const float2*)(pmax + pb);
        const float2 ps = *(const float2*)(psum + pb);
        mx0 = fmaxf(mx0, pm.x); mx1 = fmaxf(mx1, pm.y);
        s0 += ps.x; s1 += ps.y;
    }
    gv[b * 1024 + 2 * t]           = mx0;
    gv[b * 1024 + 2 * t + 1]       = mx1;
    gv[b * 1024 + 512 + 2 * t]     = s0 * (1.f / 2048.f);
    gv[b * 1024 + 512 + 2 * t + 1] = s1 * (1.f / 2048.f);
}

// ---------------------------------------------------------------------------
extern "C" void kernel_launch(void* const* d_in, const int* in_sizes, int n_in,
                              void* d_out, int out_size, void* d_ws, size_t ws_size,
                              hipStream_t stream)
{
    const float* x1    = (const float*)d_in[0];
    const float* x2    = (const float*)d_in[1];
    const float* x3    = (const float*)d_in[2];
    const float* y3    = (const float*)d_in[3];
    const float* w4    = (const float*)d_in[4];
    const float* bn4g  = (const float*)d_in[5];
    const float* bn4b  = (const float*)d_in[6];
    const float* w5    = (const float*)d_in[7];
    const float* gn5g  = (const float*)d_in[8];
    const float* gn5b  = (const float*)d_in[9];
    const float* wm1   = (const float*)d_in[10];
    const float* bm1   = (const float*)d_in[11];
    const float* gn6g  = (const float*)d_in[12];
    const float* gn6b  = (const float*)d_in[13];
    const float* wm2   = (const float*)d_in[14];
    const float* bm2   = (const float*)d_in[15];
    const float* gn7g  = (const float*)d_in[16];
    const float* gn7b  = (const float*)d_in[17];
    const float* wm3   = (const float*)d_in[18];
    const float* bm3   = (const float*)d_in[19];
    const float* gn8g  = (const float*)d_in[20];
    const float* gn8b  = (const float*)d_in[21];
    float* out = (float*)d_out;
    (void)in_sizes; (void)n_in; (void)out_size; (void)ws_size;

    char* ws = (char*)d_ws;
    // ---- arena (~218 MB of the 256 MiB ws) ----
    float*          simiF = (float*)(ws + 0);                   // 134.2 MB full simi
    float*          bufPS = (float*)(ws + 0);                   // alias: GEMM pre after topk
    unsigned short* lcH   = (unsigned short*)(ws + 134217728);  // 16.78 MB
    unsigned short* h1H   = (unsigned short*)(ws + 150994944);  // 16.78 MB
    unsigned short* x4H   = (unsigned short*)(ws + 167772160);  //  8.39 MB
    unsigned short* h2H   = (unsigned short*)(ws + 176160768);  //  8.39 MB
    float*          yT    = (float*)(ws + 184549376);           //  8.39 MB
    unsigned short* x3tH  = (unsigned short*)(ws + 192937984);  //  4.19 MB
    unsigned short* GH    = (unsigned short*)(ws + 197132288);  //  4.19 MB
    unsigned short* xnH   = (unsigned short*)(ws + 201326592);
    unsigned short* xnL   = (unsigned short*)(ws + 205520896);
    unsigned short* ynH   = (unsigned short*)(ws + 209715200);
    unsigned short* ynL   = (unsigned short*)(ws + 213909504);
    unsigned short* x1tH  = (unsigned short*)(ws + 218103808);  //  2.10 MB
    unsigned short* x2tH  = (unsigned short*)(ws + 220200960);  //  2.10 MB
    unsigned short* w4pH  = (unsigned short*)(ws + 222298112);
    unsigned short* w5H   = (unsigned short*)(ws + 222429184);
    unsigned short* m1H   = (unsigned short*)(ws + 222953472);
    unsigned short* m2H   = (unsigned short*)(ws + 223477760);
    unsigned short* m3H   = (unsigned short*)(ws + 223739904);
    float* invnx = (float*)(ws + 223805440);
    float* invny = (float*)(ws + 223870976);
    float* topw  = (float*)(ws + 223936512);                    //  1.31 MB
    int*   topi  = (int*)  (ws + 225247232);                    //  1.31 MB
    float* csb   = (float*)(ws + 226557952);                    //  128 KB
    float* cs1_5 = csb,          *cs2_5 = csb + 4096;
    float* cs1_6 = csb + 8192,   *cs2_6 = csb + 12288;
    float* cs1_7 = csb + 16384,  *cs2_7 = csb + 20480;
    float* cs1_8 = csb + 24576,  *cs2_8 = csb + 28672;
    float* stats5 = (float*)(ws + 226689024);
    float* stats6 = stats5 + 512;
    float* stats7 = stats5 + 1024;
    float* stats8 = stats5 + 1536;
    float* pmax  = (float*)(ws + 226697216);                    //  512 KB
    float* psum  = (float*)(ws + 227221504);                    //  512 KB

    const dim3 B256(256);
    const unsigned short* nu = nullptr;

    // 0. zero colsum accumulators (ws is poisoned each launch)
    hipMemsetAsync(csb, 0, 131072, stream);

    // 1. norms, transposes + bf16 splits, weight folds/splits
    normK<<<dim3(8, 8, 2), B256, 0, stream>>>(x3, y3, invnx, invny);
    tsplitK<6><<<dim3(32, 2, 8), B256, 0, stream>>>(y3, 128, nullptr, invny, ynH, ynL, yT);
    tsplitK<3><<<dim3(32, 2, 8), B256, 0, stream>>>(x3, 128, x3tH, invnx, xnH, xnL, nullptr);
    tsplitK<1><<<dim3(32, 1, 8), B256, 0, stream>>>(x1, 64, x1tH, nullptr, nullptr, nullptr, nullptr);
    tsplitK<1><<<dim3(32, 1, 8), B256, 0, stream>>>(x2, 64, x2tH, nullptr, nullptr, nullptr, nullptr);
    wsplitK<<<dim3(1024, 5), B256, 0, stream>>>(w4, w5, wm1, wm2, wm3,
        w4pH, w5H, m1H, m2H, m3H);

    // 2. simi (3-pass split-bf16 MFMA, all 8 batches) + radix topk
    mgemm<0, 0, 3><<<dim3(16, 16, 8), B256, 0, stream>>>(
        xnH, xnL, 128, nu, nu, nu, nu, nu, nu,
        ynH, ynL, (long)N2 * 128, 128, 2048, 0,
        simiF, nullptr, nullptr, nullptr, nullptr, nullptr);
    topkK<<<dim3(2048, 8), B256, 0, stream>>>(simiF, topw, topi, 0);

    // 3. gather-aggregate G (hi bf16); b fastest for XCD-L2 locality
    aggK<<<dim3(8, 256), B256, 0, stream>>>(yT, topw, topi, GH);

    // 4. conv4 (+BN eval + lrelu) over [x3 | G] with folded W4' -> x4 (1-pass)
    mgemm<1, 1, 1><<<dim3(16, 2, 8), B256, 0, stream>>>(
        x3tH, nu, 128, GH, nu, nu, nu, nu, nu,
        w4pH, nu, 0, 256, 256, 0,
        nullptr, x4H, bn4g, bn4b, nullptr, nullptr);

    // 5. conv5 over [x1|x2|x3|x4] -> pre + colsums; GN5 + lrelu -> lc (1-pass)
    mgemm<2, 2, 1><<<dim3(16, 4, 8), B256, 0, stream>>>(
        x1tH, nu, 64, x2tH, nu, x3tH, nu, x4H, nu,
        w5H, nu, 0, 512, 512, 0,
        bufPS, nullptr, nullptr, nullptr, cs1_5, cs2_5);
    statsK<<<1, B256, 0, stream>>>(cs1_5, cs2_5, stats5, 512);
    gnapplyK<0, 9><<<8192, B256, 0, stream>>>(bufPS, stats5, gn5g, gn5b, lcH);

    // 6. global pooling -> gv section of output (two-stage)
    pool1K<<<dim3(32, 8), B256, 0, stream>>>(lcH, pmax, psum);
    pool2K<<<dim3(8), B256, 0, stream>>>(pmax, psum, out + (long)8 * 128 * 2048);

    // 7. mlp1 -> pre + colsums; GN6 + relu -> h1 (1-pass)
    mgemm<0, 2, 1><<<dim3(16, 4, 8), B256, 0, stream>>>(
        lcH, nu, 512, nu, nu, nu, nu, nu, nu,
        m1H, nu, 0, 512, 512, 0,
        bufPS, nullptr, nullptr, bm1, cs1_6, cs2_6);
    statsK<<<1, B256, 0, stream>>>(cs1_6, cs2_6, stats6, 512);
    gnapplyK<1, 9><<<8192, B256, 0, stream>>>(bufPS, stats6, gn6g, gn6b, h1H);

    // 8. mlp2 -> pre + colsums; GN7 + relu -> h2 (1-pass)
    mgemm<0, 2, 1><<<dim3(16, 2, 8), B256, 0, stream>>>(
        h1H, nu, 512, nu, nu, nu, nu, nu, nu,
        m2H, nu, 0, 512, 256, 0,
        bufPS, nullptr, nullptr, bm2, cs1_7, cs2_7);
    statsK<<<1, B256, 0, stream>>>(cs1_7, cs2_7, stats7, 256);
    gnapplyK<1, 8><<<4096, B256, 0, stream>>>(bufPS, stats7, gn7g, gn7b, h2H);

    // 9. mlp3 -> pre + colsums; GN8 + relu + transpose -> emb (1-pass)
    mgemm<0, 2, 1><<<dim3(16, 1, 8), B256, 0, stream>>>(
        h2H, nu, 256, nu, nu, nu, nu, nu, nu,
        m3H, nu, 0, 256, 128, 0,
        bufPS, nullptr, nullptr, bm3, cs1_8, cs2_8);
    statsK<<<1, B256, 0, stream>>>(cs1_8, cs2_8, stats8, 128);
    gnfinalK<<<dim3(32, 2, 8), B256, 0, stream>>>(bufPS, stats8, gn8g, gn8b, out);
}

// Round 9
// 358.176 us; speedup vs baseline: 3.3648x; 1.0874x over previous
//
#include <hip/hip_runtime.h>
#include <math.h>

#define N2 2048
#define LRELU_S 0.2f
#define BN4_RS 0.9999950000374997f   // rsqrt(1+1e-5)

typedef short bf16x8 __attribute__((ext_vector_type(8)));
typedef float f32x16 __attribute__((ext_vector_type(16)));

__device__ __forceinline__ unsigned short bhi(float v) { return (unsigned short)(__float_as_uint(v) >> 16); }
__device__ __forceinline__ float bhif(float v) { return __uint_as_float(__float_as_uint(v) & 0xFFFF0000u); }
__device__ __forceinline__ float bf2f(unsigned short u) { return __uint_as_float(((unsigned int)u) << 16); }

__device__ __forceinline__ void gl16(const void* g, void* l) {
    __builtin_amdgcn_global_load_lds((const __attribute__((address_space(1))) unsigned int*)g,
                                     (__attribute__((address_space(3))) unsigned int*)l, 16, 0, 0);
}

__device__ __forceinline__ f32x16 z16() {
    f32x16 v;
    #pragma unroll
    for (int i = 0; i < 16; ++i) v[i] = 0.f;
    return v;
}

#define MFMA32 __builtin_amdgcn_mfma_f32_32x32x16_bf16

// ---------------------------------------------------------------------------
// Split-bf16 MFMA GEMM.  out[bz][n][o] = sum_k A[b][n][k] * B[o][k]
// PASSES: 3 = hi*hi + hi*lo + lo*hi (err ~2^-16, simi/topk selection path)
//         1 = hi*hi only            (err ~2^-9, conv/mlp path; GN absorbs it)
// ---------------------------------------------------------------------------
template<int ASRC, int EPI, int PASSES>
__global__ __launch_bounds__(256) void mgemm(
    const unsigned short* __restrict__ a1H, const unsigned short* __restrict__ a1L, int CA,
    const unsigned short* __restrict__ a2H, const unsigned short* __restrict__ a2L,
    const unsigned short* __restrict__ a3H, const unsigned short* __restrict__ a3L,
    const unsigned short* __restrict__ a4H, const unsigned short* __restrict__ a4L,
    const unsigned short* __restrict__ bH,  const unsigned short* __restrict__ bL, long bBs,
    int Ktot, int OC, int bbase,
    float* __restrict__ outF, unsigned short* __restrict__ oH,
    const float* __restrict__ epg, const float* __restrict__ epb,
    float* __restrict__ cs1, float* __restrict__ cs2)
{
    __shared__ alignas(16) unsigned short lAh[4096], lBh[4096];
    __shared__ alignas(16) unsigned short lAl[PASSES == 3 ? 4096 : 16];
    __shared__ alignas(16) unsigned short lBl[PASSES == 3 ? 4096 : 16];
    const int t  = threadIdx.x;
    const int n0 = blockIdx.x * 128;
    const int o0 = blockIdx.y * 128;
    const int bz = blockIdx.z;
    const int b  = bbase + bz;

    const int lane = t & 63;
    const int h    = lane >> 5;
    const int l31  = lane & 31;
    const int wid  = t >> 6;
    const int wm   = wid >> 1;
    const int wn   = wid & 1;
    const int sw   = (l31 >> 1) & 3;            // LDS chunk swizzle for frag reads

    f32x16 acc00 = z16(), acc01 = z16(), acc10 = z16(), acc11 = z16();

    const int q0 = t, q1 = t + 256;
    const int r0 = q0 >> 2, p0 = q0 & 3, c0s = p0 ^ ((r0 >> 1) & 3);
    const int r1 = q1 >> 2, p1 = q1 & 3, c1s = p1 ^ ((r1 >> 1) & 3);

    const int rA0 = (wm * 64 + l31) * 32, rA1 = rA0 + 1024;
    const int rB0 = (wn * 64 + l31) * 32, rB1 = rB0 + 1024;

    for (int kc = 0; kc < Ktot; kc += 32) {
        const unsigned short *sAH, *sAL; int koff, Cs;
        if (ASRC == 0)      { sAH = a1H; sAL = a1L; koff = kc;       Cs = CA; }
        else if (ASRC == 1) {
            if (kc < 128)   { sAH = a1H; sAL = a1L; koff = kc;       Cs = 128; }
            else            { sAH = a2H; sAL = a2L; koff = kc - 128; Cs = 128; }
        } else {
            if (kc < 64)        { sAH = a1H; sAL = a1L; koff = kc;       Cs = 64;  }
            else if (kc < 128)  { sAH = a2H; sAL = a2L; koff = kc - 64;  Cs = 64;  }
            else if (kc < 256)  { sAH = a3H; sAL = a3L; koff = kc - 128; Cs = 128; }
            else                { sAH = a4H; sAL = a4L; koff = kc - 256; Cs = 256; }
        }
        __syncthreads();
        {
            long ga = ((long)b * N2 + n0 + r0) * Cs + koff + c0s * 8;
            long gb = (long)b * bBs + (long)(o0 + r0) * Ktot + kc + c0s * 8;
            gl16(sAH + ga, lAh + q0 * 8);
            gl16(bH + gb, lBh + q0 * 8);
            if (PASSES == 3) { gl16(sAL + ga, lAl + q0 * 8); gl16(bL + gb, lBl + q0 * 8); }
            long ga1 = ((long)b * N2 + n0 + r1) * Cs + koff + c1s * 8;
            long gb1 = (long)b * bBs + (long)(o0 + r1) * Ktot + kc + c1s * 8;
            gl16(sAH + ga1, lAh + q1 * 8);
            gl16(bH + gb1, lBh + q1 * 8);
            if (PASSES == 3) { gl16(sAL + ga1, lAl + q1 * 8); gl16(bL + gb1, lBl + q1 * 8); }
        }
        __syncthreads();
        #pragma unroll
        for (int s = 0; s < 2; ++s) {
            const int off = ((s * 2 + h) ^ sw) * 8;
            bf16x8 a0h = *(const bf16x8*)(lAh + rA0 + off);
            bf16x8 a1h_ = *(const bf16x8*)(lAh + rA1 + off);
            bf16x8 b0h = *(const bf16x8*)(lBh + rB0 + off);
            bf16x8 b1h = *(const bf16x8*)(lBh + rB1 + off);
            acc00 = MFMA32(a0h, b0h, acc00, 0, 0, 0);
            acc01 = MFMA32(a0h, b1h, acc01, 0, 0, 0);
            acc10 = MFMA32(a1h_, b0h, acc10, 0, 0, 0);
            acc11 = MFMA32(a1h_, b1h, acc11, 0, 0, 0);
            if (PASSES == 3) {
                bf16x8 a0l = *(const bf16x8*)(lAl + rA0 + off);
                bf16x8 a1l_ = *(const bf16x8*)(lAl + rA1 + off);
                bf16x8 b0l = *(const bf16x8*)(lBl + rB0 + off);
                bf16x8 b1l = *(const bf16x8*)(lBl + rB1 + off);
                acc00 = MFMA32(a0h, b0l, acc00, 0, 0, 0);
                acc00 = MFMA32(a0l, b0h, acc00, 0, 0, 0);
                acc01 = MFMA32(a0h, b1l, acc01, 0, 0, 0);
                acc01 = MFMA32(a0l, b1h, acc01, 0, 0, 0);
                acc10 = MFMA32(a1h_, b0l, acc10, 0, 0, 0);
                acc10 = MFMA32(a1l_, b0h, acc10, 0, 0, 0);
                acc11 = MFMA32(a1h_, b1l, acc11, 0, 0, 0);
                acc11 = MFMA32(a1l_, b1h, acc11, 0, 0, 0);
            }
        }
    }

    #pragma unroll
    for (int ni = 0; ni < 2; ++ni) {
        const int o = o0 + wn * 64 + ni * 32 + l31;
        float sc = 0.f, sh = 0.f, bias = 0.f;
        if (EPI == 1) { sc = epg[o] * BN4_RS; sh = epb[o]; }
        if (EPI == 2) { bias = epb ? epb[o] : 0.f; }
        float s1 = 0.f, s2 = 0.f;
        #pragma unroll
        for (int mi = 0; mi < 2; ++mi) {
            #pragma unroll
            for (int r = 0; r < 16; ++r) {
                const int n = n0 + wm * 64 + mi * 32 + (r & 3) + 8 * (r >> 2) + 4 * h;
                float v = (ni == 0) ? (mi == 0 ? acc00[r] : acc10[r])
                                    : (mi == 0 ? acc01[r] : acc11[r]);
                const long oi = ((long)bz * N2 + n) * (long)OC + o;
                if (EPI == 0) {
                    outF[oi] = v;
                } else if (EPI == 1) {
                    v = fmaf(v, sc, sh);
                    v = v >= 0.f ? v : LRELU_S * v;
                    oH[oi] = bhi(v);
                } else {
                    v += bias;
                    outF[oi] = v;
                    s1 += v; s2 = fmaf(v, v, s2);
                }
            }
        }
        if (EPI == 2) {
            s1 += __shfl_xor(s1, 32);
            s2 += __shfl_xor(s2, 32);
            if (h == 0) {
                atomicAdd(cs1 + bz * OC + o, s1);
                atomicAdd(cs2 + bz * OC + o, s2);
            }
        }
    }
}

// ---------------------------------------------------------------------------
// inverse norms over C=128 channels for x3 (z=0) and y3 (z=1)
__global__ void normK(const float* __restrict__ x3, const float* __restrict__ y3,
                      float* __restrict__ invnx, float* __restrict__ invny)
{
    const int n = blockIdx.x * 256 + threadIdx.x;
    const int b = blockIdx.y;
    const float* src = blockIdx.z ? y3 : x3;
    float ss = 0.f;
    for (int c = 0; c < 128; ++c) {
        float v = src[((long)b * 128 + c) * N2 + n];
        ss = fmaf(v, v, ss);
    }
    (blockIdx.z ? invny : invnx)[b * N2 + n] = rsqrtf(ss);
}

// ---------------------------------------------------------------------------
// transpose [C][2048] -> [2048][C].  MODE bits:
//  1 = write hi bf16; 2 = write invn-scaled hi+lo bf16; 4 = write fp32
template<int MODE>
__global__ __launch_bounds__(256) void tsplitK(
    const float* __restrict__ in, int C,
    unsigned short* __restrict__ tHi, const float* __restrict__ invn,
    unsigned short* __restrict__ sHi, unsigned short* __restrict__ sLo,
    float* __restrict__ tF)
{
    __shared__ float lt[64 * 65];
    const int t = threadIdx.x;
    const int n0 = blockIdx.x * 64, c0 = blockIdx.y * 64, b = blockIdx.z;
    {
        const int nl = t & 63;
        const int cb = t >> 6;
        #pragma unroll
        for (int i = 0; i < 16; ++i) {
            const int cl = cb + 4 * i;
            lt[nl * 65 + cl] = in[((long)b * C + c0 + cl) * N2 + n0 + nl];
        }
    }
    __syncthreads();
    const int cl = t & 63;
    const int nb = t >> 6;
    #pragma unroll
    for (int i = 0; i < 16; ++i) {
        const int nl = nb + 4 * i;
        const float v = lt[nl * 65 + cl];
        const long oi = ((long)b * N2 + n0 + nl) * C + c0 + cl;
        if (MODE & 1) tHi[oi] = bhi(v);
        if (MODE & 2) {
            const float svv = v * invn[b * N2 + n0 + nl];
            sHi[oi] = bhi(svv); sLo[oi] = bhi(svv - bhif(svv));
        }
        if (MODE & 4) tF[oi] = v;
    }
}

// ---------------------------------------------------------------------------
// weight fold (w4) + bf16 hi split for all 5 weight tensors
__global__ void wsplitK(const float* __restrict__ w4, const float* __restrict__ w5,
    const float* __restrict__ wm1, const float* __restrict__ wm2, const float* __restrict__ wm3,
    unsigned short* __restrict__ w4h, unsigned short* __restrict__ w5h,
    unsigned short* __restrict__ m1h, unsigned short* __restrict__ m2h,
    unsigned short* __restrict__ m3h)
{
    const int y = blockIdx.y;
    const int idx = blockIdx.x * 256 + threadIdx.x;
    float v; unsigned short* dh;
    if (y == 0) {
        if (idx >= 256 * 256) return;
        const int k = idx & 255;
        v = w4[idx];
        if (k < 128) v -= w4[idx + 128];
        dh = w4h;
    } else if (y == 1) {
        if (idx >= 512 * 512) return;
        v = w5[idx]; dh = w5h;
    } else if (y == 2) {
        if (idx >= 512 * 512) return;
        v = wm1[idx]; dh = m1h;
    } else if (y == 3) {
        if (idx >= 256 * 512) return;
        v = wm2[idx]; dh = m2h;
    } else {
        if (idx >= 128 * 256) return;
        v = wm3[idx]; dh = m3h;
    }
    dh[idx] = bhi(v);
}

// ---------------------------------------------------------------------------
// top-20 of a 2048 simi row: value-space adaptive-quantization select.
// 1) wave/block min-max; 2) 256-bin linear histogram (low contention since
// bins adapt to value range); 3) strictly-greater bins selected outright;
// boundary bin resolved bit-exactly via compacted rank loop.
__global__ __launch_bounds__(256) void topkK(const float* __restrict__ simi,
    float* __restrict__ topw, int* __restrict__ topi, int bbase)
{
    __shared__ unsigned int hist[256];
    __shared__ unsigned int bcast[2];
    __shared__ float lmn[4], lmx[4];
    __shared__ unsigned int cnt0, candCnt, tick;
    __shared__ unsigned int candU[256];
    __shared__ float candV[256];
    __shared__ int   candI[256];
    __shared__ float selv[20];
    __shared__ int   seli[20];
    const int t  = threadIdx.x;
    const int n  = blockIdx.x;
    const int bl = blockIdx.y;
    const float* row = simi + ((long)bl * N2 + n) * N2;

    float    f[8];
    unsigned u[8];
    {
        const float4 v0 = *(const float4*)(row + 4 * t);
        const float4 v1 = *(const float4*)(row + 1024 + 4 * t);
        f[0] = v0.x; f[1] = v0.y; f[2] = v0.z; f[3] = v0.w;
        f[4] = v1.x; f[5] = v1.y; f[6] = v1.z; f[7] = v1.w;
        #pragma unroll
        for (int i = 0; i < 8; ++i) {
            unsigned ub = __float_as_uint(f[i]);
            u[i] = ub ^ (((int)ub >> 31) | 0x80000000u);   // order-preserving flip
        }
    }

    // ---- row min / max ----
    float tmn = f[0], tmx = f[0];
    #pragma unroll
    for (int i = 1; i < 8; ++i) { tmn = fminf(tmn, f[i]); tmx = fmaxf(tmx, f[i]); }
    #pragma unroll
    for (int off = 1; off < 64; off <<= 1) {
        tmn = fminf(tmn, __shfl_xor(tmn, off));
        tmx = fmaxf(tmx, __shfl_xor(tmx, off));
    }
    if ((t & 63) == 0) { lmn[t >> 6] = tmn; lmx[t >> 6] = tmx; }
    if (t == 0) { cnt0 = 0; candCnt = 0; tick = 0; }
    hist[t] = 0;
    __syncthreads();
    const float rmn = fminf(fminf(lmn[0], lmn[1]), fminf(lmn[2], lmn[3]));
    const float rmx = fmaxf(fmaxf(lmx[0], lmx[1]), fmaxf(lmx[2], lmx[3]));
    const float rng = rmx - rmn;
    const float scale = (rng > 0.f) ? (255.0f / rng) : 0.f;

    // ---- quantize + histogram ----
    int q[8];
    #pragma unroll
    for (int i = 0; i < 8; ++i) {
        int qi = (int)((f[i] - rmn) * scale);
        q[i] = qi < 0 ? 0 : (qi > 255 ? 255 : qi);
        atomicAdd(&hist[q[i]], 1u);
    }
    __syncthreads();

    // ---- suffix-scan to find boundary bin (20th largest) ----
    if (t < 64) {
        const unsigned h0 = hist[4 * t], h1 = hist[4 * t + 1];
        const unsigned h2 = hist[4 * t + 2], h3 = hist[4 * t + 3];
        const unsigned s3 = h3, s2 = h2 + s3, s1 = h1 + s2, s0 = h0 + s1;
        unsigned inc = s0;
        #pragma unroll
        for (int off = 1; off < 64; off <<= 1) {
            const unsigned o = __shfl_down(inc, off);
            if (t + off < 64) inc += o;
        }
        const unsigned excl = inc - s0;               // count in lanes > t
        const unsigned sf[5] = {excl + s0, excl + s1, excl + s2, excl + s3, excl};
        #pragma unroll
        for (int j = 0; j < 4; ++j) {
            if (sf[j] >= 20u && sf[j + 1] < 20u) {
                bcast[0] = 4 * t + j;
                bcast[1] = 20u - sf[j + 1];
            }
        }
    }
    __syncthreads();
    const int Abin   = (int)bcast[0];
    const int kneedA = (int)bcast[1];                 // to take from boundary bin
    const int gt     = 20 - kneedA;                   // strictly-greater count

    // ---- greater class: selected outright ----
    #pragma unroll
    for (int i = 0; i < 8; ++i) {
        const int idx = (i < 4) ? (4 * t + i) : (1024 + 4 * t + (i - 4));
        if (q[i] > Abin) {
            const unsigned s = atomicAdd(&cnt0, 1u);
            selv[s] = f[i]; seli[s] = idx;
        } else if (q[i] == Abin) {
            const unsigned s = atomicAdd(&candCnt, 1u);
            if (s < 256u) { candU[s] = u[i]; candV[s] = f[i]; candI[s] = idx; }
        }
    }
    __syncthreads();

    // ---- boundary bin: exact rank among candidates ----
    const int cc = (int)candCnt;
    if (cc <= 256) {
        for (int slot = t; slot < cc; slot += 256) {
            const unsigned ui = candU[slot];
            int r = 0;
            for (int j = 0; j < cc; ++j) {
                const unsigned uj = candU[j];
                r += (uj > ui) || (uj == ui && j < slot);
            }
            if (r < kneedA) { selv[gt + r] = candV[slot]; seli[gt + r] = candI[slot]; }
        }
    } else {
        // degenerate (massive ties): take first kneedA encountered
        #pragma unroll
        for (int i = 0; i < 8; ++i) {
            const int idx = (i < 4) ? (4 * t + i) : (1024 + 4 * t + (i - 4));
            if (q[i] == Abin) {
                const unsigned e = atomicAdd(&tick, 1u);
                if ((int)e < kneedA) { selv[gt + e] = f[i]; seli[gt + e] = idx; }
            }
        }
    }
    __syncthreads();

    // ---- softmax over the 20 + store ----
    if (t < 64) {
        const float v = (t < 20) ? selv[t] : -1e30f;
        float m = v;
        #pragma unroll
        for (int off = 1; off < 32; off <<= 1) m = fmaxf(m, __shfl_xor(m, off, 32));
        const float e = (t < 20) ? expf(v - m) : 0.f;
        float s = e;
        #pragma unroll
        for (int off = 1; off < 32; off <<= 1) s += __shfl_xor(s, off, 32);
        if (t < 20) {
            const long base = (((long)(bbase + bl)) * N2 + n) * 20;
            topw[base + t] = e / s;
            topi[base + t] = seli[t];
        }
    }
}

// ---------------------------------------------------------------------------
// G[n][c] = sum_k w_k * yT[idx_k][c], hi bf16 out.  b fastest for XCD-L2 locality.
__global__ __launch_bounds__(256) void aggK(const float* __restrict__ yT,
    const float* __restrict__ topw, const int* __restrict__ topi,
    unsigned short* __restrict__ Gh)
{
    const int t  = threadIdx.x;
    const int c4 = (t & 31) * 4;
    const int ns = t >> 5;                   // 0..7
    const int b  = blockIdx.x;               // fastest grid dim
    const int n  = blockIdx.y * 8 + ns;
    const long tb = ((long)b * N2 + n) * 20;
    const float* yb = yT + (long)b * N2 * 128 + c4;

    float a0 = 0.f, a1 = 0.f, a2 = 0.f, a3 = 0.f;
    #pragma unroll
    for (int k = 0; k < 20; ++k) {
        const float w  = topw[tb + k];
        const int  idx = topi[tb + k];
        const float4 v = *(const float4*)(yb + (long)idx * 128);
        a0 = fmaf(w, v.x, a0);
        a1 = fmaf(w, v.y, a1);
        a2 = fmaf(w, v.z, a2);
        a3 = fmaf(w, v.w, a3);
    }
    const long oi = ((long)b * N2 + n) * 128 + c4;
    ushort4 hh;
    hh.x = bhi(a0); hh.y = bhi(a1); hh.z = bhi(a2); hh.w = bhi(a3);
    *(ushort4*)(Gh + oi) = hh;
}

// ---------------------------------------------------------------------------
// reduce per-column sums to per-(b,group) GN stats;  one block of 256 = 8b x 32g
__global__ void statsK(const float* __restrict__ cs1, const float* __restrict__ cs2,
    float* __restrict__ stats, int C)
{
    const int t = threadIdx.x;
    const int b = t >> 5, g = t & 31;
    const int cpg = C >> 5;
    float s1 = 0.f, s2 = 0.f;
    for (int j = 0; j < cpg; ++j) {
        s1 += cs1[b * C + g * cpg + j];
        s2 += cs2[b * C + g * cpg + j];
    }
    const float cnt = (float)(cpg * N2);
    const float mu = s1 / cnt;
    const float var = s2 / cnt - mu * mu;
    stats[t * 2] = mu;
    stats[t * 2 + 1] = rsqrtf(var + 1e-5f);
}

// ---------------------------------------------------------------------------
// GN apply + activation, fp32 [n][C] -> hi bf16 [n][C].  ACT 0=lrelu 1=relu
template<int ACT, int LC>
__global__ void gnapplyK(const float* __restrict__ pre, const float* __restrict__ stats,
    const float* __restrict__ gamma, const float* __restrict__ beta,
    unsigned short* __restrict__ oH)
{
    const long i4 = ((long)blockIdx.x * 256 + threadIdx.x) * 4;
    const int C = 1 << LC;
    const int c = (int)(i4 & (C - 1));
    const int bn = (int)(i4 >> LC);
    const int b = bn >> 11;
    const int g = c >> (LC - 5);
    const float mu = stats[(b * 32 + g) * 2];
    const float rs = stats[(b * 32 + g) * 2 + 1];
    const float4 gm = *(const float4*)(gamma + c);
    const float4 bt = *(const float4*)(beta + c);
    const float4 v = *(const float4*)(pre + i4);
    const float vals[4] = {v.x, v.y, v.z, v.w};
    const float gms[4] = {gm.x, gm.y, gm.z, gm.w};
    const float bts[4] = {bt.x, bt.y, bt.z, bt.w};
    unsigned short hs[4];
    #pragma unroll
    for (int j = 0; j < 4; ++j) {
        float x = (vals[j] - mu) * (rs * gms[j]) + bts[j];
        x = (ACT == 0) ? (x >= 0.f ? x : LRELU_S * x) : (x >= 0.f ? x : 0.f);
        hs[j] = bhi(x);
    }
    ushort4 hh; hh.x = hs[0]; hh.y = hs[1]; hh.z = hs[2]; hh.w = hs[3];
    *(ushort4*)(oH + i4) = hh;
}

// ---------------------------------------------------------------------------
// final GN8 + relu + transpose to out[b][128][2048]
__global__ __launch_bounds__(256) void gnfinalK(const float* __restrict__ pre,
    const float* __restrict__ stats, const float* __restrict__ gamma,
    const float* __restrict__ beta, float* __restrict__ out)
{
    __shared__ float lt[64 * 65];
    const int t = threadIdx.x;
    const int n0 = blockIdx.x * 64, c0 = blockIdx.y * 64, b = blockIdx.z;
    {
        const int cl = t & 63;
        const int nb = t >> 6;
        const int c = c0 + cl;
        const int g = c >> 2;
        const float mu = stats[(b * 32 + g) * 2];
        const float rs = stats[(b * 32 + g) * 2 + 1];
        const float sc = rs * gamma[c], sh = beta[c] - mu * sc;
        #pragma unroll
        for (int i = 0; i < 16; ++i) {
            const int nl = nb + 4 * i;
            float v = pre[((long)b * N2 + n0 + nl) * 128 + c];
            v = v * sc + sh;
            lt[cl * 65 + nl] = v > 0.f ? v : 0.f;
        }
    }
    __syncthreads();
    const int nl = t & 63;
    const int cb = t >> 6;
    #pragma unroll
    for (int i = 0; i < 16; ++i) {
        const int cl = cb + 4 * i;
        out[((long)b * 128 + c0 + cl) * N2 + n0 + nl] = lt[cl * 65 + nl];
    }
}

// ---------------------------------------------------------------------------
// pooling stage 1: per (b, n-chunk of 64) partial max/sum over all 512 channels
__global__ __launch_bounds__(256) void pool1K(const unsigned short* __restrict__ lcH,
    float* __restrict__ pmax, float* __restrict__ psum)
{
    __shared__ float lmx[512], lsm[512];
    const int t  = threadIdx.x;
    const int cq = t & 127;          // channel quad
    const int rp = t >> 7;           // row parity
    const int nch = blockIdx.x;      // 0..31 (64 rows each)
    const int b   = blockIdx.y;
    float mx[4] = {-1e30f, -1e30f, -1e30f, -1e30f};
    float sm[4] = {0.f, 0.f, 0.f, 0.f};
    for (int i = 0; i < 32; ++i) {
        const int n = nch * 64 + 2 * i + rp;
        const long base = ((long)b * N2 + n) * 512 + cq * 4;
        const ushort4 hh = *(const ushort4*)(lcH + base);
        const float v0 = bf2f(hh.x);
        const float v1 = bf2f(hh.y);
        const float v2 = bf2f(hh.z);
        const float v3 = bf2f(hh.w);
        mx[0] = fmaxf(mx[0], v0); sm[0] += v0;
        mx[1] = fmaxf(mx[1], v1); sm[1] += v1;
        mx[2] = fmaxf(mx[2], v2); sm[2] += v2;
        mx[3] = fmaxf(mx[3], v3); sm[3] += v3;
    }
    if (rp) {
        #pragma unroll
        for (int j = 0; j < 4; ++j) { lmx[cq * 4 + j] = mx[j]; lsm[cq * 4 + j] = sm[j]; }
    }
    __syncthreads();
    if (!rp) {
        const long pb = ((long)(b * 32 + nch)) * 512 + cq * 4;
        #pragma unroll
        for (int j = 0; j < 4; ++j) {
            pmax[pb + j] = fmaxf(mx[j], lmx[cq * 4 + j]);
            psum[pb + j] = sm[j] + lsm[cq * 4 + j];
        }
    }
}

// pooling stage 2: reduce 32 chunk partials -> gv[b][1024] (max | mean)
__global__ void pool2K(const float* __restrict__ pmax, const float* __restrict__ psum,
                       float* __restrict__ gv)
{
    const int t = threadIdx.x;       // 256: 2 channels each
    const int b = blockIdx.x;
    float mx0 = -1e30f, mx1 = -1e30f, s0 = 0.f, s1 = 0.f;
    for (int nch = 0; nch < 32; ++nch) {
        const long pb = ((long)(b * 32 + nch)) * 512 + 2 * t;
        const float2 pm = *(const float2*)(pmax + pb);
        const float2 ps = *(const float2*)(psum + pb);
        mx0 = fmaxf(mx0, pm.x); mx1 = fmaxf(mx1, pm.y);
        s0 += ps.x; s1 += ps.y;
    }
    gv[b * 1024 + 2 * t]           = mx0;
    gv[b * 1024 + 2 * t + 1]       = mx1;
    gv[b * 1024 + 512 + 2 * t]     = s0 * (1.f / 2048.f);
    gv[b * 1024 + 512 + 2 * t + 1] = s1 * (1.f / 2048.f);
}

// ---------------------------------------------------------------------------
extern "C" void kernel_launch(void* const* d_in, const int* in_sizes, int n_in,
                              void* d_out, int out_size, void* d_ws, size_t ws_size,
                              hipStream_t stream)
{
    const float* x1    = (const float*)d_in[0];
    const float* x2    = (const float*)d_in[1];
    const float* x3    = (const float*)d_in[2];
    const float* y3    = (const float*)d_in[3];
    const float* w4    = (const float*)d_in[4];
    const float* bn4g  = (const float*)d_in[5];
    const float* bn4b  = (const float*)d_in[6];
    const float* w5    = (const float*)d_in[7];
    const float* gn5g  = (const float*)d_in[8];
    const float* gn5b  = (const float*)d_in[9];
    const float* wm1   = (const float*)d_in[10];
    const float* bm1   = (const float*)d_in[11];
    const float* gn6g  = (const float*)d_in[12];
    const float* gn6b  = (const float*)d_in[13];
    const float* wm2   = (const float*)d_in[14];
    const float* bm2   = (const float*)d_in[15];
    const float* gn7g  = (const float*)d_in[16];
    const float* gn7b  = (const float*)d_in[17];
    const float* wm3   = (const float*)d_in[18];
    const float* bm3   = (const float*)d_in[19];
    const float* gn8g  = (const float*)d_in[20];
    const float* gn8b  = (const float*)d_in[21];
    float* out = (float*)d_out;
    (void)in_sizes; (void)n_in; (void)out_size; (void)ws_size;

    char* ws = (char*)d_ws;
    // ---- arena (~218 MB of the 256 MiB ws) ----
    float*          simiF = (float*)(ws + 0);                   // 134.2 MB full simi
    float*          bufPS = (float*)(ws + 0);                   // alias: GEMM pre after topk
    unsigned short* lcH   = (unsigned short*)(ws + 134217728);  // 16.78 MB
    unsigned short* h1H   = (unsigned short*)(ws + 150994944);  // 16.78 MB
    unsigned short* x4H   = (unsigned short*)(ws + 167772160);  //  8.39 MB
    unsigned short* h2H   = (unsigned short*)(ws + 176160768);  //  8.39 MB
    float*          yT    = (float*)(ws + 184549376);           //  8.39 MB
    unsigned short* x3tH  = (unsigned short*)(ws + 192937984);  //  4.19 MB
    unsigned short* GH    = (unsigned short*)(ws + 197132288);  //  4.19 MB
    unsigned short* xnH   = (unsigned short*)(ws + 201326592);
    unsigned short* xnL   = (unsigned short*)(ws + 205520896);
    unsigned short* ynH   = (unsigned short*)(ws + 209715200);
    unsigned short* ynL   = (unsigned short*)(ws + 213909504);
    unsigned short* x1tH  = (unsigned short*)(ws + 218103808);  //  2.10 MB
    unsigned short* x2tH  = (unsigned short*)(ws + 220200960);  //  2.10 MB
    unsigned short* w4pH  = (unsigned short*)(ws + 222298112);
    unsigned short* w5H   = (unsigned short*)(ws + 222429184);
    unsigned short* m1H   = (unsigned short*)(ws + 222953472);
    unsigned short* m2H   = (unsigned short*)(ws + 223477760);
    unsigned short* m3H   = (unsigned short*)(ws + 223739904);
    float* invnx = (float*)(ws + 223805440);
    float* invny = (float*)(ws + 223870976);
    float* topw  = (float*)(ws + 223936512);                    //  1.31 MB
    int*   topi  = (int*)  (ws + 225247232);                    //  1.31 MB
    float* csb   = (float*)(ws + 226557952);                    //  128 KB
    float* cs1_5 = csb,          *cs2_5 = csb + 4096;
    float* cs1_6 = csb + 8192,   *cs2_6 = csb + 12288;
    float* cs1_7 = csb + 16384,  *cs2_7 = csb + 20480;
    float* cs1_8 = csb + 24576,  *cs2_8 = csb + 28672;
    float* stats5 = (float*)(ws + 226689024);
    float* stats6 = stats5 + 512;
    float* stats7 = stats5 + 1024;
    float* stats8 = stats5 + 1536;
    float* pmax  = (float*)(ws + 226697216);                    //  512 KB
    float* psum  = (float*)(ws + 227221504);                    //  512 KB

    const dim3 B256(256);
    const unsigned short* nu = nullptr;

    // 0. zero colsum accumulators (ws is poisoned each launch)
    hipMemsetAsync(csb, 0, 131072, stream);

    // 1. norms, transposes + bf16 splits, weight folds/splits
    normK<<<dim3(8, 8, 2), B256, 0, stream>>>(x3, y3, invnx, invny);
    tsplitK<6><<<dim3(32, 2, 8), B256, 0, stream>>>(y3, 128, nullptr, invny, ynH, ynL, yT);
    tsplitK<3><<<dim3(32, 2, 8), B256, 0, stream>>>(x3, 128, x3tH, invnx, xnH, xnL, nullptr);
    tsplitK<1><<<dim3(32, 1, 8), B256, 0, stream>>>(x1, 64, x1tH, nullptr, nullptr, nullptr, nullptr);
    tsplitK<1><<<dim3(32, 1, 8), B256, 0, stream>>>(x2, 64, x2tH, nullptr, nullptr, nullptr, nullptr);
    wsplitK<<<dim3(1024, 5), B256, 0, stream>>>(w4, w5, wm1, wm2, wm3,
        w4pH, w5H, m1H, m2H, m3H);

    // 2. simi (3-pass split-bf16 MFMA, all 8 batches) + adaptive-quant topk
    mgemm<0, 0, 3><<<dim3(16, 16, 8), B256, 0, stream>>>(
        xnH, xnL, 128, nu, nu, nu, nu, nu, nu,
        ynH, ynL, (long)N2 * 128, 128, 2048, 0,
        simiF, nullptr, nullptr, nullptr, nullptr, nullptr);
    topkK<<<dim3(2048, 8), B256, 0, stream>>>(simiF, topw, topi, 0);

    // 3. gather-aggregate G (hi bf16); b fastest for XCD-L2 locality
    aggK<<<dim3(8, 256), B256, 0, stream>>>(yT, topw, topi, GH);

    // 4. conv4 (+BN eval + lrelu) over [x3 | G] with folded W4' -> x4 (1-pass)
    mgemm<1, 1, 1><<<dim3(16, 2, 8), B256, 0, stream>>>(
        x3tH, nu, 128, GH, nu, nu, nu, nu, nu,
        w4pH, nu, 0, 256, 256, 0,
        nullptr, x4H, bn4g, bn4b, nullptr, nullptr);

    // 5. conv5 over [x1|x2|x3|x4] -> pre + colsums; GN5 + lrelu -> lc (1-pass)
    mgemm<2, 2, 1><<<dim3(16, 4, 8), B256, 0, stream>>>(
        x1tH, nu, 64, x2tH, nu, x3tH, nu, x4H, nu,
        w5H, nu, 0, 512, 512, 0,
        bufPS, nullptr, nullptr, nullptr, cs1_5, cs2_5);
    statsK<<<1, B256, 0, stream>>>(cs1_5, cs2_5, stats5, 512);
    gnapplyK<0, 9><<<8192, B256, 0, stream>>>(bufPS, stats5, gn5g, gn5b, lcH);

    // 6. global pooling -> gv section of output (two-stage)
    pool1K<<<dim3(32, 8), B256, 0, stream>>>(lcH, pmax, psum);
    pool2K<<<dim3(8), B256, 0, stream>>>(pmax, psum, out + (long)8 * 128 * 2048);

    // 7. mlp1 -> pre + colsums; GN6 + relu -> h1 (1-pass)
    mgemm<0, 2, 1><<<dim3(16, 4, 8), B256, 0, stream>>>(
        lcH, nu, 512, nu, nu, nu, nu, nu, nu,
        m1H, nu, 0, 512, 512, 0,
        bufPS, nullptr, nullptr, bm1, cs1_6, cs2_6);
    statsK<<<1, B256, 0, stream>>>(cs1_6, cs2_6, stats6, 512);
    gnapplyK<1, 9><<<8192, B256, 0, stream>>>(bufPS, stats6, gn6g, gn6b, h1H);

    // 8. mlp2 -> pre + colsums; GN7 + relu -> h2 (1-pass)
    mgemm<0, 2, 1><<<dim3(16, 2, 8), B256, 0, stream>>>(
        h1H, nu, 512, nu, nu, nu, nu, nu, nu,
        m2H, nu, 0, 512, 256, 0,
        bufPS, nullptr, nullptr, bm2, cs1_7, cs2_7);
    statsK<<<1, B256, 0, stream>>>(cs1_7, cs2_7, stats7, 256);
    gnapplyK<1, 8><<<4096, B256, 0, stream>>>(bufPS, stats7, gn7g, gn7b, h2H);

    // 9. mlp3 -> pre + colsums; GN8 + relu + transpose -> emb (1-pass)
    mgemm<0, 2, 1><<<dim3(16, 1, 8), B256, 0, stream>>>(
        h2H, nu, 256, nu, nu, nu, nu, nu, nu,
        m3H, nu, 0, 256, 128, 0,
        bufPS, nullptr, nullptr, bm3, cs1_8, cs2_8);
    statsK<<<1, B256, 0, stream>>>(cs1_8, cs2_8, stats8, 128);
    gnfinalK<<<dim3(32, 2, 8), B256, 0, stream>>>(bufPS, stats8, gn8g, gn8b, out);
}

// Round 13
// 325.789 us; speedup vs baseline: 3.6993x; 1.0994x over previous
//
#include <hip/hip_runtime.h>
#include <math.h>

#define N2 2048
#define LRELU_S 0.2f
#define BN4_RS 0.9999950000374997f   // rsqrt(1+1e-5)

typedef short bf16x8 __attribute__((ext_vector_type(8)));
typedef float f32x16 __attribute__((ext_vector_type(16)));
typedef float f32x4 __attribute__((ext_vector_type(4)));

__device__ __forceinline__ unsigned short bhi(float v) { return (unsigned short)(__float_as_uint(v) >> 16); }
__device__ __forceinline__ float bhif(float v) { return __uint_as_float(__float_as_uint(v) & 0xFFFF0000u); }
__device__ __forceinline__ float bf2f(unsigned short u) { return __uint_as_float(((unsigned int)u) << 16); }

__device__ __forceinline__ void gl16(const void* g, void* l) {
    __builtin_amdgcn_global_load_lds((const __attribute__((address_space(1))) unsigned int*)g,
                                     (__attribute__((address_space(3))) unsigned int*)l, 16, 0, 0);
}

__device__ __forceinline__ f32x16 z16() {
    f32x16 v;
    #pragma unroll
    for (int i = 0; i < 16; ++i) v[i] = 0.f;
    return v;
}

#define MFMA32 __builtin_amdgcn_mfma_f32_32x32x16_bf16

// ---------------------------------------------------------------------------
// Split-bf16 MFMA GEMM.  out[bz][n][o] = sum_k A[b][n][k] * B[o][k]
// PASSES: 3 = hi*hi + hi*lo + lo*hi (err ~2^-16, simi/topk selection path)
//         1 = hi*hi only            (err ~2^-9, conv/mlp path; GN absorbs it)
// EPI 0 stores nontemporal (simi is dead after topk; keep it out of L2).
// ---------------------------------------------------------------------------
template<int ASRC, int EPI, int PASSES>
__global__ __launch_bounds__(256) void mgemm(
    const unsigned short* __restrict__ a1H, const unsigned short* __restrict__ a1L, int CA,
    const unsigned short* __restrict__ a2H, const unsigned short* __restrict__ a2L,
    const unsigned short* __restrict__ a3H, const unsigned short* __restrict__ a3L,
    const unsigned short* __restrict__ a4H, const unsigned short* __restrict__ a4L,
    const unsigned short* __restrict__ bH,  const unsigned short* __restrict__ bL, long bBs,
    int Ktot, int OC, int bbase,
    float* __restrict__ outF, unsigned short* __restrict__ oH,
    const float* __restrict__ epg, const float* __restrict__ epb,
    float* __restrict__ cs1, float* __restrict__ cs2)
{
    __shared__ alignas(16) unsigned short lAh[4096], lBh[4096];
    __shared__ alignas(16) unsigned short lAl[PASSES == 3 ? 4096 : 16];
    __shared__ alignas(16) unsigned short lBl[PASSES == 3 ? 4096 : 16];
    const int t  = threadIdx.x;
    const int n0 = blockIdx.x * 128;
    const int o0 = blockIdx.y * 128;
    const int bz = blockIdx.z;
    const int b  = bbase + bz;

    const int lane = t & 63;
    const int h    = lane >> 5;
    const int l31  = lane & 31;
    const int wid  = t >> 6;
    const int wm   = wid >> 1;
    const int wn   = wid & 1;
    const int sw   = (l31 >> 1) & 3;            // LDS chunk swizzle for frag reads

    f32x16 acc00 = z16(), acc01 = z16(), acc10 = z16(), acc11 = z16();

    const int q0 = t, q1 = t + 256;
    const int r0 = q0 >> 2, p0 = q0 & 3, c0s = p0 ^ ((r0 >> 1) & 3);
    const int r1 = q1 >> 2, p1 = q1 & 3, c1s = p1 ^ ((r1 >> 1) & 3);

    const int rA0 = (wm * 64 + l31) * 32, rA1 = rA0 + 1024;
    const int rB0 = (wn * 64 + l31) * 32, rB1 = rB0 + 1024;

    for (int kc = 0; kc < Ktot; kc += 32) {
        const unsigned short *sAH, *sAL; int koff, Cs;
        if (ASRC == 0)      { sAH = a1H; sAL = a1L; koff = kc;       Cs = CA; }
        else if (ASRC == 1) {
            if (kc < 128)   { sAH = a1H; sAL = a1L; koff = kc;       Cs = 128; }
            else            { sAH = a2H; sAL = a2L; koff = kc - 128; Cs = 128; }
        } else {
            if (kc < 64)        { sAH = a1H; sAL = a1L; koff = kc;       Cs = 64;  }
            else if (kc < 128)  { sAH = a2H; sAL = a2L; koff = kc - 64;  Cs = 64;  }
            else if (kc < 256)  { sAH = a3H; sAL = a3L; koff = kc - 128; Cs = 128; }
            else                { sAH = a4H; sAL = a4L; koff = kc - 256; Cs = 256; }
        }
        __syncthreads();
        {
            long ga = ((long)b * N2 + n0 + r0) * Cs + koff + c0s * 8;
            long gb = (long)b * bBs + (long)(o0 + r0) * Ktot + kc + c0s * 8;
            gl16(sAH + ga, lAh + q0 * 8);
            gl16(bH + gb, lBh + q0 * 8);
            if (PASSES == 3) { gl16(sAL + ga, lAl + q0 * 8); gl16(bL + gb, lBl + q0 * 8); }
            long ga1 = ((long)b * N2 + n0 + r1) * Cs + koff + c1s * 8;
            long gb1 = (long)b * bBs + (long)(o0 + r1) * Ktot + kc + c1s * 8;
            gl16(sAH + ga1, lAh + q1 * 8);
            gl16(bH + gb1, lBh + q1 * 8);
            if (PASSES == 3) { gl16(sAL + ga1, lAl + q1 * 8); gl16(bL + gb1, lBl + q1 * 8); }
        }
        __syncthreads();
        #pragma unroll
        for (int s = 0; s < 2; ++s) {
            const int off = ((s * 2 + h) ^ sw) * 8;
            bf16x8 a0h = *(const bf16x8*)(lAh + rA0 + off);
            bf16x8 a1h_ = *(const bf16x8*)(lAh + rA1 + off);
            bf16x8 b0h = *(const bf16x8*)(lBh + rB0 + off);
            bf16x8 b1h = *(const bf16x8*)(lBh + rB1 + off);
            acc00 = MFMA32(a0h, b0h, acc00, 0, 0, 0);
            acc01 = MFMA32(a0h, b1h, acc01, 0, 0, 0);
            acc10 = MFMA32(a1h_, b0h, acc10, 0, 0, 0);
            acc11 = MFMA32(a1h_, b1h, acc11, 0, 0, 0);
            if (PASSES == 3) {
                bf16x8 a0l = *(const bf16x8*)(lAl + rA0 + off);
                bf16x8 a1l_ = *(const bf16x8*)(lAl + rA1 + off);
                bf16x8 b0l = *(const bf16x8*)(lBl + rB0 + off);
                bf16x8 b1l = *(const bf16x8*)(lBl + rB1 + off);
                acc00 = MFMA32(a0h, b0l, acc00, 0, 0, 0);
                acc00 = MFMA32(a0l, b0h, acc00, 0, 0, 0);
                acc01 = MFMA32(a0h, b1l, acc01, 0, 0, 0);
                acc01 = MFMA32(a0l, b1h, acc01, 0, 0, 0);
                acc10 = MFMA32(a1h_, b0l, acc10, 0, 0, 0);
                acc10 = MFMA32(a1l_, b0h, acc10, 0, 0, 0);
                acc11 = MFMA32(a1h_, b1l, acc11, 0, 0, 0);
                acc11 = MFMA32(a1l_, b1h, acc11, 0, 0, 0);
            }
        }
    }

    #pragma unroll
    for (int ni = 0; ni < 2; ++ni) {
        const int o = o0 + wn * 64 + ni * 32 + l31;
        float sc = 0.f, sh = 0.f, bias = 0.f;
        if (EPI == 1) { sc = epg[o] * BN4_RS; sh = epb[o]; }
        if (EPI == 2) { bias = epb ? epb[o] : 0.f; }
        float s1 = 0.f, s2 = 0.f;
        #pragma unroll
        for (int mi = 0; mi < 2; ++mi) {
            #pragma unroll
            for (int r = 0; r < 16; ++r) {
                const int n = n0 + wm * 64 + mi * 32 + (r & 3) + 8 * (r >> 2) + 4 * h;
                float v = (ni == 0) ? (mi == 0 ? acc00[r] : acc10[r])
                                    : (mi == 0 ? acc01[r] : acc11[r]);
                const long oi = ((long)bz * N2 + n) * (long)OC + o;
                if (EPI == 0) {
                    __builtin_nontemporal_store(v, outF + oi);
                } else if (EPI == 1) {
                    v = fmaf(v, sc, sh);
                    v = v >= 0.f ? v : LRELU_S * v;
                    oH[oi] = bhi(v);
                } else {
                    v += bias;
                    outF[oi] = v;
                    s1 += v; s2 = fmaf(v, v, s2);
                }
            }
        }
        if (EPI == 2) {
            s1 += __shfl_xor(s1, 32);
            s2 += __shfl_xor(s2, 32);
            if (h == 0) {
                atomicAdd(cs1 + bz * OC + o, s1);
                atomicAdd(cs2 + bz * OC + o, s2);
            }
        }
    }
}

// ---------------------------------------------------------------------------
// Fused transpose + norm for x3 (MODE&1: unscaled hi out) / y3 (MODE&4: fp32 out).
// Always writes invnorm-scaled hi/lo bf16 [n][128].  Norm summation order is
// bit-identical to the old normK (sequential c, fmaf).
template<int MODE>
__global__ __launch_bounds__(256) void tnormK(
    const float* __restrict__ in,
    unsigned short* __restrict__ tHi, float* __restrict__ tF,
    unsigned short* __restrict__ sHi, unsigned short* __restrict__ sLo)
{
    __shared__ float lt[64 * 130];
    __shared__ float pinv[64];
    const int t = threadIdx.x;
    const int n0 = blockIdx.x * 64, b = blockIdx.z;
    {
        const int nl = t & 63;
        const int cb = t >> 6;
        #pragma unroll
        for (int i = 0; i < 32; ++i) {
            const int cl = cb + 4 * i;
            lt[nl * 130 + cl] = in[((long)b * 128 + cl) * N2 + n0 + nl];
        }
    }
    __syncthreads();
    if (t < 64) {
        float ss = 0.f;
        for (int c = 0; c < 128; ++c) {
            const float v = lt[t * 130 + c];
            ss = fmaf(v, v, ss);
        }
        pinv[t] = rsqrtf(ss);
    }
    __syncthreads();
    const int cl = t & 127;
    const int nb = t >> 7;
    #pragma unroll
    for (int i = 0; i < 32; ++i) {
        const int nl = nb + 2 * i;
        const float v = lt[nl * 130 + cl];
        const float sv = v * pinv[nl];
        const long oi = ((long)b * N2 + n0 + nl) * 128 + cl;
        sHi[oi] = bhi(sv); sLo[oi] = bhi(sv - bhif(sv));
        if (MODE & 1) tHi[oi] = bhi(v);
        if (MODE & 4) tF[oi] = v;
    }
}

// ---------------------------------------------------------------------------
// transpose x1/x2 [64][2048] -> [2048][64] hi bf16 (z<8: x1, else x2)
__global__ __launch_bounds__(256) void t64K(
    const float* __restrict__ x1, const float* __restrict__ x2,
    unsigned short* __restrict__ o1, unsigned short* __restrict__ o2)
{
    __shared__ float lt[64 * 65];
    const int t = threadIdx.x;
    const int z = blockIdx.z;
    const int b = z & 7;
    const float* in = (z < 8) ? x1 : x2;
    unsigned short* outp = (z < 8) ? o1 : o2;
    const int n0 = blockIdx.x * 64;
    {
        const int nl = t & 63;
        const int cb = t >> 6;
        #pragma unroll
        for (int i = 0; i < 16; ++i) {
            const int cl = cb + 4 * i;
            lt[nl * 65 + cl] = in[((long)b * 64 + cl) * N2 + n0 + nl];
        }
    }
    __syncthreads();
    const int cl = t & 63;
    const int nb = t >> 6;
    #pragma unroll
    for (int i = 0; i < 16; ++i) {
        const int nl = nb + 4 * i;
        outp[((long)b * N2 + n0 + nl) * 64 + cl] = bhi(lt[nl * 65 + cl]);
    }
}

// ---------------------------------------------------------------------------
// weight fold (w4) + bf16 hi split for all 5 weight tensors
__global__ void wsplitK(const float* __restrict__ w4, const float* __restrict__ w5,
    const float* __restrict__ wm1, const float* __restrict__ wm2, const float* __restrict__ wm3,
    unsigned short* __restrict__ w4h, unsigned short* __restrict__ w5h,
    unsigned short* __restrict__ m1h, unsigned short* __restrict__ m2h,
    unsigned short* __restrict__ m3h)
{
    const int y = blockIdx.y;
    const int idx = blockIdx.x * 256 + threadIdx.x;
    float v; unsigned short* dh;
    if (y == 0) {
        if (idx >= 256 * 256) return;
        const int k = idx & 255;
        v = w4[idx];
        if (k < 128) v -= w4[idx + 128];
        dh = w4h;
    } else if (y == 1) {
        if (idx >= 512 * 512) return;
        v = w5[idx]; dh = w5h;
    } else if (y == 2) {
        if (idx >= 512 * 512) return;
        v = wm1[idx]; dh = m1h;
    } else if (y == 3) {
        if (idx >= 256 * 512) return;
        v = wm2[idx]; dh = m2h;
    } else {
        if (idx >= 128 * 256) return;
        v = wm3[idx]; dh = m3h;
    }
    dh[idx] = bhi(v);
}

// ---------------------------------------------------------------------------
// top-20 of a 2048 simi row: value-space adaptive-quantization select.
__global__ __launch_bounds__(256) void topkK(const float* __restrict__ simi,
    float* __restrict__ topw, int* __restrict__ topi, int bbase)
{
    __shared__ unsigned int hist[256];
    __shared__ unsigned int bcast[2];
    __shared__ float lmn[4], lmx[4];
    __shared__ unsigned int cnt0, candCnt, tick;
    __shared__ unsigned int candU[256];
    __shared__ float candV[256];
    __shared__ int   candI[256];
    __shared__ float selv[20];
    __shared__ int   seli[20];
    const int t  = threadIdx.x;
    const int n  = blockIdx.x;
    const int bl = blockIdx.y;
    const float* row = simi + ((long)bl * N2 + n) * N2;

    float    f[8];
    unsigned u[8];
    {
        const f32x4 v0 = __builtin_nontemporal_load((const f32x4*)(row + 4 * t));
        const f32x4 v1 = __builtin_nontemporal_load((const f32x4*)(row + 1024 + 4 * t));
        f[0] = v0[0]; f[1] = v0[1]; f[2] = v0[2]; f[3] = v0[3];
        f[4] = v1[0]; f[5] = v1[1]; f[6] = v1[2]; f[7] = v1[3];
        #pragma unroll
        for (int i = 0; i < 8; ++i) {
            unsigned ub = __float_as_uint(f[i]);
            u[i] = ub ^ (((int)ub >> 31) | 0x80000000u);   // order-preserving flip
        }
    }

    // ---- row min / max ----
    float tmn = f[0], tmx = f[0];
    #pragma unroll
    for (int i = 1; i < 8; ++i) { tmn = fminf(tmn, f[i]); tmx = fmaxf(tmx, f[i]); }
    #pragma unroll
    for (int off = 1; off < 64; off <<= 1) {
        tmn = fminf(tmn, __shfl_xor(tmn, off));
        tmx = fmaxf(tmx, __shfl_xor(tmx, off));
    }
    if ((t & 63) == 0) { lmn[t >> 6] = tmn; lmx[t >> 6] = tmx; }
    if (t == 0) { cnt0 = 0; candCnt = 0; tick = 0; }
    hist[t] = 0;
    __syncthreads();
    const float rmn = fminf(fminf(lmn[0], lmn[1]), fminf(lmn[2], lmn[3]));
    const float rmx = fmaxf(fmaxf(lmx[0], lmx[1]), fmaxf(lmx[2], lmx[3]));
    const float rng = rmx - rmn;
    const float scale = (rng > 0.f) ? (255.0f / rng) : 0.f;

    // ---- quantize + histogram ----
    int q[8];
    #pragma unroll
    for (int i = 0; i < 8; ++i) {
        int qi = (int)((f[i] - rmn) * scale);
        q[i] = qi < 0 ? 0 : (qi > 255 ? 255 : qi);
        atomicAdd(&hist[q[i]], 1u);
    }
    __syncthreads();

    // ---- suffix-scan to find boundary bin (20th largest) ----
    if (t < 64) {
        const unsigned h0 = hist[4 * t], h1 = hist[4 * t + 1];
        const unsigned h2 = hist[4 * t + 2], h3 = hist[4 * t + 3];
        const unsigned s3 = h3, s2 = h2 + s3, s1 = h1 + s2, s0 = h0 + s1;
        unsigned inc = s0;
        #pragma unroll
        for (int off = 1; off < 64; off <<= 1) {
            const unsigned o = __shfl_down(inc, off);
            if (t + off < 64) inc += o;
        }
        const unsigned excl = inc - s0;               // count in lanes > t
        const unsigned sf[5] = {excl + s0, excl + s1, excl + s2, excl + s3, excl};
        #pragma unroll
        for (int j = 0; j < 4; ++j) {
            if (sf[j] >= 20u && sf[j + 1] < 20u) {
                bcast[0] = 4 * t + j;
                bcast[1] = 20u - sf[j + 1];
            }
        }
    }
    __syncthreads();
    const int Abin   = (int)bcast[0];
    const int kneedA = (int)bcast[1];                 // to take from boundary bin
    const int gt     = 20 - kneedA;                   // strictly-greater count

    // ---- greater class: selected outright ----
    #pragma unroll
    for (int i = 0; i < 8; ++i) {
        const int idx = (i < 4) ? (4 * t + i) : (1024 + 4 * t + (i - 4));
        if (q[i] > Abin) {
            const unsigned s = atomicAdd(&cnt0, 1u);
            selv[s] = f[i]; seli[s] = idx;
        } else if (q[i] == Abin) {
            const unsigned s = atomicAdd(&candCnt, 1u);
            if (s < 256u) { candU[s] = u[i]; candV[s] = f[i]; candI[s] = idx; }
        }
    }
    __syncthreads();

    // ---- boundary bin: exact rank among candidates ----
    const int cc = (int)candCnt;
    if (cc <= 256) {
        for (int slot = t; slot < cc; slot += 256) {
            const unsigned ui = candU[slot];
            int r = 0;
            for (int j = 0; j < cc; ++j) {
                const unsigned uj = candU[j];
                r += (uj > ui) || (uj == ui && j < slot);
            }
            if (r < kneedA) { selv[gt + r] = candV[slot]; seli[gt + r] = candI[slot]; }
        }
    } else {
        // degenerate (massive ties): take first kneedA encountered
        #pragma unroll
        for (int i = 0; i < 8; ++i) {
            const int idx = (i < 4) ? (4 * t + i) : (1024 + 4 * t + (i - 4));
            if (q[i] == Abin) {
                const unsigned e = atomicAdd(&tick, 1u);
                if ((int)e < kneedA) { selv[gt + e] = f[i]; seli[gt + e] = idx; }
            }
        }
    }
    __syncthreads();

    // ---- softmax over the 20 + store ----
    if (t < 64) {
        const float v = (t < 20) ? selv[t] : -1e30f;
        float m = v;
        #pragma unroll
        for (int off = 1; off < 32; off <<= 1) m = fmaxf(m, __shfl_xor(m, off, 32));
        const float e = (t < 20) ? expf(v - m) : 0.f;
        float s = e;
        #pragma unroll
        for (int off = 1; off < 32; off <<= 1) s += __shfl_xor(s, off, 32);
        if (t < 20) {
            const long base = (((long)(bbase + bl)) * N2 + n) * 20;
            topw[base + t] = e / s;
            topi[base + t] = seli[t];
        }
    }
}

// ---------------------------------------------------------------------------
// G[n][c] = sum_k w_k * yT[idx_k][c], hi bf16 out.  b fastest for XCD-L2 locality.
__global__ __launch_bounds__(256) void aggK(const float* __restrict__ yT,
    const float* __restrict__ topw, const int* __restrict__ topi,
    unsigned short* __restrict__ Gh)
{
    const int t  = threadIdx.x;
    const int c4 = (t & 31) * 4;
    const int ns = t >> 5;                   // 0..7
    const int b  = blockIdx.x;               // fastest grid dim
    const int n  = blockIdx.y * 8 + ns;
    const long tb = ((long)b * N2 + n) * 20;
    const float* yb = yT + (long)b * N2 * 128 + c4;

    float a0 = 0.f, a1 = 0.f, a2 = 0.f, a3 = 0.f;
    #pragma unroll
    for (int k = 0; k < 20; ++k) {
        const float w  = topw[tb + k];
        const int  idx = topi[tb + k];
        const float4 v = *(const float4*)(yb + (long)idx * 128);
        a0 = fmaf(w, v.x, a0);
        a1 = fmaf(w, v.y, a1);
        a2 = fmaf(w, v.z, a2);
        a3 = fmaf(w, v.w, a3);
    }
    const long oi = ((long)b * N2 + n) * 128 + c4;
    ushort4 hh;
    hh.x = bhi(a0); hh.y = bhi(a1); hh.z = bhi(a2); hh.w = bhi(a3);
    *(ushort4*)(Gh + oi) = hh;
}

// ---------------------------------------------------------------------------
// GN apply + activation with INLINE stats (from colsum buffers).
// fp32 [n][C] -> hi bf16 [n][C].  ACT 0=lrelu 1=relu.  Block = 1024 elems.
template<int ACT, int LC>
__global__ void gnapplyK(const float* __restrict__ pre,
    const float* __restrict__ cs1, const float* __restrict__ cs2,
    const float* __restrict__ gamma, const float* __restrict__ beta,
    unsigned short* __restrict__ oH)
{
    __shared__ float smu[32], srs[32];
    const int C = 1 << LC;
    const int cpg = C >> 5;
    const long blockBase = (long)blockIdx.x * 1024;
    const int b = (int)(blockBase >> (LC + 11));
    const int t = threadIdx.x;
    if (t < 32) {
        float s1 = 0.f, s2 = 0.f;
        for (int j = 0; j < cpg; ++j) {
            s1 += cs1[b * C + t * cpg + j];
            s2 += cs2[b * C + t * cpg + j];
        }
        const float cnt = (float)(cpg * N2);
        const float mu = s1 / cnt;
        const float var = s2 / cnt - mu * mu;
        smu[t] = mu; srs[t] = rsqrtf(var + 1e-5f);
    }
    __syncthreads();
    const long i4 = blockBase + t * 4;
    const int c = (int)(i4 & (C - 1));
    const int g = c >> (LC - 5);
    const float mu = smu[g];
    const float rs = srs[g];
    const float4 gm = *(const float4*)(gamma + c);
    const float4 bt = *(const float4*)(beta + c);
    const float4 v = *(const float4*)(pre + i4);
    const float vals[4] = {v.x, v.y, v.z, v.w};
    const float gms[4] = {gm.x, gm.y, gm.z, gm.w};
    const float bts[4] = {bt.x, bt.y, bt.z, bt.w};
    unsigned short hs[4];
    #pragma unroll
    for (int j = 0; j < 4; ++j) {
        float x = (vals[j] - mu) * (rs * gms[j]) + bts[j];
        x = (ACT == 0) ? (x >= 0.f ? x : LRELU_S * x) : (x >= 0.f ? x : 0.f);
        hs[j] = bhi(x);
    }
    ushort4 hh; hh.x = hs[0]; hh.y = hs[1]; hh.z = hs[2]; hh.w = hs[3];
    *(ushort4*)(oH + i4) = hh;
}

// ---------------------------------------------------------------------------
// final GN8 (inline stats) + relu + transpose to out[b][128][2048]
__global__ __launch_bounds__(256) void gnfinalK(const float* __restrict__ pre,
    const float* __restrict__ cs1, const float* __restrict__ cs2,
    const float* __restrict__ gamma, const float* __restrict__ beta,
    float* __restrict__ out)
{
    __shared__ float lt[64 * 65];
    __shared__ float smu[16], srs[16];
    const int t = threadIdx.x;
    const int n0 = blockIdx.x * 64, c0 = blockIdx.y * 64, b = blockIdx.z;
    if (t < 16) {
        const int g = (c0 >> 2) + t;
        float s1 = 0.f, s2 = 0.f;
        for (int j = 0; j < 4; ++j) {
            s1 += cs1[b * 128 + g * 4 + j];
            s2 += cs2[b * 128 + g * 4 + j];
        }
        const float cnt = (float)(4 * N2);
        const float mu = s1 / cnt;
        const float var = s2 / cnt - mu * mu;
        smu[t] = mu; srs[t] = rsqrtf(var + 1e-5f);
    }
    __syncthreads();
    {
        const int cl = t & 63;
        const int nb = t >> 6;
        const int c = c0 + cl;
        const float mu = smu[cl >> 2];
        const float rs = srs[cl >> 2];
        const float sc = rs * gamma[c], sh = beta[c] - mu * sc;
        #pragma unroll
        for (int i = 0; i < 16; ++i) {
            const int nl = nb + 4 * i;
            float v = pre[((long)b * N2 + n0 + nl) * 128 + c];
            v = v * sc + sh;
            lt[cl * 65 + nl] = v > 0.f ? v : 0.f;
        }
    }
    __syncthreads();
    const int nl = t & 63;
    const int cb = t >> 6;
    #pragma unroll
    for (int i = 0; i < 16; ++i) {
        const int cl = cb + 4 * i;
        out[((long)b * 128 + c0 + cl) * N2 + n0 + nl] = lt[cl * 65 + nl];
    }
}

// ---------------------------------------------------------------------------
// pooling stage 1: per (b, n-chunk of 64) partial max/sum over all 512 channels
__global__ __launch_bounds__(256) void pool1K(const unsigned short* __restrict__ lcH,
    float* __restrict__ pmax, float* __restrict__ psum)
{
    __shared__ float lmx[512], lsm[512];
    const int t  = threadIdx.x;
    const int cq = t & 127;          // channel quad
    const int rp = t >> 7;           // row parity
    const int nch = blockIdx.x;      // 0..31 (64 rows each)
    const int b   = blockIdx.y;
    float mx[4] = {-1e30f, -1e30f, -1e30f, -1e30f};
    float sm[4] = {0.f, 0.f, 0.f, 0.f};
    for (int i = 0; i < 32; ++i) {
        const int n = nch * 64 + 2 * i + rp;
        const long base = ((long)b * N2 + n) * 512 + cq * 4;
        const ushort4 hh = *(const ushort4*)(lcH + base);
        const float v0 = bf2f(hh.x);
        const float v1 = bf2f(hh.y);
        const float v2 = bf2f(hh.z);
        const float v3 = bf2f(hh.w);
        mx[0] = fmaxf(mx[0], v0); sm[0] += v0;
        mx[1] = fmaxf(mx[1], v1); sm[1] += v1;
        mx[2] = fmaxf(mx[2], v2); sm[2] += v2;
        mx[3] = fmaxf(mx[3], v3); sm[3] += v3;
    }
    if (rp) {
        #pragma unroll
        for (int j = 0; j < 4; ++j) { lmx[cq * 4 + j] = mx[j]; lsm[cq * 4 + j] = sm[j]; }
    }
    __syncthreads();
    if (!rp) {
        const long pb = ((long)(b * 32 + nch)) * 512 + cq * 4;
        #pragma unroll
        for (int j = 0; j < 4; ++j) {
            pmax[pb + j] = fmaxf(mx[j], lmx[cq * 4 + j]);
            psum[pb + j] = sm[j] + lsm[cq * 4 + j];
        }
    }
}

// pooling stage 2: reduce 32 chunk partials -> gv[b][1024] (max | mean)
__global__ void pool2K(const float* __restrict__ pmax, const float* __restrict__ psum,
                       float* __restrict__ gv)
{
    const int t = threadIdx.x;       // 256: 2 channels each
    const int b = blockIdx.x;
    float mx0 = -1e30f, mx1 = -1e30f, s0 = 0.f, s1 = 0.f;
    for (int nch = 0; nch < 32; ++nch) {
        const long pb = ((long)(b * 32 + nch)) * 512 + 2 * t;
        const float2 pm = *(const float2*)(pmax + pb);
        const float2 ps = *(const float2*)(psum + pb);
        mx0 = fmaxf(mx0, pm.x); mx1 = fmaxf(mx1, pm.y);
        s0 += ps.x; s1 += ps.y;
    }
    gv[b * 1024 + 2 * t]           = mx0;
    gv[b * 1024 + 2 * t + 1]       = mx1;
    gv[b * 1024 + 512 + 2 * t]     = s0 * (1.f / 2048.f);
    gv[b * 1024 + 512 + 2 * t + 1] = s1 * (1.f / 2048.f);
}

// ---------------------------------------------------------------------------
extern "C" void kernel_launch(void* const* d_in, const int* in_sizes, int n_in,
                              void* d_out, int out_size, void* d_ws, size_t ws_size,
                              hipStream_t stream)
{
    const float* x1    = (const float*)d_in[0];
    const float* x2    = (const float*)d_in[1];
    const float* x3    = (const float*)d_in[2];
    const float* y3    = (const float*)d_in[3];
    const float* w4    = (const float*)d_in[4];
    const float* bn4g  = (const float*)d_in[5];
    const float* bn4b  = (const float*)d_in[6];
    const float* w5    = (const float*)d_in[7];
    const float* gn5g  = (const float*)d_in[8];
    const float* gn5b  = (const float*)d_in[9];
    const float* wm1   = (const float*)d_in[10];
    const float* bm1   = (const float*)d_in[11];
    const float* gn6g  = (const float*)d_in[12];
    const float* gn6b  = (const float*)d_in[13];
    const float* wm2   = (const float*)d_in[14];
    const float* bm2   = (const float*)d_in[15];
    const float* gn7g  = (const float*)d_in[16];
    const float* gn7b  = (const float*)d_in[17];
    const float* wm3   = (const float*)d_in[18];
    const float* bm3   = (const float*)d_in[19];
    const float* gn8g  = (const float*)d_in[20];
    const float* gn8b  = (const float*)d_in[21];
    float* out = (float*)d_out;
    (void)in_sizes; (void)n_in; (void)out_size; (void)ws_size;

    char* ws = (char*)d_ws;
    // ---- arena (~218 MB of the 256 MiB ws) ----
    float*          simiF = (float*)(ws + 0);                   // 134.2 MB full simi
    float*          bufPS = (float*)(ws + 0);                   // alias: GEMM pre after topk
    unsigned short* lcH   = (unsigned short*)(ws + 134217728);  // 16.78 MB
    unsigned short* h1H   = (unsigned short*)(ws + 150994944);  // 16.78 MB
    unsigned short* x4H   = (unsigned short*)(ws + 167772160);  //  8.39 MB
    unsigned short* h2H   = (unsigned short*)(ws + 176160768);  //  8.39 MB
    float*          yT    = (float*)(ws + 184549376);           //  8.39 MB
    unsigned short* x3tH  = (unsigned short*)(ws + 192937984);  //  4.19 MB
    unsigned short* GH    = (unsigned short*)(ws + 197132288);  //  4.19 MB
    unsigned short* xnH   = (unsigned short*)(ws + 201326592);
    unsigned short* xnL   = (unsigned short*)(ws + 205520896);
    unsigned short* ynH   = (unsigned short*)(ws + 209715200);
    unsigned short* ynL   = (unsigned short*)(ws + 213909504);
    unsigned short* x1tH  = (unsigned short*)(ws + 218103808);  //  2.10 MB
    unsigned short* x2tH  = (unsigned short*)(ws + 220200960);  //  2.10 MB
    unsigned short* w4pH  = (unsigned short*)(ws + 222298112);
    unsigned short* w5H   = (unsigned short*)(ws + 222429184);
    unsigned short* m1H   = (unsigned short*)(ws + 222953472);
    unsigned short* m2H   = (unsigned short*)(ws + 223477760);
    unsigned short* m3H   = (unsigned short*)(ws + 223739904);
    float* topw  = (float*)(ws + 223936512);                    //  1.31 MB
    int*   topi  = (int*)  (ws + 225247232);                    //  1.31 MB
    float* csb   = (float*)(ws + 226557952);                    //  128 KB
    float* cs1_5 = csb,          *cs2_5 = csb + 4096;
    float* cs1_6 = csb + 8192,   *cs2_6 = csb + 12288;
    float* cs1_7 = csb + 16384,  *cs2_7 = csb + 20480;
    float* cs1_8 = csb + 24576,  *cs2_8 = csb + 28672;
    float* pmax  = (float*)(ws + 226697216);                    //  512 KB
    float* psum  = (float*)(ws + 227221504);                    //  512 KB

    const dim3 B256(256);
    const unsigned short* nu = nullptr;

    // 0. zero colsum accumulators (ws is poisoned each launch)
    hipMemsetAsync(csb, 0, 131072, stream);

    // 1. fused transpose+norm (x3, y3), x1/x2 transpose, weight folds/splits
    tnormK<4><<<dim3(32, 1, 8), B256, 0, stream>>>(y3, nullptr, yT, ynH, ynL);
    tnormK<1><<<dim3(32, 1, 8), B256, 0, stream>>>(x3, x3tH, nullptr, xnH, xnL);
    t64K<<<dim3(32, 1, 16), B256, 0, stream>>>(x1, x2, x1tH, x2tH);
    wsplitK<<<dim3(1024, 5), B256, 0, stream>>>(w4, w5, wm1, wm2, wm3,
        w4pH, w5H, m1H, m2H, m3H);

    // 2. simi (3-pass split-bf16 MFMA, nt-store) + adaptive-quant topk (nt-load)
    mgemm<0, 0, 3><<<dim3(16, 16, 8), B256, 0, stream>>>(
        xnH, xnL, 128, nu, nu, nu, nu, nu, nu,
        ynH, ynL, (long)N2 * 128, 128, 2048, 0,
        simiF, nullptr, nullptr, nullptr, nullptr, nullptr);
    topkK<<<dim3(2048, 8), B256, 0, stream>>>(simiF, topw, topi, 0);

    // 3. gather-aggregate G (hi bf16); b fastest for XCD-L2 locality
    aggK<<<dim3(8, 256), B256, 0, stream>>>(yT, topw, topi, GH);

    // 4. conv4 (+BN eval + lrelu) over [x3 | G] with folded W4' -> x4 (1-pass)
    mgemm<1, 1, 1><<<dim3(16, 2, 8), B256, 0, stream>>>(
        x3tH, nu, 128, GH, nu, nu, nu, nu, nu,
        w4pH, nu, 0, 256, 256, 0,
        nullptr, x4H, bn4g, bn4b, nullptr, nullptr);

    // 5. conv5 over [x1|x2|x3|x4] -> pre + colsums; GN5(inline stats)+lrelu -> lc
    mgemm<2, 2, 1><<<dim3(16, 4, 8), B256, 0, stream>>>(
        x1tH, nu, 64, x2tH, nu, x3tH, nu, x4H, nu,
        w5H, nu, 0, 512, 512, 0,
        bufPS, nullptr, nullptr, nullptr, cs1_5, cs2_5);
    gnapplyK<0, 9><<<8192, B256, 0, stream>>>(bufPS, cs1_5, cs2_5, gn5g, gn5b, lcH);

    // 6. global pooling -> gv section of output (two-stage)
    pool1K<<<dim3(32, 8), B256, 0, stream>>>(lcH, pmax, psum);
    pool2K<<<dim3(8), B256, 0, stream>>>(pmax, psum, out + (long)8 * 128 * 2048);

    // 7. mlp1 -> pre + colsums; GN6(inline)+relu -> h1 (1-pass)
    mgemm<0, 2, 1><<<dim3(16, 4, 8), B256, 0, stream>>>(
        lcH, nu, 512, nu, nu, nu, nu, nu, nu,
        m1H, nu, 0, 512, 512, 0,
        bufPS, nullptr, nullptr, bm1, cs1_6, cs2_6);
    gnapplyK<1, 9><<<8192, B256, 0, stream>>>(bufPS, cs1_6, cs2_6, gn6g, gn6b, h1H);

    // 8. mlp2 -> pre + colsums; GN7(inline)+relu -> h2 (1-pass)
    mgemm<0, 2, 1><<<dim3(16, 2, 8), B256, 0, stream>>>(
        h1H, nu, 512, nu, nu, nu, nu, nu, nu,
        m2H, nu, 0, 512, 256, 0,
        bufPS, nullptr, nullptr, bm2, cs1_7, cs2_7);
    gnapplyK<1, 8><<<4096, B256, 0, stream>>>(bufPS, cs1_7, cs2_7, gn7g, gn7b, h2H);

    // 9. mlp3 -> pre + colsums; GN8(inline)+relu+transpose -> emb (1-pass)
    mgemm<0, 2, 1><<<dim3(16, 1, 8), B256, 0, stream>>>(
        h2H, nu, 256, nu, nu, nu, nu, nu, nu,
        m3H, nu, 0, 256, 128, 0,
        bufPS, nullptr, nullptr, bm3, cs1_8, cs2_8);
    gnfinalK<<<dim3(32, 2, 8), B256, 0, stream>>>(bufPS, cs1_8, cs2_8, gn8g, gn8b, out);
}